// Round 10
// baseline (796.315 us; speedup 1.0000x reference)
//
#include <hip/hip_runtime.h>

#define N1V 100000
#define N2V 500
#define NEV 1000000
#define ALPHAV 0.2f
#define NB 2048       // histogram/scatter blocks
#define CHUNK 489     // ceil(NEV/NB)
#define CHD 8         // dst chunks per type
#define GP 132        // As padded stride (k-major)

typedef float f32x4 __attribute__((ext_vector_type(4)));
typedef unsigned int u32;
typedef unsigned short u16;

__device__ __forceinline__ float wave_sum(float v) {
#pragma unroll
  for (int off = 32; off > 0; off >>= 1) v += __shfl_xor(v, off, 64);
  return v;
}

__device__ __forceinline__ u32 pack_bf16x2(float a, float b) {
  u32 ua = __float_as_uint(a), ub = __float_as_uint(b);
  u32 ra = (ua + 0x7FFFu + ((ua >> 16) & 1u)) >> 16;
  u32 rb = (ub + 0x7FFFu + ((ub >> 16) & 1u)) >> 16;
  return ra | (rb << 16);
}

__device__ __forceinline__ float bf16_to_f(u16 h) {
  return __uint_as_float(((u32)h) << 16);
}

// ---------------- prep: c[320] = a^T @ a_2 ; aT[p*128+j] = a[j*320+p] ----------------
__global__ __launch_bounds__(256) void k_prep(const float* __restrict__ a,
                                              const float* __restrict__ a2,
                                              float* __restrict__ c,
                                              float* __restrict__ aT) {
  int b = blockIdx.x;
  if (b < 160) {
    int id = b * 256 + threadIdx.x;          // 0..40959
    int p = id >> 7, j = id & 127;
    aT[id] = a[j * 320 + p];
  } else {
    int p = (b - 160) * 256 + threadIdx.x;   // 0..511
    if (p < 320) {
      float s = 0.f;
      for (int k = 0; k < 128; ++k) s += a2[k] * a[k * 320 + p];
      c[p] = s;
    }
  }
}

// ---------------- z2[t] = x2[t].c2 ; z1[i] = x1[i].c1 ----------------
__global__ __launch_bounds__(256) void k_z2(const float* __restrict__ x2,
                                            const float* __restrict__ c,
                                            float* __restrict__ z2g) {
  int w = (blockIdx.x * 256 + threadIdx.x) >> 6;
  int l = threadIdx.x & 63;
  if (w >= N2V) return;
  float p = x2[(size_t)w * 128 + l] * c[128 + l] + x2[(size_t)w * 128 + 64 + l] * c[192 + l];
  float s = wave_sum(p);
  if (l == 0) z2g[w] = s;
}

__global__ __launch_bounds__(256) void k_z1(const float* __restrict__ x1,
                                            const float* __restrict__ c,
                                            float* __restrict__ z1g) {
  int w = (blockIdx.x * 256 + threadIdx.x) >> 6;
  int l = threadIdx.x & 63;
  if (w >= N1V) return;
  float p = x1[(size_t)w * 128 + l] * c[l] + x1[(size_t)w * 128 + 64 + l] * c[64 + l];
  float s = wave_sum(p);
  if (l == 0) z1g[w] = s;
}

// ---------------- fused linear pass: histograms + w + ee->bf16 ----------------
// thread-per-edge within block chunk: reads ee row once (nontemporal),
// computes z3 dot, w -> wbuf (coalesced), eeh row (bf16, 128B contiguous),
// src histogram (global atomics), dst histogram (LDS -> hblk).
__global__ __launch_bounds__(256) void k_histw(const int* __restrict__ src,
                                               const int* __restrict__ dst,
                                               const float* __restrict__ ee,
                                               const float* __restrict__ z1g,
                                               const float* __restrict__ z2g,
                                               const float* __restrict__ c,
                                               int* __restrict__ c1,
                                               int* __restrict__ hblk,
                                               float* __restrict__ wbuf,
                                               u32* __restrict__ eeh) {
  __shared__ int h[512];
  __shared__ float c3s[64];
  for (int i = threadIdx.x; i < 512; i += 256) h[i] = 0;
  if (threadIdx.x < 64) c3s[threadIdx.x] = c[256 + threadIdx.x];
  __syncthreads();
  int b = blockIdx.x;
  int b0 = b * CHUNK, b1 = min(b0 + CHUNK, NEV);
  for (int e = b0 + threadIdx.x; e < b1; e += 256) {
    int sv = src[e], d = dst[e];
    const f32x4* row = (const f32x4*)(ee + (size_t)e * 64);
    u32* orow = eeh + (size_t)e * 32;
    float dot = 0.f;
#pragma unroll
    for (int q = 0; q < 4; ++q) {
      f32x4 f0 = __builtin_nontemporal_load(row + 4 * q + 0);
      f32x4 f1 = __builtin_nontemporal_load(row + 4 * q + 1);
      f32x4 f2 = __builtin_nontemporal_load(row + 4 * q + 2);
      f32x4 f3 = __builtin_nontemporal_load(row + 4 * q + 3);
      dot += f0.x * c3s[16 * q + 0] + f0.y * c3s[16 * q + 1] +
             f0.z * c3s[16 * q + 2] + f0.w * c3s[16 * q + 3] +
             f1.x * c3s[16 * q + 4] + f1.y * c3s[16 * q + 5] +
             f1.z * c3s[16 * q + 6] + f1.w * c3s[16 * q + 7] +
             f2.x * c3s[16 * q + 8] + f2.y * c3s[16 * q + 9] +
             f2.z * c3s[16 * q + 10] + f2.w * c3s[16 * q + 11] +
             f3.x * c3s[16 * q + 12] + f3.y * c3s[16 * q + 13] +
             f3.z * c3s[16 * q + 14] + f3.w * c3s[16 * q + 15];
      uint4 o0, o1;
      o0.x = pack_bf16x2(f0.x, f0.y); o0.y = pack_bf16x2(f0.z, f0.w);
      o0.z = pack_bf16x2(f1.x, f1.y); o0.w = pack_bf16x2(f1.z, f1.w);
      o1.x = pack_bf16x2(f2.x, f2.y); o1.y = pack_bf16x2(f2.z, f2.w);
      o1.z = pack_bf16x2(f3.x, f3.y); o1.w = pack_bf16x2(f3.z, f3.w);
      *(uint4*)(orow + 8 * q) = o0;
      *(uint4*)(orow + 8 * q + 4) = o1;
    }
    float z = z1g[sv] + z2g[d] + dot;
    float zp = z > 0.f ? z : ALPHAV * z;
    wbuf[e] = __expf(-zp);
    atomicAdd(&c1[sv], 1);
    atomicAdd(&h[d], 1);
  }
  __syncthreads();
  for (int i = threadIdx.x; i < 512; i += 256) hblk[(size_t)b * 512 + i] = h[i];
}

// ---------------- column scan over NB blocks: hblk[b][t] -> exclusive prefix; tot2[t] ----------------
__global__ __launch_bounds__(256) void k_colscan(int* __restrict__ hblk,
                                                 int* __restrict__ tot2) {
  __shared__ int s[256];
  int t = blockIdx.x;            // 0..511
  int tid = threadIdx.x;         // 0..255, each owns 8 blocks
  int v[8]; int tot = 0;
#pragma unroll
  for (int j = 0; j < 8; ++j) {
    int b = tid * 8 + j;
    v[j] = hblk[(size_t)b * 512 + t];
    tot += v[j];
  }
  s[tid] = tot; __syncthreads();
  for (int off = 1; off < 256; off <<= 1) {
    int tv = (tid >= off) ? s[tid - off] : 0;
    __syncthreads();
    if (tid >= off) s[tid] += tv;
    __syncthreads();
  }
  int run = s[tid] - tot;
#pragma unroll
  for (int j = 0; j < 8; ++j) {
    int b = tid * 8 + j;
    hblk[(size_t)b * 512 + t] = run;
    run += v[j];
  }
  if (tid == 255) tot2[t] = run;
}

// ---------------- scan for src counts ----------------
__global__ __launch_bounds__(256) void k_scanA(const int* __restrict__ cnt,
                                               int* __restrict__ outp,
                                               int* __restrict__ partials, int n) {
  __shared__ int s[256];
  int tid = threadIdx.x;
  int base = blockIdx.x * 2048 + tid * 8;
  int v[8]; int tot = 0;
#pragma unroll
  for (int j = 0; j < 8; ++j) { int idx = base + j; v[j] = (idx < n) ? cnt[idx] : 0; tot += v[j]; }
  s[tid] = tot; __syncthreads();
  for (int off = 1; off < 256; off <<= 1) {
    int tv = 0;
    if (tid >= off) tv = s[tid - off];
    __syncthreads();
    if (tid >= off) s[tid] += tv;
    __syncthreads();
  }
  int run = s[tid] - tot;
#pragma unroll
  for (int j = 0; j < 8; ++j) { int idx = base + j; if (idx < n) outp[idx] = run; run += v[j]; }
  if (tid == 255) partials[blockIdx.x] = s[255];
}

__global__ __launch_bounds__(512) void k_scanB(int* __restrict__ partials, int nPart,
                                               const int* __restrict__ tot2,
                                               int* __restrict__ rp2) {
  __shared__ int s[512];
  int tid = threadIdx.x;
  int v = (tid < N2V) ? tot2[tid] : 0;
  s[tid] = v; __syncthreads();
  for (int off = 1; off < 512; off <<= 1) {
    int tv = 0;
    if (tid >= off) tv = s[tid - off];
    __syncthreads();
    if (tid >= off) s[tid] += tv;
    __syncthreads();
  }
  if (tid < N2V) rp2[tid] = s[tid] - v;
  if (tid == N2V - 1) rp2[N2V] = s[tid];
  if (tid == 0) {
    int run = 0;
    for (int b = 0; b < nPart; ++b) { int t = partials[b]; partials[b] = run; run += t; }
  }
}

__global__ __launch_bounds__(256) void k_scanC(int* __restrict__ rp, int* __restrict__ cur,
                                               const int* __restrict__ partials, int n, int total) {
  int i = blockIdx.x * 256 + threadIdx.x;
  if (i < n) {
    int v = rp[i] + partials[i >> 11];
    rp[i] = v; cur[i] = v;
  }
  if (i == 0) rp[n] = total;
}

// ---------------- light scatter: CSR placement only ----------------
__global__ __launch_bounds__(256) void k_scatter(const int* __restrict__ src,
                                                 const int* __restrict__ dst,
                                                 int* __restrict__ cur1,
                                                 const int* __restrict__ hblk,
                                                 const int* __restrict__ rp2,
                                                 int* __restrict__ e1, int* __restrict__ e2) {
  __shared__ int h[512];
  __shared__ int basep[512];
  int b = blockIdx.x;
  int b0 = b * CHUNK, b1 = min(b0 + CHUNK, NEV);
  for (int i = threadIdx.x; i < 512; i += 256) {
    basep[i] = ((i < N2V) ? rp2[i] : 0) + hblk[(size_t)b * 512 + i];
    h[i] = 0;
  }
  __syncthreads();
  for (int e = b0 + threadIdx.x; e < b1; e += 256) {
    int sv = src[e], d = dst[e];
    int p = atomicAdd(&cur1[sv], 1);
    e1[p] = e;
    int loc = atomicAdd(&h[d], 1);
    e2[basep[d] + loc] = e;
  }
}

// ---------------- dst-grouped pure gather pass (bf16 ee) ----------------
__global__ __launch_bounds__(256) void k_dst(const float* __restrict__ x1,
                                             const u16* __restrict__ eeh,
                                             const float* __restrict__ wbuf,
                                             const int* __restrict__ edge_src,
                                             const int* __restrict__ rp2,
                                             const int* __restrict__ e2,
                                             float* __restrict__ acc2) {
  __shared__ float red[4][224];
  int t = blockIdx.x / CHD;
  int chunk = blockIdx.x % CHD;
  int tid = threadIdx.x, wv = tid >> 6, l = tid & 63;
  int start = rp2[t], end = rp2[t + 1];
  int n = end - start;
  int sub = chunk * 4 + wv;                                  // 0..31
  int i0 = start + (int)(((long long)n * sub) >> 5);
  int i1 = start + (int)(((long long)n * (sub + 1)) >> 5);
  float sxa = 0.f, sxb = 0.f, s3 = 0.f, rsum = 0.f;
  int p = i0;
  for (; p + 4 <= i1; p += 4) {
    int ea = e2[p], eb = e2[p + 1], ec = e2[p + 2], ed = e2[p + 3];
    float wa = wbuf[ea], wb = wbuf[eb], wc = wbuf[ec], wdv = wbuf[ed];
    int sa = edge_src[ea], sb = edge_src[eb], sc = edge_src[ec], sd = edge_src[ed];
    float eva = bf16_to_f(eeh[(size_t)ea * 64 + l]);
    float evb = bf16_to_f(eeh[(size_t)eb * 64 + l]);
    float evc = bf16_to_f(eeh[(size_t)ec * 64 + l]);
    float evd = bf16_to_f(eeh[(size_t)ed * 64 + l]);
    float xaa = x1[(size_t)sa * 128 + l], xba = x1[(size_t)sa * 128 + 64 + l];
    float xab = x1[(size_t)sb * 128 + l], xbb = x1[(size_t)sb * 128 + 64 + l];
    float xac = x1[(size_t)sc * 128 + l], xbc = x1[(size_t)sc * 128 + 64 + l];
    float xad = x1[(size_t)sd * 128 + l], xbd = x1[(size_t)sd * 128 + 64 + l];
    rsum += (wa + wb) + (wc + wdv);
    s3 += wa * eva + wb * evb + wc * evc + wdv * evd;
    sxa += wa * xaa + wb * xab + wc * xac + wdv * xad;
    sxb += wa * xba + wb * xbb + wc * xbc + wdv * xbd;
  }
  for (; p < i1; ++p) {
    int ea = e2[p];
    float wa = wbuf[ea];
    int sa = edge_src[ea];
    rsum += wa;
    s3 += wa * bf16_to_f(eeh[(size_t)ea * 64 + l]);
    sxa += wa * x1[(size_t)sa * 128 + l];
    sxb += wa * x1[(size_t)sa * 128 + 64 + l];
  }
  red[wv][l] = sxa; red[wv][64 + l] = sxb; red[wv][128 + l] = s3;
  if (l == 0) red[wv][192] = rsum;
  __syncthreads();
  if (tid < 193) {
    float v = red[0][tid] + red[1][tid] + red[2][tid] + red[3][tid];
    if (v != 0.f) atomicAdd(&acc2[t * 256 + tid], v);
  }
}

// ---------------- dst finalize ----------------
__global__ __launch_bounds__(256) void k_dst_final(const float* __restrict__ acc2,
                                                   float* __restrict__ sbuf2,
                                                   float* __restrict__ rs2) {
  int t = blockIdx.x, tid = threadIdx.x;
  float rtot = acc2[t * 256 + 192];
  float scale = rtot > 0.f ? 1.0f / rtot : 0.f;
  if (tid < 192) sbuf2[t * 192 + tid] = acc2[t * 256 + tid] * scale;
  if (tid == 192) rs2[t] = rtot;
}

// ---------------- src-grouped pure gather pass (bf16 ee) ----------------
__global__ __launch_bounds__(256) void k_src(const float* __restrict__ x2,
                                             const u16* __restrict__ eeh,
                                             const float* __restrict__ wbuf,
                                             const int* __restrict__ edge_dst,
                                             const int* __restrict__ rp1,
                                             const int* __restrict__ e1,
                                             float* __restrict__ sbuf1,
                                             float* __restrict__ rs1) {
  int wid = (blockIdx.x * 256 + threadIdx.x) >> 6;
  int l = threadIdx.x & 63;
  if (wid >= N1V) return;
  int start = rp1[wid], end = rp1[wid + 1];
  float s2a = 0.f, s2b = 0.f, s1 = 0.f, rsum = 0.f;
  int p = start;
  for (; p + 4 <= end; p += 4) {
    int ea = e1[p], eb = e1[p + 1], ec = e1[p + 2], ed = e1[p + 3];
    float wa = wbuf[ea], wb = wbuf[eb], wc = wbuf[ec], wdv = wbuf[ed];
    int da = edge_dst[ea], db = edge_dst[eb], dc = edge_dst[ec], dd = edge_dst[ed];
    float eva = bf16_to_f(eeh[(size_t)ea * 64 + l]);
    float evb = bf16_to_f(eeh[(size_t)eb * 64 + l]);
    float evc = bf16_to_f(eeh[(size_t)ec * 64 + l]);
    float evd = bf16_to_f(eeh[(size_t)ed * 64 + l]);
    float xaa = x2[(size_t)da * 128 + l], xba = x2[(size_t)da * 128 + 64 + l];
    float xab = x2[(size_t)db * 128 + l], xbb = x2[(size_t)db * 128 + 64 + l];
    float xac = x2[(size_t)dc * 128 + l], xbc = x2[(size_t)dc * 128 + 64 + l];
    float xad = x2[(size_t)dd * 128 + l], xbd = x2[(size_t)dd * 128 + 64 + l];
    rsum += (wa + wb) + (wc + wdv);
    s1 += wa * eva + wb * evb + wc * evc + wdv * evd;
    s2a += wa * xaa + wb * xab + wc * xac + wdv * xad;
    s2b += wa * xba + wb * xbb + wc * xbc + wdv * xbd;
  }
  for (; p < end; ++p) {
    int ea = e1[p];
    float wa = wbuf[ea];
    int da = edge_dst[ea];
    rsum += wa;
    s1 += wa * bf16_to_f(eeh[(size_t)ea * 64 + l]);
    s2a += wa * x2[(size_t)da * 128 + l];
    s2b += wa * x2[(size_t)da * 128 + 64 + l];
  }
  float scale = (end > start) ? 1.0f / rsum : 0.f;
  sbuf1[(size_t)wid * 192 + l] = s2a * scale;
  sbuf1[(size_t)wid * 192 + 64 + l] = s2b * scale;
  sbuf1[(size_t)wid * 192 + 128 + l] = s1 * scale;
  if (l == 0) rs1[wid] = (end > start) ? rsum : 0.f;
}

// ---------------- fused output GEMM: out = mask * elu(A[M,320] @ a^T) ----------------
__global__ __launch_bounds__(256, 4) void k_gemm(const float* __restrict__ X,
                                                 const float* __restrict__ S,
                                                 const float* __restrict__ aT,
                                                 const float* __restrict__ rs,
                                                 float* __restrict__ out,
                                                 int M, int mode) {
  __shared__ float As[32 * GP];
  __shared__ float Bs[32 * 128];
  int tid = threadIdx.x;
  int row0 = blockIdx.x * 128;
  int tm = (tid >> 4) << 3;     // 0,8,...,120
  int tn = (tid & 15) << 2;     // 0,4,...,60
  float acc[8][8];
#pragma unroll
  for (int r = 0; r < 8; ++r)
#pragma unroll
    for (int cc = 0; cc < 8; ++cc) acc[r][cc] = 0.f;

  for (int k0 = 0; k0 < 320; k0 += 32) {
    {
      const float4* bsrc = (const float4*)(aT + k0 * 128);
      float4* bdst = (float4*)Bs;
#pragma unroll
      for (int q = 0; q < 4; ++q) bdst[tid + 256 * q] = bsrc[tid + 256 * q];
    }
#pragma unroll
    for (int q = 0; q < 4; ++q) {
      int t0 = tid + 256 * q;
      int m = t0 >> 3;
      int kq = (t0 & 7) << 2;
      int gi = row0 + m;
      int p = k0 + kq;
      float4 v = make_float4(0.f, 0.f, 0.f, 0.f);
      if (gi < M) {
        const float* sp;
        if (mode == 0) sp = (p < 128) ? (X + (size_t)gi * 128 + p) : (S + (size_t)gi * 192 + (p - 128));
        else sp = (p >= 128 && p < 256) ? (X + (size_t)gi * 128 + (p - 128))
                                        : (S + (size_t)gi * 192 + (p < 128 ? p : p - 128));
        v = *(const float4*)sp;
      }
      As[(kq + 0) * GP + m] = v.x;
      As[(kq + 1) * GP + m] = v.y;
      As[(kq + 2) * GP + m] = v.z;
      As[(kq + 3) * GP + m] = v.w;
    }
    __syncthreads();
#pragma unroll 8
    for (int kk = 0; kk < 32; ++kk) {
      float4 a0 = *(const float4*)&As[kk * GP + tm];
      float4 a1 = *(const float4*)&As[kk * GP + tm + 4];
      float4 b0 = *(const float4*)&Bs[kk * 128 + tn];
      float4 b1 = *(const float4*)&Bs[kk * 128 + 64 + tn];
      float af[8] = {a0.x, a0.y, a0.z, a0.w, a1.x, a1.y, a1.z, a1.w};
      float bf[8] = {b0.x, b0.y, b0.z, b0.w, b1.x, b1.y, b1.z, b1.w};
#pragma unroll
      for (int r = 0; r < 8; ++r)
#pragma unroll
        for (int cc = 0; cc < 8; ++cc) acc[r][cc] += af[r] * bf[cc];
    }
    __syncthreads();
  }
#pragma unroll
  for (int r = 0; r < 8; ++r) {
    int gi = row0 + tm + r;
    if (gi < M) {
      float rsv = rs[gi];
      bool ok = rsv > 0.f;
      float4 o0, o1;
      float h;
      h = acc[r][0]; o0.x = ok ? (h > 0.f ? h : expm1f(h)) : 0.f;
      h = acc[r][1]; o0.y = ok ? (h > 0.f ? h : expm1f(h)) : 0.f;
      h = acc[r][2]; o0.z = ok ? (h > 0.f ? h : expm1f(h)) : 0.f;
      h = acc[r][3]; o0.w = ok ? (h > 0.f ? h : expm1f(h)) : 0.f;
      h = acc[r][4]; o1.x = ok ? (h > 0.f ? h : expm1f(h)) : 0.f;
      h = acc[r][5]; o1.y = ok ? (h > 0.f ? h : expm1f(h)) : 0.f;
      h = acc[r][6]; o1.z = ok ? (h > 0.f ? h : expm1f(h)) : 0.f;
      h = acc[r][7]; o1.w = ok ? (h > 0.f ? h : expm1f(h)) : 0.f;
      *(float4*)(out + (size_t)gi * 128 + tn) = o0;
      *(float4*)(out + (size_t)gi * 128 + 64 + tn) = o1;
    }
  }
}

// =====================================================================================

static inline size_t align_up(size_t x, size_t a) { return (x + a - 1) & ~(a - 1); }

extern "C" void kernel_launch(void* const* d_in, const int* in_sizes, int n_in,
                              void* d_out, int out_size, void* d_ws, size_t ws_size,
                              hipStream_t stream) {
  const float* x1 = (const float*)d_in[0];
  const float* x2 = (const float*)d_in[1];
  const float* ee = (const float*)d_in[2];
  const float* a = (const float*)d_in[3];
  const float* a2 = (const float*)d_in[4];
  const int* esrc = (const int*)d_in[5];
  const int* edst = (const int*)d_in[6];
  float* out = (float*)d_out;

  char* base = (char*)d_ws;
  size_t off = 0;
  auto alloc = [&](size_t bytes) -> char* {
    char* p = base + off;
    off = align_up(off + bytes, 256);
    return p;
  };
  float* c = (float*)alloc(320 * 4);
  float* z1g = (float*)alloc(N1V * 4);
  float* z2g = (float*)alloc(512 * 4);
  float* aT = (float*)alloc(320 * 128 * 4);
  int* rp1 = (int*)alloc((N1V + 1) * 4);
  int* cur1 = (int*)alloc(N1V * 4);
  int* rp2 = (int*)alloc(512 * 4);
  int* partials = (int*)alloc(64 * 4);
  int* hblk = (int*)alloc((size_t)NB * 512 * 4);   // 4 MB
  int* tot2 = (int*)alloc(512 * 4);
  int* e1 = (int*)alloc(NEV * 4);
  int* e2 = (int*)alloc(NEV * 4);
  float* wbuf = (float*)alloc(NEV * 4);
  u32* eeh = (u32*)alloc((size_t)NEV * 128);        // 128 MB (bf16 ee)
  float* rs1 = (float*)alloc(N1V * 4);
  float* rs2 = (float*)alloc(512 * 4);
  float* sbuf1 = (float*)alloc((size_t)N1V * 192 * 4);
  float* sbuf2 = (float*)alloc(512 * 192 * 4);
  float* acc2 = (float*)alloc(512 * 256 * 4);
  (void)ws_size; (void)out_size; (void)n_in; (void)in_sizes;

  hipMemsetAsync(cur1, 0, N1V * 4, stream);
  hipMemsetAsync(acc2, 0, 512 * 256 * 4, stream);

  hipLaunchKernelGGL(k_prep, dim3(162), dim3(256), 0, stream, a, a2, c, aT);
  hipLaunchKernelGGL(k_z2, dim3(125), dim3(256), 0, stream, x2, c, z2g);
  hipLaunchKernelGGL(k_z1, dim3(25000), dim3(256), 0, stream, x1, c, z1g);
  hipLaunchKernelGGL(k_histw, dim3(NB), dim3(256), 0, stream,
                     esrc, edst, ee, z1g, z2g, c, cur1, hblk, wbuf, eeh);
  hipLaunchKernelGGL(k_colscan, dim3(512), dim3(256), 0, stream, hblk, tot2);

  const int nScanBlocks = (N1V + 2047) / 2048;  // 49
  hipLaunchKernelGGL(k_scanA, dim3(nScanBlocks), dim3(256), 0, stream, cur1, rp1, partials, N1V);
  hipLaunchKernelGGL(k_scanB, dim3(1), dim3(512), 0, stream, partials, nScanBlocks, tot2, rp2);
  hipLaunchKernelGGL(k_scanC, dim3((N1V + 255) / 256), dim3(256), 0, stream, rp1, cur1, partials, N1V, NEV);
  hipLaunchKernelGGL(k_scatter, dim3(NB), dim3(256), 0, stream,
                     esrc, edst, cur1, hblk, rp2, e1, e2);

  hipLaunchKernelGGL(k_dst, dim3(N2V * CHD), dim3(256), 0, stream,
                     x1, (const u16*)eeh, wbuf, esrc, rp2, e2, acc2);
  hipLaunchKernelGGL(k_dst_final, dim3(N2V), dim3(256), 0, stream, acc2, sbuf2, rs2);

  hipLaunchKernelGGL(k_src, dim3(N1V / 4), dim3(256), 0, stream,
                     x2, (const u16*)eeh, wbuf, edst, rp1, e1, sbuf1, rs1);

  hipLaunchKernelGGL(k_gemm, dim3((N1V + 127) / 128), dim3(256), 0, stream,
                     x1, sbuf1, aT, rs1, out, N1V, 0);
  hipLaunchKernelGGL(k_gemm, dim3((N2V + 127) / 128), dim3(256), 0, stream,
                     x2, sbuf2, aT, rs2, out + (size_t)N1V * 128, N2V, 1);
}

// Round 11
// 748.924 us; speedup vs baseline: 1.0633x; 1.0633x over previous
//
#include <hip/hip_runtime.h>

#define N1V 100000
#define N2V 500
#define NEV 1000000
#define ALPHAV 0.2f
#define NB 2048       // histogram/scatter/z3 blocks
#define CHUNK 489     // ceil(NEV/NB)
#define CHD 8         // dst chunks per type
#define GP 132        // As padded stride (k-major)

typedef float f32x4 __attribute__((ext_vector_type(4)));

__device__ __forceinline__ float wave_sum(float v) {
#pragma unroll
  for (int off = 32; off > 0; off >>= 1) v += __shfl_xor(v, off, 64);
  return v;
}

// ---------------- prep: c[320] = a^T @ a_2 ; aT[p*128+j] = a[j*320+p] ----------------
__global__ __launch_bounds__(256) void k_prep(const float* __restrict__ a,
                                              const float* __restrict__ a2,
                                              float* __restrict__ c,
                                              float* __restrict__ aT) {
  int b = blockIdx.x;
  if (b < 160) {
    int id = b * 256 + threadIdx.x;          // 0..40959
    int p = id >> 7, j = id & 127;
    aT[id] = a[j * 320 + p];
  } else {
    int p = (b - 160) * 256 + threadIdx.x;   // 0..511
    if (p < 320) {
      float s = 0.f;
      for (int k = 0; k < 128; ++k) s += a2[k] * a[k * 320 + p];
      c[p] = s;
    }
  }
}

// ---------------- z2[t] = x2[t].c2 ; z1[i] = x1[i].c1 ----------------
__global__ __launch_bounds__(256) void k_z2(const float* __restrict__ x2,
                                            const float* __restrict__ c,
                                            float* __restrict__ z2g) {
  int w = (blockIdx.x * 256 + threadIdx.x) >> 6;
  int l = threadIdx.x & 63;
  if (w >= N2V) return;
  float p = x2[(size_t)w * 128 + l] * c[128 + l] + x2[(size_t)w * 128 + 64 + l] * c[192 + l];
  float s = wave_sum(p);
  if (l == 0) z2g[w] = s;
}

__global__ __launch_bounds__(256) void k_z1(const float* __restrict__ x1,
                                            const float* __restrict__ c,
                                            float* __restrict__ z1g) {
  int w = (blockIdx.x * 256 + threadIdx.x) >> 6;
  int l = threadIdx.x & 63;
  if (w >= N1V) return;
  float p = x1[(size_t)w * 128 + l] * c[l] + x1[(size_t)w * 128 + 64 + l] * c[64 + l];
  float s = wave_sum(p);
  if (l == 0) z1g[w] = s;
}

// ---------------- pure streaming w-pass: wbuf[e] = exp(-leaky(z1+z2+ee.c3)) ----------------
__global__ __launch_bounds__(256) void k_z3(const int* __restrict__ src,
                                            const int* __restrict__ dst,
                                            const float* __restrict__ ee,
                                            const float* __restrict__ z1g,
                                            const float* __restrict__ z2g,
                                            const float* __restrict__ c,
                                            float* __restrict__ wbuf) {
  __shared__ float c3s[64];
  if (threadIdx.x < 64) c3s[threadIdx.x] = c[256 + threadIdx.x];
  __syncthreads();
  int b = blockIdx.x;
  int b0 = b * CHUNK, b1 = min(b0 + CHUNK, NEV);
  for (int e = b0 + threadIdx.x; e < b1; e += 256) {
    int sv = src[e], d = dst[e];
    const f32x4* row = (const f32x4*)(ee + (size_t)e * 64);
    float d0 = 0.f, d1 = 0.f, d2 = 0.f, d3 = 0.f;
#pragma unroll
    for (int q = 0; q < 4; ++q) {
      f32x4 f0 = __builtin_nontemporal_load(row + 4 * q + 0);
      f32x4 f1 = __builtin_nontemporal_load(row + 4 * q + 1);
      f32x4 f2 = __builtin_nontemporal_load(row + 4 * q + 2);
      f32x4 f3 = __builtin_nontemporal_load(row + 4 * q + 3);
      d0 += f0.x * c3s[16 * q + 0] + f0.y * c3s[16 * q + 1] +
            f0.z * c3s[16 * q + 2] + f0.w * c3s[16 * q + 3];
      d1 += f1.x * c3s[16 * q + 4] + f1.y * c3s[16 * q + 5] +
            f1.z * c3s[16 * q + 6] + f1.w * c3s[16 * q + 7];
      d2 += f2.x * c3s[16 * q + 8] + f2.y * c3s[16 * q + 9] +
            f2.z * c3s[16 * q + 10] + f2.w * c3s[16 * q + 11];
      d3 += f3.x * c3s[16 * q + 12] + f3.y * c3s[16 * q + 13] +
            f3.z * c3s[16 * q + 14] + f3.w * c3s[16 * q + 15];
    }
    float z = z1g[sv] + z2g[d] + ((d0 + d1) + (d2 + d3));
    float zp = z > 0.f ? z : ALPHAV * z;
    wbuf[e] = __expf(-zp);
  }
}

// ---------------- histogram: global atomics for src (100K buckets), LDS for dst ----------------
__global__ __launch_bounds__(256) void k_hist(const int* __restrict__ src,
                                              const int* __restrict__ dst,
                                              int* __restrict__ c1,
                                              int* __restrict__ hblk) {
  __shared__ int h[512];
  for (int i = threadIdx.x; i < 512; i += 256) h[i] = 0;
  __syncthreads();
  int b = blockIdx.x;
  int b0 = b * CHUNK, b1 = min(b0 + CHUNK, NEV);
  for (int e = b0 + threadIdx.x; e < b1; e += 256) {
    atomicAdd(&c1[src[e]], 1);
    atomicAdd(&h[dst[e]], 1);
  }
  __syncthreads();
  for (int i = threadIdx.x; i < 512; i += 256) hblk[(size_t)b * 512 + i] = h[i];
}

// ---------------- column scan over NB blocks ----------------
__global__ __launch_bounds__(256) void k_colscan(int* __restrict__ hblk,
                                                 int* __restrict__ tot2) {
  __shared__ int s[256];
  int t = blockIdx.x;            // 0..511
  int tid = threadIdx.x;         // each owns 8 blocks
  int v[8]; int tot = 0;
#pragma unroll
  for (int j = 0; j < 8; ++j) {
    int b = tid * 8 + j;
    v[j] = hblk[(size_t)b * 512 + t];
    tot += v[j];
  }
  s[tid] = tot; __syncthreads();
  for (int off = 1; off < 256; off <<= 1) {
    int tv = (tid >= off) ? s[tid - off] : 0;
    __syncthreads();
    if (tid >= off) s[tid] += tv;
    __syncthreads();
  }
  int run = s[tid] - tot;
#pragma unroll
  for (int j = 0; j < 8; ++j) {
    int b = tid * 8 + j;
    hblk[(size_t)b * 512 + t] = run;
    run += v[j];
  }
  if (tid == 255) tot2[t] = run;
}

// ---------------- scan for src counts ----------------
__global__ __launch_bounds__(256) void k_scanA(const int* __restrict__ cnt,
                                               int* __restrict__ outp,
                                               int* __restrict__ partials, int n) {
  __shared__ int s[256];
  int tid = threadIdx.x;
  int base = blockIdx.x * 2048 + tid * 8;
  int v[8]; int tot = 0;
#pragma unroll
  for (int j = 0; j < 8; ++j) { int idx = base + j; v[j] = (idx < n) ? cnt[idx] : 0; tot += v[j]; }
  s[tid] = tot; __syncthreads();
  for (int off = 1; off < 256; off <<= 1) {
    int tv = 0;
    if (tid >= off) tv = s[tid - off];
    __syncthreads();
    if (tid >= off) s[tid] += tv;
    __syncthreads();
  }
  int run = s[tid] - tot;
#pragma unroll
  for (int j = 0; j < 8; ++j) { int idx = base + j; if (idx < n) outp[idx] = run; run += v[j]; }
  if (tid == 255) partials[blockIdx.x] = s[255];
}

__global__ __launch_bounds__(512) void k_scanB(int* __restrict__ partials, int nPart,
                                               const int* __restrict__ tot2,
                                               int* __restrict__ rp2) {
  __shared__ int s[512];
  int tid = threadIdx.x;
  int v = (tid < N2V) ? tot2[tid] : 0;
  s[tid] = v; __syncthreads();
  for (int off = 1; off < 512; off <<= 1) {
    int tv = 0;
    if (tid >= off) tv = s[tid - off];
    __syncthreads();
    if (tid >= off) s[tid] += tv;
    __syncthreads();
  }
  if (tid < N2V) rp2[tid] = s[tid] - v;
  if (tid == N2V - 1) rp2[N2V] = s[tid];
  if (tid == 0) {
    int run = 0;
    for (int b = 0; b < nPart; ++b) { int t = partials[b]; partials[b] = run; run += t; }
  }
}

__global__ __launch_bounds__(256) void k_scanC(int* __restrict__ rp, int* __restrict__ cur,
                                               const int* __restrict__ partials, int n, int total) {
  int i = blockIdx.x * 256 + threadIdx.x;
  if (i < n) {
    int v = rp[i] + partials[i >> 11];
    rp[i] = v; cur[i] = v;
  }
  if (i == 0) rp[n] = total;
}

// ---------------- light scatter: CSR placement only ----------------
__global__ __launch_bounds__(256) void k_scatter(const int* __restrict__ src,
                                                 const int* __restrict__ dst,
                                                 int* __restrict__ cur1,
                                                 const int* __restrict__ hblk,
                                                 const int* __restrict__ rp2,
                                                 int* __restrict__ e1, int* __restrict__ e2) {
  __shared__ int h[512];
  __shared__ int basep[512];
  int b = blockIdx.x;
  int b0 = b * CHUNK, b1 = min(b0 + CHUNK, NEV);
  for (int i = threadIdx.x; i < 512; i += 256) {
    basep[i] = ((i < N2V) ? rp2[i] : 0) + hblk[(size_t)b * 512 + i];
    h[i] = 0;
  }
  __syncthreads();
  for (int e = b0 + threadIdx.x; e < b1; e += 256) {
    int sv = src[e], d = dst[e];
    int p = atomicAdd(&cur1[sv], 1);
    e1[p] = e;
    int loc = atomicAdd(&h[d], 1);
    e2[basep[d] + loc] = e;
  }
}

// ---------------- dst-grouped pure gather pass ----------------
__global__ __launch_bounds__(256) void k_dst(const float* __restrict__ x1,
                                             const float* __restrict__ ee,
                                             const float* __restrict__ wbuf,
                                             const int* __restrict__ edge_src,
                                             const int* __restrict__ rp2,
                                             const int* __restrict__ e2,
                                             float* __restrict__ acc2) {
  __shared__ float red[4][224];
  int t = blockIdx.x / CHD;
  int chunk = blockIdx.x % CHD;
  int tid = threadIdx.x, wv = tid >> 6, l = tid & 63;
  int start = rp2[t], end = rp2[t + 1];
  int n = end - start;
  int sub = chunk * 4 + wv;                                  // 0..31
  int i0 = start + (int)(((long long)n * sub) >> 5);
  int i1 = start + (int)(((long long)n * (sub + 1)) >> 5);
  float sxa = 0.f, sxb = 0.f, s3 = 0.f, rsum = 0.f;
  int p = i0;
  for (; p + 4 <= i1; p += 4) {
    int ea = e2[p], eb = e2[p + 1], ec = e2[p + 2], ed = e2[p + 3];
    float wa = wbuf[ea], wb = wbuf[eb], wc = wbuf[ec], wdv = wbuf[ed];
    int sa = edge_src[ea], sb = edge_src[eb], sc = edge_src[ec], sd = edge_src[ed];
    float eva = __builtin_nontemporal_load(ee + (size_t)ea * 64 + l);
    float evb = __builtin_nontemporal_load(ee + (size_t)eb * 64 + l);
    float evc = __builtin_nontemporal_load(ee + (size_t)ec * 64 + l);
    float evd = __builtin_nontemporal_load(ee + (size_t)ed * 64 + l);
    float xaa = x1[(size_t)sa * 128 + l], xba = x1[(size_t)sa * 128 + 64 + l];
    float xab = x1[(size_t)sb * 128 + l], xbb = x1[(size_t)sb * 128 + 64 + l];
    float xac = x1[(size_t)sc * 128 + l], xbc = x1[(size_t)sc * 128 + 64 + l];
    float xad = x1[(size_t)sd * 128 + l], xbd = x1[(size_t)sd * 128 + 64 + l];
    rsum += (wa + wb) + (wc + wdv);
    s3 += wa * eva + wb * evb + wc * evc + wdv * evd;
    sxa += wa * xaa + wb * xab + wc * xac + wdv * xad;
    sxb += wa * xba + wb * xbb + wc * xbc + wdv * xbd;
  }
  for (; p < i1; ++p) {
    int ea = e2[p];
    float wa = wbuf[ea];
    int sa = edge_src[ea];
    rsum += wa;
    s3 += wa * __builtin_nontemporal_load(ee + (size_t)ea * 64 + l);
    sxa += wa * x1[(size_t)sa * 128 + l];
    sxb += wa * x1[(size_t)sa * 128 + 64 + l];
  }
  red[wv][l] = sxa; red[wv][64 + l] = sxb; red[wv][128 + l] = s3;
  if (l == 0) red[wv][192] = rsum;
  __syncthreads();
  if (tid < 193) {
    float v = red[0][tid] + red[1][tid] + red[2][tid] + red[3][tid];
    if (v != 0.f) atomicAdd(&acc2[t * 256 + tid], v);
  }
}

// ---------------- dst finalize ----------------
__global__ __launch_bounds__(256) void k_dst_final(const float* __restrict__ acc2,
                                                   float* __restrict__ sbuf2,
                                                   float* __restrict__ rs2) {
  int t = blockIdx.x, tid = threadIdx.x;
  float rtot = acc2[t * 256 + 192];
  float scale = rtot > 0.f ? 1.0f / rtot : 0.f;
  if (tid < 192) sbuf2[t * 192 + tid] = acc2[t * 256 + tid] * scale;
  if (tid == 192) rs2[t] = rtot;
}

// ---------------- src-grouped pure gather pass ----------------
__global__ __launch_bounds__(256) void k_src(const float* __restrict__ x2,
                                             const float* __restrict__ ee,
                                             const float* __restrict__ wbuf,
                                             const int* __restrict__ edge_dst,
                                             const int* __restrict__ rp1,
                                             const int* __restrict__ e1,
                                             float* __restrict__ sbuf1,
                                             float* __restrict__ rs1) {
  int wid = (blockIdx.x * 256 + threadIdx.x) >> 6;
  int l = threadIdx.x & 63;
  if (wid >= N1V) return;
  int start = rp1[wid], end = rp1[wid + 1];
  float s2a = 0.f, s2b = 0.f, s1 = 0.f, rsum = 0.f;
  int p = start;
  for (; p + 4 <= end; p += 4) {
    int ea = e1[p], eb = e1[p + 1], ec = e1[p + 2], ed = e1[p + 3];
    float wa = wbuf[ea], wb = wbuf[eb], wc = wbuf[ec], wdv = wbuf[ed];
    int da = edge_dst[ea], db = edge_dst[eb], dc = edge_dst[ec], dd = edge_dst[ed];
    float eva = __builtin_nontemporal_load(ee + (size_t)ea * 64 + l);
    float evb = __builtin_nontemporal_load(ee + (size_t)eb * 64 + l);
    float evc = __builtin_nontemporal_load(ee + (size_t)ec * 64 + l);
    float evd = __builtin_nontemporal_load(ee + (size_t)ed * 64 + l);
    float xaa = x2[(size_t)da * 128 + l], xba = x2[(size_t)da * 128 + 64 + l];
    float xab = x2[(size_t)db * 128 + l], xbb = x2[(size_t)db * 128 + 64 + l];
    float xac = x2[(size_t)dc * 128 + l], xbc = x2[(size_t)dc * 128 + 64 + l];
    float xad = x2[(size_t)dd * 128 + l], xbd = x2[(size_t)dd * 128 + 64 + l];
    rsum += (wa + wb) + (wc + wdv);
    s1 += wa * eva + wb * evb + wc * evc + wdv * evd;
    s2a += wa * xaa + wb * xab + wc * xac + wdv * xad;
    s2b += wa * xba + wb * xbb + wc * xbc + wdv * xbd;
  }
  for (; p < end; ++p) {
    int ea = e1[p];
    float wa = wbuf[ea];
    int da = edge_dst[ea];
    rsum += wa;
    s1 += wa * __builtin_nontemporal_load(ee + (size_t)ea * 64 + l);
    s2a += wa * x2[(size_t)da * 128 + l];
    s2b += wa * x2[(size_t)da * 128 + 64 + l];
  }
  float scale = (end > start) ? 1.0f / rsum : 0.f;
  sbuf1[(size_t)wid * 192 + l] = s2a * scale;
  sbuf1[(size_t)wid * 192 + 64 + l] = s2b * scale;
  sbuf1[(size_t)wid * 192 + 128 + l] = s1 * scale;
  if (l == 0) rs1[wid] = (end > start) ? rsum : 0.f;
}

// ---------------- fused output GEMM: out = mask * elu(A[M,320] @ a^T) ----------------
__global__ __launch_bounds__(256, 4) void k_gemm(const float* __restrict__ X,
                                                 const float* __restrict__ S,
                                                 const float* __restrict__ aT,
                                                 const float* __restrict__ rs,
                                                 float* __restrict__ out,
                                                 int M, int mode) {
  __shared__ float As[32 * GP];
  __shared__ float Bs[32 * 128];
  int tid = threadIdx.x;
  int row0 = blockIdx.x * 128;
  int tm = (tid >> 4) << 3;     // 0,8,...,120
  int tn = (tid & 15) << 2;     // 0,4,...,60
  float acc[8][8];
#pragma unroll
  for (int r = 0; r < 8; ++r)
#pragma unroll
    for (int cc = 0; cc < 8; ++cc) acc[r][cc] = 0.f;

  for (int k0 = 0; k0 < 320; k0 += 32) {
    {
      const float4* bsrc = (const float4*)(aT + k0 * 128);
      float4* bdst = (float4*)Bs;
#pragma unroll
      for (int q = 0; q < 4; ++q) bdst[tid + 256 * q] = bsrc[tid + 256 * q];
    }
#pragma unroll
    for (int q = 0; q < 4; ++q) {
      int t0 = tid + 256 * q;
      int m = t0 >> 3;
      int kq = (t0 & 7) << 2;
      int gi = row0 + m;
      int p = k0 + kq;
      float4 v = make_float4(0.f, 0.f, 0.f, 0.f);
      if (gi < M) {
        const float* sp;
        if (mode == 0) sp = (p < 128) ? (X + (size_t)gi * 128 + p) : (S + (size_t)gi * 192 + (p - 128));
        else sp = (p >= 128 && p < 256) ? (X + (size_t)gi * 128 + (p - 128))
                                        : (S + (size_t)gi * 192 + (p < 128 ? p : p - 128));
        v = *(const float4*)sp;
      }
      As[(kq + 0) * GP + m] = v.x;
      As[(kq + 1) * GP + m] = v.y;
      As[(kq + 2) * GP + m] = v.z;
      As[(kq + 3) * GP + m] = v.w;
    }
    __syncthreads();
#pragma unroll 8
    for (int kk = 0; kk < 32; ++kk) {
      float4 a0 = *(const float4*)&As[kk * GP + tm];
      float4 a1 = *(const float4*)&As[kk * GP + tm + 4];
      float4 b0 = *(const float4*)&Bs[kk * 128 + tn];
      float4 b1 = *(const float4*)&Bs[kk * 128 + 64 + tn];
      float af[8] = {a0.x, a0.y, a0.z, a0.w, a1.x, a1.y, a1.z, a1.w};
      float bf[8] = {b0.x, b0.y, b0.z, b0.w, b1.x, b1.y, b1.z, b1.w};
#pragma unroll
      for (int r = 0; r < 8; ++r)
#pragma unroll
        for (int cc = 0; cc < 8; ++cc) acc[r][cc] += af[r] * bf[cc];
    }
    __syncthreads();
  }
#pragma unroll
  for (int r = 0; r < 8; ++r) {
    int gi = row0 + tm + r;
    if (gi < M) {
      float rsv = rs[gi];
      bool ok = rsv > 0.f;
      float4 o0, o1;
      float h;
      h = acc[r][0]; o0.x = ok ? (h > 0.f ? h : expm1f(h)) : 0.f;
      h = acc[r][1]; o0.y = ok ? (h > 0.f ? h : expm1f(h)) : 0.f;
      h = acc[r][2]; o0.z = ok ? (h > 0.f ? h : expm1f(h)) : 0.f;
      h = acc[r][3]; o0.w = ok ? (h > 0.f ? h : expm1f(h)) : 0.f;
      h = acc[r][4]; o1.x = ok ? (h > 0.f ? h : expm1f(h)) : 0.f;
      h = acc[r][5]; o1.y = ok ? (h > 0.f ? h : expm1f(h)) : 0.f;
      h = acc[r][6]; o1.z = ok ? (h > 0.f ? h : expm1f(h)) : 0.f;
      h = acc[r][7]; o1.w = ok ? (h > 0.f ? h : expm1f(h)) : 0.f;
      *(float4*)(out + (size_t)gi * 128 + tn) = o0;
      *(float4*)(out + (size_t)gi * 128 + 64 + tn) = o1;
    }
  }
}

// =====================================================================================

static inline size_t align_up(size_t x, size_t a) { return (x + a - 1) & ~(a - 1); }

extern "C" void kernel_launch(void* const* d_in, const int* in_sizes, int n_in,
                              void* d_out, int out_size, void* d_ws, size_t ws_size,
                              hipStream_t stream) {
  const float* x1 = (const float*)d_in[0];
  const float* x2 = (const float*)d_in[1];
  const float* ee = (const float*)d_in[2];
  const float* a = (const float*)d_in[3];
  const float* a2 = (const float*)d_in[4];
  const int* esrc = (const int*)d_in[5];
  const int* edst = (const int*)d_in[6];
  float* out = (float*)d_out;

  char* base = (char*)d_ws;
  size_t off = 0;
  auto alloc = [&](size_t bytes) -> char* {
    char* p = base + off;
    off = align_up(off + bytes, 256);
    return p;
  };
  float* c = (float*)alloc(320 * 4);
  float* z1g = (float*)alloc(N1V * 4);
  float* z2g = (float*)alloc(512 * 4);
  float* aT = (float*)alloc(320 * 128 * 4);
  int* rp1 = (int*)alloc((N1V + 1) * 4);
  int* cur1 = (int*)alloc(N1V * 4);
  int* rp2 = (int*)alloc(512 * 4);
  int* partials = (int*)alloc(64 * 4);
  int* hblk = (int*)alloc((size_t)NB * 512 * 4);   // 4 MB
  int* tot2 = (int*)alloc(512 * 4);
  int* e1 = (int*)alloc(NEV * 4);
  int* e2 = (int*)alloc(NEV * 4);
  float* wbuf = (float*)alloc(NEV * 4);
  float* rs1 = (float*)alloc(N1V * 4);
  float* rs2 = (float*)alloc(512 * 4);
  float* sbuf1 = (float*)alloc((size_t)N1V * 192 * 4);
  float* sbuf2 = (float*)alloc(512 * 192 * 4);
  float* acc2 = (float*)alloc(512 * 256 * 4);
  (void)ws_size; (void)out_size; (void)n_in; (void)in_sizes;

  hipMemsetAsync(cur1, 0, N1V * 4, stream);
  hipMemsetAsync(acc2, 0, 512 * 256 * 4, stream);

  hipLaunchKernelGGL(k_prep, dim3(162), dim3(256), 0, stream, a, a2, c, aT);
  hipLaunchKernelGGL(k_z2, dim3(125), dim3(256), 0, stream, x2, c, z2g);
  hipLaunchKernelGGL(k_z1, dim3(25000), dim3(256), 0, stream, x1, c, z1g);
  hipLaunchKernelGGL(k_hist, dim3(NB), dim3(256), 0, stream, esrc, edst, cur1, hblk);
  hipLaunchKernelGGL(k_z3, dim3(NB), dim3(256), 0, stream,
                     esrc, edst, ee, z1g, z2g, c, wbuf);
  hipLaunchKernelGGL(k_colscan, dim3(512), dim3(256), 0, stream, hblk, tot2);

  const int nScanBlocks = (N1V + 2047) / 2048;  // 49
  hipLaunchKernelGGL(k_scanA, dim3(nScanBlocks), dim3(256), 0, stream, cur1, rp1, partials, N1V);
  hipLaunchKernelGGL(k_scanB, dim3(1), dim3(512), 0, stream, partials, nScanBlocks, tot2, rp2);
  hipLaunchKernelGGL(k_scanC, dim3((N1V + 255) / 256), dim3(256), 0, stream, rp1, cur1, partials, N1V, NEV);
  hipLaunchKernelGGL(k_scatter, dim3(NB), dim3(256), 0, stream,
                     esrc, edst, cur1, hblk, rp2, e1, e2);

  hipLaunchKernelGGL(k_dst, dim3(N2V * CHD), dim3(256), 0, stream,
                     x1, ee, wbuf, esrc, rp2, e2, acc2);
  hipLaunchKernelGGL(k_dst_final, dim3(N2V), dim3(256), 0, stream, acc2, sbuf2, rs2);

  hipLaunchKernelGGL(k_src, dim3(N1V / 4), dim3(256), 0, stream,
                     x2, ee, wbuf, edst, rp1, e1, sbuf1, rs1);

  hipLaunchKernelGGL(k_gemm, dim3((N1V + 127) / 128), dim3(256), 0, stream,
                     x1, sbuf1, aT, rs1, out, N1V, 0);
  hipLaunchKernelGGL(k_gemm, dim3((N2V + 127) / 128), dim3(256), 0, stream,
                     x2, sbuf2, aT, rs2, out + (size_t)N1V * 128, N2V, 1);
}

// Round 12
// 747.462 us; speedup vs baseline: 1.0654x; 1.0020x over previous
//
#include <hip/hip_runtime.h>

#define N1V 100000
#define N2V 500
#define NEV 1000000
#define ALPHAV 0.2f
#define NB 2048       // histogram/scatter blocks
#define CHUNK 489     // ceil(NEV/NB)
#define CHD 8         // dst chunks per type
#define GP 132        // As padded stride (k-major)

typedef float f32x4 __attribute__((ext_vector_type(4)));

__device__ __forceinline__ float wave_sum(float v) {
#pragma unroll
  for (int off = 32; off > 0; off >>= 1) v += __shfl_xor(v, off, 64);
  return v;
}

// ---------------- prep: c[320] = a^T @ a_2 ; aT[p*128+j] = a[j*320+p] ----------------
__global__ __launch_bounds__(256) void k_prep(const float* __restrict__ a,
                                              const float* __restrict__ a2,
                                              float* __restrict__ c,
                                              float* __restrict__ aT) {
  int b = blockIdx.x;
  if (b < 160) {
    int id = b * 256 + threadIdx.x;          // 0..40959
    int p = id >> 7, j = id & 127;
    aT[id] = a[j * 320 + p];
  } else {
    int p = (b - 160) * 256 + threadIdx.x;   // 0..511
    if (p < 320) {
      float s = 0.f;
      for (int k = 0; k < 128; ++k) s += a2[k] * a[k * 320 + p];
      c[p] = s;
    }
  }
}

// ---------------- z2[t] = x2[t].c2 ; z1[i] = x1[i].c1 ----------------
__global__ __launch_bounds__(256) void k_z2(const float* __restrict__ x2,
                                            const float* __restrict__ c,
                                            float* __restrict__ z2g) {
  int w = (blockIdx.x * 256 + threadIdx.x) >> 6;
  int l = threadIdx.x & 63;
  if (w >= N2V) return;
  float p = x2[(size_t)w * 128 + l] * c[128 + l] + x2[(size_t)w * 128 + 64 + l] * c[192 + l];
  float s = wave_sum(p);
  if (l == 0) z2g[w] = s;
}

__global__ __launch_bounds__(256) void k_z1(const float* __restrict__ x1,
                                            const float* __restrict__ c,
                                            float* __restrict__ z1g) {
  int w = (blockIdx.x * 256 + threadIdx.x) >> 6;
  int l = threadIdx.x & 63;
  if (w >= N1V) return;
  float p = x1[(size_t)w * 128 + l] * c[l] + x1[(size_t)w * 128 + 64 + l] * c[64 + l];
  float s = wave_sum(p);
  if (l == 0) z1g[w] = s;
}

// ---------------- fused linear pass: histograms + w (NO transcode) ----------------
__global__ __launch_bounds__(256) void k_histw(const int* __restrict__ src,
                                               const int* __restrict__ dst,
                                               const float* __restrict__ ee,
                                               const float* __restrict__ z1g,
                                               const float* __restrict__ z2g,
                                               const float* __restrict__ c,
                                               int* __restrict__ c1,
                                               int* __restrict__ hblk,
                                               float* __restrict__ wbuf) {
  __shared__ int h[512];
  __shared__ float c3s[64];
  for (int i = threadIdx.x; i < 512; i += 256) h[i] = 0;
  if (threadIdx.x < 64) c3s[threadIdx.x] = c[256 + threadIdx.x];
  __syncthreads();
  int b = blockIdx.x;
  int b0 = b * CHUNK, b1 = min(b0 + CHUNK, NEV);
  for (int e = b0 + threadIdx.x; e < b1; e += 256) {
    int sv = src[e], d = dst[e];
    const f32x4* row = (const f32x4*)(ee + (size_t)e * 64);
    float d0 = 0.f, d1 = 0.f, d2 = 0.f, d3 = 0.f;
#pragma unroll
    for (int q = 0; q < 4; ++q) {
      f32x4 f0 = __builtin_nontemporal_load(row + 4 * q + 0);
      f32x4 f1 = __builtin_nontemporal_load(row + 4 * q + 1);
      f32x4 f2 = __builtin_nontemporal_load(row + 4 * q + 2);
      f32x4 f3 = __builtin_nontemporal_load(row + 4 * q + 3);
      d0 += f0.x * c3s[16 * q + 0] + f0.y * c3s[16 * q + 1] +
            f0.z * c3s[16 * q + 2] + f0.w * c3s[16 * q + 3];
      d1 += f1.x * c3s[16 * q + 4] + f1.y * c3s[16 * q + 5] +
            f1.z * c3s[16 * q + 6] + f1.w * c3s[16 * q + 7];
      d2 += f2.x * c3s[16 * q + 8] + f2.y * c3s[16 * q + 9] +
            f2.z * c3s[16 * q + 10] + f2.w * c3s[16 * q + 11];
      d3 += f3.x * c3s[16 * q + 12] + f3.y * c3s[16 * q + 13] +
            f3.z * c3s[16 * q + 14] + f3.w * c3s[16 * q + 15];
    }
    float z = z1g[sv] + z2g[d] + ((d0 + d1) + (d2 + d3));
    float zp = z > 0.f ? z : ALPHAV * z;
    wbuf[e] = __expf(-zp);
    atomicAdd(&c1[sv], 1);
    atomicAdd(&h[d], 1);
  }
  __syncthreads();
  for (int i = threadIdx.x; i < 512; i += 256) hblk[(size_t)b * 512 + i] = h[i];
}

// ---------------- column scan over NB blocks ----------------
__global__ __launch_bounds__(256) void k_colscan(int* __restrict__ hblk,
                                                 int* __restrict__ tot2) {
  __shared__ int s[256];
  int t = blockIdx.x;            // 0..511
  int tid = threadIdx.x;         // each owns 8 blocks
  int v[8]; int tot = 0;
#pragma unroll
  for (int j = 0; j < 8; ++j) {
    int b = tid * 8 + j;
    v[j] = hblk[(size_t)b * 512 + t];
    tot += v[j];
  }
  s[tid] = tot; __syncthreads();
  for (int off = 1; off < 256; off <<= 1) {
    int tv = (tid >= off) ? s[tid - off] : 0;
    __syncthreads();
    if (tid >= off) s[tid] += tv;
    __syncthreads();
  }
  int run = s[tid] - tot;
#pragma unroll
  for (int j = 0; j < 8; ++j) {
    int b = tid * 8 + j;
    hblk[(size_t)b * 512 + t] = run;
    run += v[j];
  }
  if (tid == 255) tot2[t] = run;
}

// ---------------- scan for src counts ----------------
__global__ __launch_bounds__(256) void k_scanA(const int* __restrict__ cnt,
                                               int* __restrict__ outp,
                                               int* __restrict__ partials, int n) {
  __shared__ int s[256];
  int tid = threadIdx.x;
  int base = blockIdx.x * 2048 + tid * 8;
  int v[8]; int tot = 0;
#pragma unroll
  for (int j = 0; j < 8; ++j) { int idx = base + j; v[j] = (idx < n) ? cnt[idx] : 0; tot += v[j]; }
  s[tid] = tot; __syncthreads();
  for (int off = 1; off < 256; off <<= 1) {
    int tv = 0;
    if (tid >= off) tv = s[tid - off];
    __syncthreads();
    if (tid >= off) s[tid] += tv;
    __syncthreads();
  }
  int run = s[tid] - tot;
#pragma unroll
  for (int j = 0; j < 8; ++j) { int idx = base + j; if (idx < n) outp[idx] = run; run += v[j]; }
  if (tid == 255) partials[blockIdx.x] = s[255];
}

__global__ __launch_bounds__(512) void k_scanB(int* __restrict__ partials, int nPart,
                                               const int* __restrict__ tot2,
                                               int* __restrict__ rp2) {
  __shared__ int s[512];
  int tid = threadIdx.x;
  int v = (tid < N2V) ? tot2[tid] : 0;
  s[tid] = v; __syncthreads();
  for (int off = 1; off < 512; off <<= 1) {
    int tv = 0;
    if (tid >= off) tv = s[tid - off];
    __syncthreads();
    if (tid >= off) s[tid] += tv;
    __syncthreads();
  }
  if (tid < N2V) rp2[tid] = s[tid] - v;
  if (tid == N2V - 1) rp2[N2V] = s[tid];
  if (tid == 0) {
    int run = 0;
    for (int b = 0; b < nPart; ++b) { int t = partials[b]; partials[b] = run; run += t; }
  }
}

__global__ __launch_bounds__(256) void k_scanC(int* __restrict__ rp, int* __restrict__ cur,
                                               const int* __restrict__ partials, int n, int total) {
  int i = blockIdx.x * 256 + threadIdx.x;
  if (i < n) {
    int v = rp[i] + partials[i >> 11];
    rp[i] = v; cur[i] = v;
  }
  if (i == 0) rp[n] = total;
}

// ---------------- light scatter: CSR placement only ----------------
__global__ __launch_bounds__(256) void k_scatter(const int* __restrict__ src,
                                                 const int* __restrict__ dst,
                                                 int* __restrict__ cur1,
                                                 const int* __restrict__ hblk,
                                                 const int* __restrict__ rp2,
                                                 int* __restrict__ e1, int* __restrict__ e2) {
  __shared__ int h[512];
  __shared__ int basep[512];
  int b = blockIdx.x;
  int b0 = b * CHUNK, b1 = min(b0 + CHUNK, NEV);
  for (int i = threadIdx.x; i < 512; i += 256) {
    basep[i] = ((i < N2V) ? rp2[i] : 0) + hblk[(size_t)b * 512 + i];
    h[i] = 0;
  }
  __syncthreads();
  for (int e = b0 + threadIdx.x; e < b1; e += 256) {
    int sv = src[e], d = dst[e];
    int p = atomicAdd(&cur1[sv], 1);
    e1[p] = e;
    int loc = atomicAdd(&h[d], 1);
    e2[basep[d] + loc] = e;
  }
}

// ---------------- dst-grouped pure gather pass ----------------
__global__ __launch_bounds__(256) void k_dst(const float* __restrict__ x1,
                                             const float* __restrict__ ee,
                                             const float* __restrict__ wbuf,
                                             const int* __restrict__ edge_src,
                                             const int* __restrict__ rp2,
                                             const int* __restrict__ e2,
                                             float* __restrict__ acc2) {
  __shared__ float red[4][224];
  int t = blockIdx.x / CHD;
  int chunk = blockIdx.x % CHD;
  int tid = threadIdx.x, wv = tid >> 6, l = tid & 63;
  int start = rp2[t], end = rp2[t + 1];
  int n = end - start;
  int sub = chunk * 4 + wv;                                  // 0..31
  int i0 = start + (int)(((long long)n * sub) >> 5);
  int i1 = start + (int)(((long long)n * (sub + 1)) >> 5);
  float sxa = 0.f, sxb = 0.f, s3 = 0.f, rsum = 0.f;
  int p = i0;
  for (; p + 4 <= i1; p += 4) {
    int ea = e2[p], eb = e2[p + 1], ec = e2[p + 2], ed = e2[p + 3];
    float wa = wbuf[ea], wb = wbuf[eb], wc = wbuf[ec], wdv = wbuf[ed];
    int sa = edge_src[ea], sb = edge_src[eb], sc = edge_src[ec], sd = edge_src[ed];
    float eva = __builtin_nontemporal_load(ee + (size_t)ea * 64 + l);
    float evb = __builtin_nontemporal_load(ee + (size_t)eb * 64 + l);
    float evc = __builtin_nontemporal_load(ee + (size_t)ec * 64 + l);
    float evd = __builtin_nontemporal_load(ee + (size_t)ed * 64 + l);
    float xaa = x1[(size_t)sa * 128 + l], xba = x1[(size_t)sa * 128 + 64 + l];
    float xab = x1[(size_t)sb * 128 + l], xbb = x1[(size_t)sb * 128 + 64 + l];
    float xac = x1[(size_t)sc * 128 + l], xbc = x1[(size_t)sc * 128 + 64 + l];
    float xad = x1[(size_t)sd * 128 + l], xbd = x1[(size_t)sd * 128 + 64 + l];
    rsum += (wa + wb) + (wc + wdv);
    s3 += wa * eva + wb * evb + wc * evc + wdv * evd;
    sxa += wa * xaa + wb * xab + wc * xac + wdv * xad;
    sxb += wa * xba + wb * xbb + wc * xbc + wdv * xbd;
  }
  for (; p < i1; ++p) {
    int ea = e2[p];
    float wa = wbuf[ea];
    int sa = edge_src[ea];
    rsum += wa;
    s3 += wa * __builtin_nontemporal_load(ee + (size_t)ea * 64 + l);
    sxa += wa * x1[(size_t)sa * 128 + l];
    sxb += wa * x1[(size_t)sa * 128 + 64 + l];
  }
  red[wv][l] = sxa; red[wv][64 + l] = sxb; red[wv][128 + l] = s3;
  if (l == 0) red[wv][192] = rsum;
  __syncthreads();
  if (tid < 193) {
    float v = red[0][tid] + red[1][tid] + red[2][tid] + red[3][tid];
    if (v != 0.f) atomicAdd(&acc2[t * 256 + tid], v);
  }
}

// ---------------- dst finalize ----------------
__global__ __launch_bounds__(256) void k_dst_final(const float* __restrict__ acc2,
                                                   float* __restrict__ sbuf2,
                                                   float* __restrict__ rs2) {
  int t = blockIdx.x, tid = threadIdx.x;
  float rtot = acc2[t * 256 + 192];
  float scale = rtot > 0.f ? 1.0f / rtot : 0.f;
  if (tid < 192) sbuf2[t * 192 + tid] = acc2[t * 256 + tid] * scale;
  if (tid == 192) rs2[t] = rtot;
}

// ---------------- src-grouped pure gather pass ----------------
__global__ __launch_bounds__(256) void k_src(const float* __restrict__ x2,
                                             const float* __restrict__ ee,
                                             const float* __restrict__ wbuf,
                                             const int* __restrict__ edge_dst,
                                             const int* __restrict__ rp1,
                                             const int* __restrict__ e1,
                                             float* __restrict__ sbuf1,
                                             float* __restrict__ rs1) {
  int wid = (blockIdx.x * 256 + threadIdx.x) >> 6;
  int l = threadIdx.x & 63;
  if (wid >= N1V) return;
  int start = rp1[wid], end = rp1[wid + 1];
  float s2a = 0.f, s2b = 0.f, s1 = 0.f, rsum = 0.f;
  int p = start;
  for (; p + 4 <= end; p += 4) {
    int ea = e1[p], eb = e1[p + 1], ec = e1[p + 2], ed = e1[p + 3];
    float wa = wbuf[ea], wb = wbuf[eb], wc = wbuf[ec], wdv = wbuf[ed];
    int da = edge_dst[ea], db = edge_dst[eb], dc = edge_dst[ec], dd = edge_dst[ed];
    float eva = __builtin_nontemporal_load(ee + (size_t)ea * 64 + l);
    float evb = __builtin_nontemporal_load(ee + (size_t)eb * 64 + l);
    float evc = __builtin_nontemporal_load(ee + (size_t)ec * 64 + l);
    float evd = __builtin_nontemporal_load(ee + (size_t)ed * 64 + l);
    float xaa = x2[(size_t)da * 128 + l], xba = x2[(size_t)da * 128 + 64 + l];
    float xab = x2[(size_t)db * 128 + l], xbb = x2[(size_t)db * 128 + 64 + l];
    float xac = x2[(size_t)dc * 128 + l], xbc = x2[(size_t)dc * 128 + 64 + l];
    float xad = x2[(size_t)dd * 128 + l], xbd = x2[(size_t)dd * 128 + 64 + l];
    rsum += (wa + wb) + (wc + wdv);
    s1 += wa * eva + wb * evb + wc * evc + wdv * evd;
    s2a += wa * xaa + wb * xab + wc * xac + wdv * xad;
    s2b += wa * xba + wb * xbb + wc * xbc + wdv * xbd;
  }
  for (; p < end; ++p) {
    int ea = e1[p];
    float wa = wbuf[ea];
    int da = edge_dst[ea];
    rsum += wa;
    s1 += wa * __builtin_nontemporal_load(ee + (size_t)ea * 64 + l);
    s2a += wa * x2[(size_t)da * 128 + l];
    s2b += wa * x2[(size_t)da * 128 + 64 + l];
  }
  float scale = (end > start) ? 1.0f / rsum : 0.f;
  sbuf1[(size_t)wid * 192 + l] = s2a * scale;
  sbuf1[(size_t)wid * 192 + 64 + l] = s2b * scale;
  sbuf1[(size_t)wid * 192 + 128 + l] = s1 * scale;
  if (l == 0) rs1[wid] = (end > start) ? rsum : 0.f;
}

// ---------------- fused output GEMM, register-prefetch pipelined ----------------
__global__ __launch_bounds__(256, 4) void k_gemm(const float* __restrict__ X,
                                                 const float* __restrict__ S,
                                                 const float* __restrict__ aT,
                                                 const float* __restrict__ rs,
                                                 float* __restrict__ out,
                                                 int M, int mode) {
  __shared__ float As[32 * GP];
  __shared__ float Bs[32 * 128];
  int tid = threadIdx.x;
  int row0 = blockIdx.x * 128;
  int tm = (tid >> 4) << 3;     // 0,8,...,120
  int tn = (tid & 15) << 2;     // 0,4,...,60
  float acc[8][8];
#pragma unroll
  for (int r = 0; r < 8; ++r)
#pragma unroll
    for (int cc = 0; cc < 8; ++cc) acc[r][cc] = 0.f;

  f32x4 bA[4], bB[4];
  auto loadTile = [&](int k0) {
    const f32x4* bsrc = (const f32x4*)(aT + k0 * 128);
#pragma unroll
    for (int q = 0; q < 4; ++q) bB[q] = bsrc[tid + 256 * q];
#pragma unroll
    for (int q = 0; q < 4; ++q) {
      int t0 = tid + 256 * q;
      int m = t0 >> 3;
      int kq = (t0 & 7) << 2;
      int gi = row0 + m;
      int p = k0 + kq;
      f32x4 v = {0.f, 0.f, 0.f, 0.f};
      if (gi < M) {
        const float* sp;
        if (mode == 0) sp = (p < 128) ? (X + (size_t)gi * 128 + p) : (S + (size_t)gi * 192 + (p - 128));
        else sp = (p >= 128 && p < 256) ? (X + (size_t)gi * 128 + (p - 128))
                                        : (S + (size_t)gi * 192 + (p < 128 ? p : p - 128));
        v = *(const f32x4*)sp;
      }
      bA[q] = v;
    }
  };

  loadTile(0);
  for (int it = 0; it < 10; ++it) {
    __syncthreads();   // previous compute done before LDS overwrite (no-op on it=0)
    {
      f32x4* bdst = (f32x4*)Bs;
#pragma unroll
      for (int q = 0; q < 4; ++q) bdst[tid + 256 * q] = bB[q];
#pragma unroll
      for (int q = 0; q < 4; ++q) {
        int t0 = tid + 256 * q;
        int m = t0 >> 3;
        int kq = (t0 & 7) << 2;
        As[(kq + 0) * GP + m] = bA[q].x;
        As[(kq + 1) * GP + m] = bA[q].y;
        As[(kq + 2) * GP + m] = bA[q].z;
        As[(kq + 3) * GP + m] = bA[q].w;
      }
    }
    __syncthreads();
    if (it < 9) loadTile((it + 1) * 32);   // prefetch; waitcnt lands after compute
#pragma unroll 8
    for (int kk = 0; kk < 32; ++kk) {
      float4 a0 = *(const float4*)&As[kk * GP + tm];
      float4 a1 = *(const float4*)&As[kk * GP + tm + 4];
      float4 b0 = *(const float4*)&Bs[kk * 128 + tn];
      float4 b1 = *(const float4*)&Bs[kk * 128 + 64 + tn];
      float af[8] = {a0.x, a0.y, a0.z, a0.w, a1.x, a1.y, a1.z, a1.w};
      float bf[8] = {b0.x, b0.y, b0.z, b0.w, b1.x, b1.y, b1.z, b1.w};
#pragma unroll
      for (int r = 0; r < 8; ++r)
#pragma unroll
        for (int cc = 0; cc < 8; ++cc) acc[r][cc] += af[r] * bf[cc];
    }
  }
#pragma unroll
  for (int r = 0; r < 8; ++r) {
    int gi = row0 + tm + r;
    if (gi < M) {
      float rsv = rs[gi];
      bool ok = rsv > 0.f;
      float4 o0, o1;
      float h;
      h = acc[r][0]; o0.x = ok ? (h > 0.f ? h : expm1f(h)) : 0.f;
      h = acc[r][1]; o0.y = ok ? (h > 0.f ? h : expm1f(h)) : 0.f;
      h = acc[r][2]; o0.z = ok ? (h > 0.f ? h : expm1f(h)) : 0.f;
      h = acc[r][3]; o0.w = ok ? (h > 0.f ? h : expm1f(h)) : 0.f;
      h = acc[r][4]; o1.x = ok ? (h > 0.f ? h : expm1f(h)) : 0.f;
      h = acc[r][5]; o1.y = ok ? (h > 0.f ? h : expm1f(h)) : 0.f;
      h = acc[r][6]; o1.z = ok ? (h > 0.f ? h : expm1f(h)) : 0.f;
      h = acc[r][7]; o1.w = ok ? (h > 0.f ? h : expm1f(h)) : 0.f;
      *(float4*)(out + (size_t)gi * 128 + tn) = o0;
      *(float4*)(out + (size_t)gi * 128 + 64 + tn) = o1;
    }
  }
}

// =====================================================================================

static inline size_t align_up(size_t x, size_t a) { return (x + a - 1) & ~(a - 1); }

extern "C" void kernel_launch(void* const* d_in, const int* in_sizes, int n_in,
                              void* d_out, int out_size, void* d_ws, size_t ws_size,
                              hipStream_t stream) {
  const float* x1 = (const float*)d_in[0];
  const float* x2 = (const float*)d_in[1];
  const float* ee = (const float*)d_in[2];
  const float* a = (const float*)d_in[3];
  const float* a2 = (const float*)d_in[4];
  const int* esrc = (const int*)d_in[5];
  const int* edst = (const int*)d_in[6];
  float* out = (float*)d_out;

  char* base = (char*)d_ws;
  size_t off = 0;
  auto alloc = [&](size_t bytes) -> char* {
    char* p = base + off;
    off = align_up(off + bytes, 256);
    return p;
  };
  float* c = (float*)alloc(320 * 4);
  float* z1g = (float*)alloc(N1V * 4);
  float* z2g = (float*)alloc(512 * 4);
  float* aT = (float*)alloc(320 * 128 * 4);
  int* rp1 = (int*)alloc((N1V + 1) * 4);
  int* cur1 = (int*)alloc(N1V * 4);
  int* rp2 = (int*)alloc(512 * 4);
  int* partials = (int*)alloc(64 * 4);
  int* hblk = (int*)alloc((size_t)NB * 512 * 4);   // 4 MB
  int* tot2 = (int*)alloc(512 * 4);
  int* e1 = (int*)alloc(NEV * 4);
  int* e2 = (int*)alloc(NEV * 4);
  float* wbuf = (float*)alloc(NEV * 4);
  float* rs1 = (float*)alloc(N1V * 4);
  float* rs2 = (float*)alloc(512 * 4);
  float* sbuf1 = (float*)alloc((size_t)N1V * 192 * 4);
  float* sbuf2 = (float*)alloc(512 * 192 * 4);
  float* acc2 = (float*)alloc(512 * 256 * 4);
  (void)ws_size; (void)out_size; (void)n_in; (void)in_sizes;

  hipMemsetAsync(cur1, 0, N1V * 4, stream);
  hipMemsetAsync(acc2, 0, 512 * 256 * 4, stream);

  hipLaunchKernelGGL(k_prep, dim3(162), dim3(256), 0, stream, a, a2, c, aT);
  hipLaunchKernelGGL(k_z2, dim3(125), dim3(256), 0, stream, x2, c, z2g);
  hipLaunchKernelGGL(k_z1, dim3(25000), dim3(256), 0, stream, x1, c, z1g);
  hipLaunchKernelGGL(k_histw, dim3(NB), dim3(256), 0, stream,
                     esrc, edst, ee, z1g, z2g, c, cur1, hblk, wbuf);
  hipLaunchKernelGGL(k_colscan, dim3(512), dim3(256), 0, stream, hblk, tot2);

  const int nScanBlocks = (N1V + 2047) / 2048;  // 49
  hipLaunchKernelGGL(k_scanA, dim3(nScanBlocks), dim3(256), 0, stream, cur1, rp1, partials, N1V);
  hipLaunchKernelGGL(k_scanB, dim3(1), dim3(512), 0, stream, partials, nScanBlocks, tot2, rp2);
  hipLaunchKernelGGL(k_scanC, dim3((N1V + 255) / 256), dim3(256), 0, stream, rp1, cur1, partials, N1V, NEV);
  hipLaunchKernelGGL(k_scatter, dim3(NB), dim3(256), 0, stream,
                     esrc, edst, cur1, hblk, rp2, e1, e2);

  hipLaunchKernelGGL(k_dst, dim3(N2V * CHD), dim3(256), 0, stream,
                     x1, ee, wbuf, esrc, rp2, e2, acc2);
  hipLaunchKernelGGL(k_dst_final, dim3(N2V), dim3(256), 0, stream, acc2, sbuf2, rs2);

  hipLaunchKernelGGL(k_src, dim3(N1V / 4), dim3(256), 0, stream,
                     x2, ee, wbuf, edst, rp1, e1, sbuf1, rs1);

  hipLaunchKernelGGL(k_gemm, dim3((N1V + 127) / 128), dim3(256), 0, stream,
                     x1, sbuf1, aT, rs1, out, N1V, 0);
  hipLaunchKernelGGL(k_gemm, dim3((N2V + 127) / 128), dim3(256), 0, stream,
                     x2, sbuf2, aT, rs2, out + (size_t)N1V * 128, N2V, 1);
}

// Round 13
// 564.097 us; speedup vs baseline: 1.4117x; 1.3251x over previous
//
#include <hip/hip_runtime.h>

#define N1V 100000
#define N2V 500
#define NEV 1000000
#define ALPHAV 0.2f
#define NB 2048       // histogram/scatter blocks
#define CHUNK 489     // ceil(NEV/NB)
#define CHD 8         // dst chunks per type

typedef float f32x4 __attribute__((ext_vector_type(4)));
typedef unsigned int u32;
using bf16x8 = __attribute__((ext_vector_type(8))) short;   // 8 bf16 (4 VGPRs)
using f32x4v = __attribute__((ext_vector_type(4))) float;

__device__ __forceinline__ float wave_sum(float v) {
#pragma unroll
  for (int off = 32; off > 0; off >>= 1) v += __shfl_xor(v, off, 64);
  return v;
}

__device__ __forceinline__ u32 pack_bf16x2(float a, float b) {
  u32 ua = __float_as_uint(a), ub = __float_as_uint(b);
  u32 ra = (ua + 0x7FFFu + ((ua >> 16) & 1u)) >> 16;
  u32 rb = (ub + 0x7FFFu + ((ub >> 16) & 1u)) >> 16;
  return ra | (rb << 16);
}

// ---------------- prep: c[320] = a^T @ a_2 ----------------
__global__ __launch_bounds__(256) void k_prep(const float* __restrict__ a,
                                              const float* __restrict__ a2,
                                              float* __restrict__ c) {
  int p = blockIdx.x * 256 + threadIdx.x;
  if (p < 320) {
    float s = 0.f;
    for (int k = 0; k < 128; ++k) s += a2[k] * a[k * 320 + p];
    c[p] = s;
  }
}

// ---------------- bf16 conversions: x1, a, x2 ----------------
__global__ __launch_bounds__(256) void k_conv(const float* __restrict__ x1,
                                              const float* __restrict__ x2,
                                              const float* __restrict__ a,
                                              u32* __restrict__ x1bf,
                                              u32* __restrict__ x2bf,
                                              u32* __restrict__ abf) {
  size_t gid = (size_t)blockIdx.x * 256 + threadIdx.x;
  const size_t n_x1 = (size_t)N1V * 128 / 8;   // 1,600,000
  const size_t n_a = 128 * 320 / 8;            // 5,120
  const size_t n_x2 = (size_t)N2V * 128 / 8;   // 8,000
  const float* srcp; u32* dstp; size_t idx;
  if (gid < n_x1) { srcp = x1; dstp = x1bf; idx = gid; }
  else if (gid < n_x1 + n_a) { srcp = a; dstp = abf; idx = gid - n_x1; }
  else if (gid < n_x1 + n_a + n_x2) { srcp = x2; dstp = x2bf; idx = gid - n_x1 - n_a; }
  else return;
  const f32x4* s = (const f32x4*)(srcp + idx * 8);
  f32x4 v0 = s[0], v1 = s[1];
  uint4 o;
  o.x = pack_bf16x2(v0.x, v0.y); o.y = pack_bf16x2(v0.z, v0.w);
  o.z = pack_bf16x2(v1.x, v1.y); o.w = pack_bf16x2(v1.z, v1.w);
  *(uint4*)(dstp + idx * 4) = o;
}

// ---------------- z2[t] = x2[t].c2 ; z1[i] = x1[i].c1 ----------------
__global__ __launch_bounds__(256) void k_z2(const float* __restrict__ x2,
                                            const float* __restrict__ c,
                                            float* __restrict__ z2g) {
  int w = (blockIdx.x * 256 + threadIdx.x) >> 6;
  int l = threadIdx.x & 63;
  if (w >= N2V) return;
  float p = x2[(size_t)w * 128 + l] * c[128 + l] + x2[(size_t)w * 128 + 64 + l] * c[192 + l];
  float s = wave_sum(p);
  if (l == 0) z2g[w] = s;
}

__global__ __launch_bounds__(256) void k_z1(const float* __restrict__ x1,
                                            const float* __restrict__ c,
                                            float* __restrict__ z1g) {
  int w = (blockIdx.x * 256 + threadIdx.x) >> 6;
  int l = threadIdx.x & 63;
  if (w >= N1V) return;
  float p = x1[(size_t)w * 128 + l] * c[l] + x1[(size_t)w * 128 + 64 + l] * c[64 + l];
  float s = wave_sum(p);
  if (l == 0) z1g[w] = s;
}

// ---------------- fused linear pass: histograms + w ----------------
__global__ __launch_bounds__(256) void k_histw(const int* __restrict__ src,
                                               const int* __restrict__ dst,
                                               const float* __restrict__ ee,
                                               const float* __restrict__ z1g,
                                               const float* __restrict__ z2g,
                                               const float* __restrict__ c,
                                               int* __restrict__ c1,
                                               int* __restrict__ hblk,
                                               float* __restrict__ wbuf) {
  __shared__ int h[512];
  __shared__ float c3s[64];
  for (int i = threadIdx.x; i < 512; i += 256) h[i] = 0;
  if (threadIdx.x < 64) c3s[threadIdx.x] = c[256 + threadIdx.x];
  __syncthreads();
  int b = blockIdx.x;
  int b0 = b * CHUNK, b1 = min(b0 + CHUNK, NEV);
  for (int e = b0 + threadIdx.x; e < b1; e += 256) {
    int sv = src[e], d = dst[e];
    const f32x4* row = (const f32x4*)(ee + (size_t)e * 64);
    float d0 = 0.f, d1 = 0.f, d2 = 0.f, d3 = 0.f;
#pragma unroll
    for (int q = 0; q < 4; ++q) {
      f32x4 f0 = __builtin_nontemporal_load(row + 4 * q + 0);
      f32x4 f1 = __builtin_nontemporal_load(row + 4 * q + 1);
      f32x4 f2 = __builtin_nontemporal_load(row + 4 * q + 2);
      f32x4 f3 = __builtin_nontemporal_load(row + 4 * q + 3);
      d0 += f0.x * c3s[16 * q + 0] + f0.y * c3s[16 * q + 1] +
            f0.z * c3s[16 * q + 2] + f0.w * c3s[16 * q + 3];
      d1 += f1.x * c3s[16 * q + 4] + f1.y * c3s[16 * q + 5] +
            f1.z * c3s[16 * q + 6] + f1.w * c3s[16 * q + 7];
      d2 += f2.x * c3s[16 * q + 8] + f2.y * c3s[16 * q + 9] +
            f2.z * c3s[16 * q + 10] + f2.w * c3s[16 * q + 11];
      d3 += f3.x * c3s[16 * q + 12] + f3.y * c3s[16 * q + 13] +
            f3.z * c3s[16 * q + 14] + f3.w * c3s[16 * q + 15];
    }
    float z = z1g[sv] + z2g[d] + ((d0 + d1) + (d2 + d3));
    float zp = z > 0.f ? z : ALPHAV * z;
    wbuf[e] = __expf(-zp);
    atomicAdd(&c1[sv], 1);
    atomicAdd(&h[d], 1);
  }
  __syncthreads();
  for (int i = threadIdx.x; i < 512; i += 256) hblk[(size_t)b * 512 + i] = h[i];
}

// ---------------- column scan over NB blocks ----------------
__global__ __launch_bounds__(256) void k_colscan(int* __restrict__ hblk,
                                                 int* __restrict__ tot2) {
  __shared__ int s[256];
  int t = blockIdx.x;
  int tid = threadIdx.x;
  int v[8]; int tot = 0;
#pragma unroll
  for (int j = 0; j < 8; ++j) {
    int b = tid * 8 + j;
    v[j] = hblk[(size_t)b * 512 + t];
    tot += v[j];
  }
  s[tid] = tot; __syncthreads();
  for (int off = 1; off < 256; off <<= 1) {
    int tv = (tid >= off) ? s[tid - off] : 0;
    __syncthreads();
    if (tid >= off) s[tid] += tv;
    __syncthreads();
  }
  int run = s[tid] - tot;
#pragma unroll
  for (int j = 0; j < 8; ++j) {
    int b = tid * 8 + j;
    hblk[(size_t)b * 512 + t] = run;
    run += v[j];
  }
  if (tid == 255) tot2[t] = run;
}

// ---------------- scan for src counts ----------------
__global__ __launch_bounds__(256) void k_scanA(const int* __restrict__ cnt,
                                               int* __restrict__ outp,
                                               int* __restrict__ partials, int n) {
  __shared__ int s[256];
  int tid = threadIdx.x;
  int base = blockIdx.x * 2048 + tid * 8;
  int v[8]; int tot = 0;
#pragma unroll
  for (int j = 0; j < 8; ++j) { int idx = base + j; v[j] = (idx < n) ? cnt[idx] : 0; tot += v[j]; }
  s[tid] = tot; __syncthreads();
  for (int off = 1; off < 256; off <<= 1) {
    int tv = 0;
    if (tid >= off) tv = s[tid - off];
    __syncthreads();
    if (tid >= off) s[tid] += tv;
    __syncthreads();
  }
  int run = s[tid] - tot;
#pragma unroll
  for (int j = 0; j < 8; ++j) { int idx = base + j; if (idx < n) outp[idx] = run; run += v[j]; }
  if (tid == 255) partials[blockIdx.x] = s[255];
}

__global__ __launch_bounds__(512) void k_scanB(int* __restrict__ partials, int nPart,
                                               const int* __restrict__ tot2,
                                               int* __restrict__ rp2) {
  __shared__ int s[512];
  int tid = threadIdx.x;
  int v = (tid < N2V) ? tot2[tid] : 0;
  s[tid] = v; __syncthreads();
  for (int off = 1; off < 512; off <<= 1) {
    int tv = 0;
    if (tid >= off) tv = s[tid - off];
    __syncthreads();
    if (tid >= off) s[tid] += tv;
    __syncthreads();
  }
  if (tid < N2V) rp2[tid] = s[tid] - v;
  if (tid == N2V - 1) rp2[N2V] = s[tid];
  if (tid == 0) {
    int run = 0;
    for (int b = 0; b < nPart; ++b) { int t = partials[b]; partials[b] = run; run += t; }
  }
}

__global__ __launch_bounds__(256) void k_scanC(int* __restrict__ rp, int* __restrict__ cur,
                                               const int* __restrict__ partials, int n, int total) {
  int i = blockIdx.x * 256 + threadIdx.x;
  if (i < n) {
    int v = rp[i] + partials[i >> 11];
    rp[i] = v; cur[i] = v;
  }
  if (i == 0) rp[n] = total;
}

// ---------------- light scatter: CSR placement only ----------------
__global__ __launch_bounds__(256) void k_scatter(const int* __restrict__ src,
                                                 const int* __restrict__ dst,
                                                 int* __restrict__ cur1,
                                                 const int* __restrict__ hblk,
                                                 const int* __restrict__ rp2,
                                                 int* __restrict__ e1, int* __restrict__ e2) {
  __shared__ int h[512];
  __shared__ int basep[512];
  int b = blockIdx.x;
  int b0 = b * CHUNK, b1 = min(b0 + CHUNK, NEV);
  for (int i = threadIdx.x; i < 512; i += 256) {
    basep[i] = ((i < N2V) ? rp2[i] : 0) + hblk[(size_t)b * 512 + i];
    h[i] = 0;
  }
  __syncthreads();
  for (int e = b0 + threadIdx.x; e < b1; e += 256) {
    int sv = src[e], d = dst[e];
    int p = atomicAdd(&cur1[sv], 1);
    e1[p] = e;
    int loc = atomicAdd(&h[d], 1);
    e2[basep[d] + loc] = e;
  }
}

// ---------------- dst-grouped pure gather pass ----------------
__global__ __launch_bounds__(256) void k_dst(const float* __restrict__ x1,
                                             const float* __restrict__ ee,
                                             const float* __restrict__ wbuf,
                                             const int* __restrict__ edge_src,
                                             const int* __restrict__ rp2,
                                             const int* __restrict__ e2,
                                             float* __restrict__ acc2) {
  __shared__ float red[4][224];
  int t = blockIdx.x / CHD;
  int chunk = blockIdx.x % CHD;
  int tid = threadIdx.x, wv = tid >> 6, l = tid & 63;
  int start = rp2[t], end = rp2[t + 1];
  int n = end - start;
  int sub = chunk * 4 + wv;                                  // 0..31
  int i0 = start + (int)(((long long)n * sub) >> 5);
  int i1 = start + (int)(((long long)n * (sub + 1)) >> 5);
  float sxa = 0.f, sxb = 0.f, s3 = 0.f, rsum = 0.f;
  int p = i0;
  for (; p + 4 <= i1; p += 4) {
    int ea = e2[p], eb = e2[p + 1], ec = e2[p + 2], ed = e2[p + 3];
    float wa = wbuf[ea], wb = wbuf[eb], wc = wbuf[ec], wdv = wbuf[ed];
    int sa = edge_src[ea], sb = edge_src[eb], sc = edge_src[ec], sd = edge_src[ed];
    float eva = __builtin_nontemporal_load(ee + (size_t)ea * 64 + l);
    float evb = __builtin_nontemporal_load(ee + (size_t)eb * 64 + l);
    float evc = __builtin_nontemporal_load(ee + (size_t)ec * 64 + l);
    float evd = __builtin_nontemporal_load(ee + (size_t)ed * 64 + l);
    float xaa = x1[(size_t)sa * 128 + l], xba = x1[(size_t)sa * 128 + 64 + l];
    float xab = x1[(size_t)sb * 128 + l], xbb = x1[(size_t)sb * 128 + 64 + l];
    float xac = x1[(size_t)sc * 128 + l], xbc = x1[(size_t)sc * 128 + 64 + l];
    float xad = x1[(size_t)sd * 128 + l], xbd = x1[(size_t)sd * 128 + 64 + l];
    rsum += (wa + wb) + (wc + wdv);
    s3 += wa * eva + wb * evb + wc * evc + wdv * evd;
    sxa += wa * xaa + wb * xab + wc * xac + wdv * xad;
    sxb += wa * xba + wb * xbb + wc * xbc + wdv * xbd;
  }
  for (; p < i1; ++p) {
    int ea = e2[p];
    float wa = wbuf[ea];
    int sa = edge_src[ea];
    rsum += wa;
    s3 += wa * __builtin_nontemporal_load(ee + (size_t)ea * 64 + l);
    sxa += wa * x1[(size_t)sa * 128 + l];
    sxb += wa * x1[(size_t)sa * 128 + 64 + l];
  }
  red[wv][l] = sxa; red[wv][64 + l] = sxb; red[wv][128 + l] = s3;
  if (l == 0) red[wv][192] = rsum;
  __syncthreads();
  if (tid < 193) {
    float v = red[0][tid] + red[1][tid] + red[2][tid] + red[3][tid];
    if (v != 0.f) atomicAdd(&acc2[t * 256 + tid], v);
  }
}

// ---------------- dst finalize: bf16-pack sbuf2 ----------------
__global__ __launch_bounds__(256) void k_dst_final(const float* __restrict__ acc2,
                                                   u32* __restrict__ sbuf2bf,
                                                   float* __restrict__ rs2) {
  int t = blockIdx.x, tid = threadIdx.x;
  float rtot = acc2[t * 256 + 192];
  float scale = rtot > 0.f ? 1.0f / rtot : 0.f;
  if (tid < 192) {
    float o = acc2[t * 256 + tid] * scale;
    float pr = __shfl_xor(o, 1);
    if (!(tid & 1)) sbuf2bf[t * 96 + (tid >> 1)] = pack_bf16x2(o, pr);
  }
  if (tid == 192) rs2[t] = rtot;
}

// ---------------- src-grouped pure gather pass; bf16-pack sbuf1 ----------------
__global__ __launch_bounds__(256) void k_src(const float* __restrict__ x2,
                                             const float* __restrict__ ee,
                                             const float* __restrict__ wbuf,
                                             const int* __restrict__ edge_dst,
                                             const int* __restrict__ rp1,
                                             const int* __restrict__ e1,
                                             u32* __restrict__ sbuf1bf,
                                             float* __restrict__ rs1) {
  int wid = (blockIdx.x * 256 + threadIdx.x) >> 6;
  int l = threadIdx.x & 63;
  if (wid >= N1V) return;
  int start = rp1[wid], end = rp1[wid + 1];
  float s2a = 0.f, s2b = 0.f, s1 = 0.f, rsum = 0.f;
  int p = start;
  for (; p + 4 <= end; p += 4) {
    int ea = e1[p], eb = e1[p + 1], ec = e1[p + 2], ed = e1[p + 3];
    float wa = wbuf[ea], wb = wbuf[eb], wc = wbuf[ec], wdv = wbuf[ed];
    int da = edge_dst[ea], db = edge_dst[eb], dc = edge_dst[ec], dd = edge_dst[ed];
    float eva = __builtin_nontemporal_load(ee + (size_t)ea * 64 + l);
    float evb = __builtin_nontemporal_load(ee + (size_t)eb * 64 + l);
    float evc = __builtin_nontemporal_load(ee + (size_t)ec * 64 + l);
    float evd = __builtin_nontemporal_load(ee + (size_t)ed * 64 + l);
    float xaa = x2[(size_t)da * 128 + l], xba = x2[(size_t)da * 128 + 64 + l];
    float xab = x2[(size_t)db * 128 + l], xbb = x2[(size_t)db * 128 + 64 + l];
    float xac = x2[(size_t)dc * 128 + l], xbc = x2[(size_t)dc * 128 + 64 + l];
    float xad = x2[(size_t)dd * 128 + l], xbd = x2[(size_t)dd * 128 + 64 + l];
    rsum += (wa + wb) + (wc + wdv);
    s1 += wa * eva + wb * evb + wc * evc + wdv * evd;
    s2a += wa * xaa + wb * xab + wc * xac + wdv * xad;
    s2b += wa * xba + wb * xbb + wc * xbc + wdv * xbd;
  }
  for (; p < end; ++p) {
    int ea = e1[p];
    float wa = wbuf[ea];
    int da = edge_dst[ea];
    rsum += wa;
    s1 += wa * __builtin_nontemporal_load(ee + (size_t)ea * 64 + l);
    s2a += wa * x2[(size_t)da * 128 + l];
    s2b += wa * x2[(size_t)da * 128 + 64 + l];
  }
  float scale = (end > start) ? 1.0f / rsum : 0.f;
  float o2a = s2a * scale, o2b = s2b * scale, o1v = s1 * scale;
  float p2a = __shfl_xor(o2a, 1), p2b = __shfl_xor(o2b, 1), p1v = __shfl_xor(o1v, 1);
  if (!(l & 1)) {
    u32* baseo = sbuf1bf + (size_t)wid * 96;
    baseo[(l >> 1)] = pack_bf16x2(o2a, p2a);
    baseo[32 + (l >> 1)] = pack_bf16x2(o2b, p2b);
    baseo[64 + (l >> 1)] = pack_bf16x2(o1v, p1v);
  }
  if (l == 0) rs1[wid] = (end > start) ? rsum : 0.f;
}

// ---------------- MFMA output GEMM: out = mask * elu(A[M,320]bf16 @ a^Tbf16) ----------------
// block = 64 rows, 4 waves x 16 rows; per wave: 8 n-tiles of 16 cols, K-steps of 32.
// A frag: lane row = l&15, k = (l>>4)*8+j ; B frag symmetric; D: row=(l>>4)*4+r, col=l&15.
__global__ __launch_bounds__(256) void k_gemm(const u32* __restrict__ Xbf,   // row = 64 u32
                                              const u32* __restrict__ Sbf,   // row = 96 u32
                                              const u32* __restrict__ abf,   // [128][160] u32
                                              const float* __restrict__ rs,
                                              float* __restrict__ out,
                                              int M, int mode) {
  __shared__ short Bt[128 * 40];   // [n=128][k=32 bf16 + pad 8]
  int tid = threadIdx.x;
  int w = tid >> 6, l = tid & 63;
  int r = l & 15, cchunk = l >> 4;          // 0..3
  int row0 = blockIdx.x * 64;
  int gi = row0 + w * 16 + r;               // A-row this lane loads
  int gclamp = min(gi, M - 1);
  f32x4v acc[8];
#pragma unroll
  for (int i = 0; i < 8; ++i) acc[i] = (f32x4v){0.f, 0.f, 0.f, 0.f};

  for (int ks = 0; ks < 10; ++ks) {
    if (ks) __syncthreads();
    {
      int n = tid >> 1, half = tid & 1;
      const u32* srcp = abf + n * 160 + ks * 16 + half * 8;
      u32* dstp = (u32*)&Bt[n * 40] + half * 8;
      *(uint4*)(dstp) = *(const uint4*)(srcp);
      *(uint4*)(dstp + 4) = *(const uint4*)(srcp + 4);
    }
    __syncthreads();
    int ck = ks * 4 + cchunk;                // 8-elem chunk index, 0..39
    const u32* ap;
    if (mode == 0) {
      ap = (ck < 16) ? (Xbf + (size_t)gclamp * 64 + ck * 4)
                     : (Sbf + (size_t)gclamp * 96 + (ck - 16) * 4);
    } else {
      ap = (ck < 16) ? (Sbf + (size_t)gclamp * 96 + ck * 4)
         : (ck < 32) ? (Xbf + (size_t)gclamp * 64 + (ck - 16) * 4)
                     : (Sbf + (size_t)gclamp * 96 + 64 + (ck - 32) * 4);
    }
    bf16x8 afrag = *(const bf16x8*)ap;
#pragma unroll
    for (int nt = 0; nt < 8; ++nt) {
      bf16x8 bfrag = *(const bf16x8*)&Bt[(nt * 16 + r) * 40 + cchunk * 8];
      acc[nt] = __builtin_amdgcn_mfma_f32_16x16x32_bf16(afrag, bfrag, acc[nt], 0, 0, 0);
    }
  }
  int baser = row0 + w * 16 + cchunk * 4;
#pragma unroll
  for (int rr = 0; rr < 4; ++rr) {
    int go = baser + rr;
    if (go < M) {
      float rsv = rs[go];
      bool ok = rsv > 0.f;
#pragma unroll
      for (int nt = 0; nt < 8; ++nt) {
        float h = acc[nt][rr];
        float v = ok ? (h > 0.f ? h : expm1f(h)) : 0.f;
        out[(size_t)go * 128 + nt * 16 + r] = v;
      }
    }
  }
}

// =====================================================================================

static inline size_t align_up(size_t x, size_t a) { return (x + a - 1) & ~(a - 1); }

extern "C" void kernel_launch(void* const* d_in, const int* in_sizes, int n_in,
                              void* d_out, int out_size, void* d_ws, size_t ws_size,
                              hipStream_t stream) {
  const float* x1 = (const float*)d_in[0];
  const float* x2 = (const float*)d_in[1];
  const float* ee = (const float*)d_in[2];
  const float* a = (const float*)d_in[3];
  const float* a2 = (const float*)d_in[4];
  const int* esrc = (const int*)d_in[5];
  const int* edst = (const int*)d_in[6];
  float* out = (float*)d_out;

  char* base = (char*)d_ws;
  size_t off = 0;
  auto alloc = [&](size_t bytes) -> char* {
    char* p = base + off;
    off = align_up(off + bytes, 256);
    return p;
  };
  float* c = (float*)alloc(320 * 4);
  float* z1g = (float*)alloc(N1V * 4);
  float* z2g = (float*)alloc(512 * 4);
  u32* x1bf = (u32*)alloc((size_t)N1V * 64 * 4);      // 25.6 MB
  u32* x2bf = (u32*)alloc((size_t)N2V * 64 * 4);
  u32* abf = (u32*)alloc(128 * 160 * 4);              // 80 KB
  int* rp1 = (int*)alloc((N1V + 1) * 4);
  int* cur1 = (int*)alloc(N1V * 4);
  int* rp2 = (int*)alloc(512 * 4);
  int* partials = (int*)alloc(64 * 4);
  int* hblk = (int*)alloc((size_t)NB * 512 * 4);      // 4 MB
  int* tot2 = (int*)alloc(512 * 4);
  int* e1 = (int*)alloc(NEV * 4);
  int* e2 = (int*)alloc(NEV * 4);
  float* wbuf = (float*)alloc(NEV * 4);
  float* rs1 = (float*)alloc(N1V * 4);
  float* rs2 = (float*)alloc(512 * 4);
  u32* sbuf1bf = (u32*)alloc((size_t)N1V * 96 * 4);   // 38.4 MB
  u32* sbuf2bf = (u32*)alloc(512 * 96 * 4);
  float* acc2 = (float*)alloc(512 * 256 * 4);
  (void)ws_size; (void)out_size; (void)n_in; (void)in_sizes;

  hipMemsetAsync(cur1, 0, N1V * 4, stream);
  hipMemsetAsync(acc2, 0, 512 * 256 * 4, stream);

  hipLaunchKernelGGL(k_prep, dim3(2), dim3(256), 0, stream, a, a2, c);
  hipLaunchKernelGGL(k_conv, dim3((1600000 + 5120 + 8000 + 255) / 256), dim3(256), 0, stream,
                     x1, x2, a, x1bf, x2bf, abf);
  hipLaunchKernelGGL(k_z2, dim3(125), dim3(256), 0, stream, x2, c, z2g);
  hipLaunchKernelGGL(k_z1, dim3(25000), dim3(256), 0, stream, x1, c, z1g);
  hipLaunchKernelGGL(k_histw, dim3(NB), dim3(256), 0, stream,
                     esrc, edst, ee, z1g, z2g, c, cur1, hblk, wbuf);
  hipLaunchKernelGGL(k_colscan, dim3(512), dim3(256), 0, stream, hblk, tot2);

  const int nScanBlocks = (N1V + 2047) / 2048;  // 49
  hipLaunchKernelGGL(k_scanA, dim3(nScanBlocks), dim3(256), 0, stream, cur1, rp1, partials, N1V);
  hipLaunchKernelGGL(k_scanB, dim3(1), dim3(512), 0, stream, partials, nScanBlocks, tot2, rp2);
  hipLaunchKernelGGL(k_scanC, dim3((N1V + 255) / 256), dim3(256), 0, stream, rp1, cur1, partials, N1V, NEV);
  hipLaunchKernelGGL(k_scatter, dim3(NB), dim3(256), 0, stream,
                     esrc, edst, cur1, hblk, rp2, e1, e2);

  hipLaunchKernelGGL(k_dst, dim3(N2V * CHD), dim3(256), 0, stream,
                     x1, ee, wbuf, esrc, rp2, e2, acc2);
  hipLaunchKernelGGL(k_dst_final, dim3(N2V), dim3(256), 0, stream, acc2, sbuf2bf, rs2);

  hipLaunchKernelGGL(k_src, dim3(N1V / 4), dim3(256), 0, stream,
                     x2, ee, wbuf, edst, rp1, e1, sbuf1bf, rs1);

  hipLaunchKernelGGL(k_gemm, dim3((N1V + 63) / 64), dim3(256), 0, stream,
                     x1bf, sbuf1bf, abf, rs1, out, N1V, 0);
  hipLaunchKernelGGL(k_gemm, dim3((N2V + 63) / 64), dim3(256), 0, stream,
                     x2bf, sbuf2bf, abf, rs2, out + (size_t)N1V * 128, N2V, 1);
}

// Round 14
// 485.683 us; speedup vs baseline: 1.6396x; 1.1615x over previous
//
#include <hip/hip_runtime.h>

#define N1V 100000
#define N2V 500
#define NEV 1000000
#define ALPHAV 0.2f
#define NB 2048       // histogram/scatter blocks
#define CHUNK 489     // ceil(NEV/NB)
#define CHD 8         // dst chunks per type

typedef float f32x4 __attribute__((ext_vector_type(4)));
typedef unsigned int u32;
using bf16x8 = __attribute__((ext_vector_type(8))) short;   // 8 bf16 (4 VGPRs)
using f32x4v = __attribute__((ext_vector_type(4))) float;

__device__ __forceinline__ float wave_sum(float v) {
#pragma unroll
  for (int off = 32; off > 0; off >>= 1) v += __shfl_xor(v, off, 64);
  return v;
}

__device__ __forceinline__ u32 pack_bf16x2(float a, float b) {
  u32 ua = __float_as_uint(a), ub = __float_as_uint(b);
  u32 ra = (ua + 0x7FFFu + ((ua >> 16) & 1u)) >> 16;
  u32 rb = (ub + 0x7FFFu + ((ub >> 16) & 1u)) >> 16;
  return ra | (rb << 16);
}

// ---------------- prep: c[320] = a^T @ a_2 ----------------
__global__ __launch_bounds__(256) void k_prep(const float* __restrict__ a,
                                              const float* __restrict__ a2,
                                              float* __restrict__ c) {
  int p = blockIdx.x * 256 + threadIdx.x;
  if (p < 320) {
    float s = 0.f;
    for (int k = 0; k < 128; ++k) s += a2[k] * a[k * 320 + p];
    c[p] = s;
  }
}

// ---------------- bf16 conversions: x1, a, x2 ----------------
__global__ __launch_bounds__(256) void k_conv(const float* __restrict__ x1,
                                              const float* __restrict__ x2,
                                              const float* __restrict__ a,
                                              u32* __restrict__ x1bf,
                                              u32* __restrict__ x2bf,
                                              u32* __restrict__ abf) {
  size_t gid = (size_t)blockIdx.x * 256 + threadIdx.x;
  const size_t n_x1 = (size_t)N1V * 128 / 8;   // 1,600,000
  const size_t n_a = 128 * 320 / 8;            // 5,120
  const size_t n_x2 = (size_t)N2V * 128 / 8;   // 8,000
  const float* srcp; u32* dstp; size_t idx;
  if (gid < n_x1) { srcp = x1; dstp = x1bf; idx = gid; }
  else if (gid < n_x1 + n_a) { srcp = a; dstp = abf; idx = gid - n_x1; }
  else if (gid < n_x1 + n_a + n_x2) { srcp = x2; dstp = x2bf; idx = gid - n_x1 - n_a; }
  else return;
  const f32x4* s = (const f32x4*)(srcp + idx * 8);
  f32x4 v0 = s[0], v1 = s[1];
  uint4 o;
  o.x = pack_bf16x2(v0.x, v0.y); o.y = pack_bf16x2(v0.z, v0.w);
  o.z = pack_bf16x2(v1.x, v1.y); o.w = pack_bf16x2(v1.z, v1.w);
  *(uint4*)(dstp + idx * 4) = o;
}

// ---------------- z2[t] = x2[t].c2 ; z1[i] = x1[i].c1 ----------------
__global__ __launch_bounds__(256) void k_z2(const float* __restrict__ x2,
                                            const float* __restrict__ c,
                                            float* __restrict__ z2g) {
  int w = (blockIdx.x * 256 + threadIdx.x) >> 6;
  int l = threadIdx.x & 63;
  if (w >= N2V) return;
  float p = x2[(size_t)w * 128 + l] * c[128 + l] + x2[(size_t)w * 128 + 64 + l] * c[192 + l];
  float s = wave_sum(p);
  if (l == 0) z2g[w] = s;
}

__global__ __launch_bounds__(256) void k_z1(const float* __restrict__ x1,
                                            const float* __restrict__ c,
                                            float* __restrict__ z1g) {
  int w = (blockIdx.x * 256 + threadIdx.x) >> 6;
  int l = threadIdx.x & 63;
  if (w >= N1V) return;
  float p = x1[(size_t)w * 128 + l] * c[l] + x1[(size_t)w * 128 + 64 + l] * c[64 + l];
  float s = wave_sum(p);
  if (l == 0) z1g[w] = s;
}

// ---------------- fused linear pass: histograms + w (LDS stage-transpose) ----------------
// per 128-edge tile: coalesced stage into LDS (stride 65), 2 threads/edge half-row dot
// from LDS (bank = (j+k)%32, conflict-free), shfl_xor(1) combine, then w + atomics.
__global__ __launch_bounds__(256) void k_histw(const int* __restrict__ src,
                                               const int* __restrict__ dst,
                                               const float* __restrict__ ee,
                                               const float* __restrict__ z1g,
                                               const float* __restrict__ z2g,
                                               const float* __restrict__ c,
                                               int* __restrict__ c1,
                                               int* __restrict__ hblk,
                                               float* __restrict__ wbuf) {
  __shared__ float tile[128 * 65];
  __shared__ int h[512];
  for (int i = threadIdx.x; i < 512; i += 256) h[i] = 0;
  int tid = threadIdx.x;
  int half = tid & 1, j = tid >> 1;
  float creg[32];
#pragma unroll
  for (int k = 0; k < 32; ++k) creg[k] = c[256 + half * 32 + k];
  __syncthreads();

  int b = blockIdx.x;
  int b0 = b * CHUNK, b1 = min(b0 + CHUNK, NEV);
  for (int ts = b0; ts < b1; ts += 128) {
    int nt = min(128, b1 - ts);
    __syncthreads();
    // stage: idx over tile floats/4; consecutive tid -> consecutive 16B (coalesced)
#pragma unroll
    for (int i = 0; i < 8; ++i) {
      int idx = i * 256 + tid;          // 0..2047 -> (row, 16B-chunk)
      int r = idx >> 4, cc = idx & 15;
      if (r < nt) {
        f32x4 v = __builtin_nontemporal_load((const f32x4*)(ee + (size_t)(ts + r) * 64) + cc);
        int basef = r * 65 + cc * 4;
        tile[basef + 0] = v.x; tile[basef + 1] = v.y;
        tile[basef + 2] = v.z; tile[basef + 3] = v.w;
      }
    }
    __syncthreads();
    if (j < nt) {
      float dotv = 0.f;
      int basef = j * 65 + half * 32;
#pragma unroll
      for (int k = 0; k < 32; ++k) dotv += tile[basef + k] * creg[k];
      dotv += __shfl_xor(dotv, 1);
      if (half == 0) {
        int e = ts + j;
        int sv = src[e], d = dst[e];
        float z = z1g[sv] + z2g[d] + dotv;
        float zp = z > 0.f ? z : ALPHAV * z;
        wbuf[e] = __expf(-zp);
        atomicAdd(&c1[sv], 1);
        atomicAdd(&h[d], 1);
      }
    }
  }
  __syncthreads();
  for (int i = threadIdx.x; i < 512; i += 256) hblk[(size_t)b * 512 + i] = h[i];
}

// ---------------- column scan over NB blocks ----------------
__global__ __launch_bounds__(256) void k_colscan(int* __restrict__ hblk,
                                                 int* __restrict__ tot2) {
  __shared__ int s[256];
  int t = blockIdx.x;
  int tid = threadIdx.x;
  int v[8]; int tot = 0;
#pragma unroll
  for (int j = 0; j < 8; ++j) {
    int b = tid * 8 + j;
    v[j] = hblk[(size_t)b * 512 + t];
    tot += v[j];
  }
  s[tid] = tot; __syncthreads();
  for (int off = 1; off < 256; off <<= 1) {
    int tv = (tid >= off) ? s[tid - off] : 0;
    __syncthreads();
    if (tid >= off) s[tid] += tv;
    __syncthreads();
  }
  int run = s[tid] - tot;
#pragma unroll
  for (int j = 0; j < 8; ++j) {
    int b = tid * 8 + j;
    hblk[(size_t)b * 512 + t] = run;
    run += v[j];
  }
  if (tid == 255) tot2[t] = run;
}

// ---------------- scan for src counts ----------------
__global__ __launch_bounds__(256) void k_scanA(const int* __restrict__ cnt,
                                               int* __restrict__ outp,
                                               int* __restrict__ partials, int n) {
  __shared__ int s[256];
  int tid = threadIdx.x;
  int base = blockIdx.x * 2048 + tid * 8;
  int v[8]; int tot = 0;
#pragma unroll
  for (int j = 0; j < 8; ++j) { int idx = base + j; v[j] = (idx < n) ? cnt[idx] : 0; tot += v[j]; }
  s[tid] = tot; __syncthreads();
  for (int off = 1; off < 256; off <<= 1) {
    int tv = 0;
    if (tid >= off) tv = s[tid - off];
    __syncthreads();
    if (tid >= off) s[tid] += tv;
    __syncthreads();
  }
  int run = s[tid] - tot;
#pragma unroll
  for (int j = 0; j < 8; ++j) { int idx = base + j; if (idx < n) outp[idx] = run; run += v[j]; }
  if (tid == 255) partials[blockIdx.x] = s[255];
}

__global__ __launch_bounds__(512) void k_scanB(int* __restrict__ partials, int nPart,
                                               const int* __restrict__ tot2,
                                               int* __restrict__ rp2) {
  __shared__ int s[512];
  int tid = threadIdx.x;
  int v = (tid < N2V) ? tot2[tid] : 0;
  s[tid] = v; __syncthreads();
  for (int off = 1; off < 512; off <<= 1) {
    int tv = 0;
    if (tid >= off) tv = s[tid - off];
    __syncthreads();
    if (tid >= off) s[tid] += tv;
    __syncthreads();
  }
  if (tid < N2V) rp2[tid] = s[tid] - v;
  if (tid == N2V - 1) rp2[N2V] = s[tid];
  if (tid == 0) {
    int run = 0;
    for (int b = 0; b < nPart; ++b) { int t = partials[b]; partials[b] = run; run += t; }
  }
}

__global__ __launch_bounds__(256) void k_scanC(int* __restrict__ rp, int* __restrict__ cur,
                                               const int* __restrict__ partials, int n, int total) {
  int i = blockIdx.x * 256 + threadIdx.x;
  if (i < n) {
    int v = rp[i] + partials[i >> 11];
    rp[i] = v; cur[i] = v;
  }
  if (i == 0) rp[n] = total;
}

// ---------------- light scatter: CSR placement only ----------------
__global__ __launch_bounds__(256) void k_scatter(const int* __restrict__ src,
                                                 const int* __restrict__ dst,
                                                 int* __restrict__ cur1,
                                                 const int* __restrict__ hblk,
                                                 const int* __restrict__ rp2,
                                                 int* __restrict__ e1, int* __restrict__ e2) {
  __shared__ int h[512];
  __shared__ int basep[512];
  int b = blockIdx.x;
  int b0 = b * CHUNK, b1 = min(b0 + CHUNK, NEV);
  for (int i = threadIdx.x; i < 512; i += 256) {
    basep[i] = ((i < N2V) ? rp2[i] : 0) + hblk[(size_t)b * 512 + i];
    h[i] = 0;
  }
  __syncthreads();
  for (int e = b0 + threadIdx.x; e < b1; e += 256) {
    int sv = src[e], d = dst[e];
    int p = atomicAdd(&cur1[sv], 1);
    e1[p] = e;
    int loc = atomicAdd(&h[d], 1);
    e2[basep[d] + loc] = e;
  }
}

// ---------------- dst-grouped pure gather pass ----------------
__global__ __launch_bounds__(256) void k_dst(const float* __restrict__ x1,
                                             const float* __restrict__ ee,
                                             const float* __restrict__ wbuf,
                                             const int* __restrict__ edge_src,
                                             const int* __restrict__ rp2,
                                             const int* __restrict__ e2,
                                             float* __restrict__ acc2) {
  __shared__ float red[4][224];
  int t = blockIdx.x / CHD;
  int chunk = blockIdx.x % CHD;
  int tid = threadIdx.x, wv = tid >> 6, l = tid & 63;
  int start = rp2[t], end = rp2[t + 1];
  int n = end - start;
  int sub = chunk * 4 + wv;                                  // 0..31
  int i0 = start + (int)(((long long)n * sub) >> 5);
  int i1 = start + (int)(((long long)n * (sub + 1)) >> 5);
  float sxa = 0.f, sxb = 0.f, s3 = 0.f, rsum = 0.f;
  int p = i0;
  for (; p + 4 <= i1; p += 4) {
    int ea = e2[p], eb = e2[p + 1], ec = e2[p + 2], ed = e2[p + 3];
    float wa = wbuf[ea], wb = wbuf[eb], wc = wbuf[ec], wdv = wbuf[ed];
    int sa = edge_src[ea], sb = edge_src[eb], sc = edge_src[ec], sd = edge_src[ed];
    float eva = __builtin_nontemporal_load(ee + (size_t)ea * 64 + l);
    float evb = __builtin_nontemporal_load(ee + (size_t)eb * 64 + l);
    float evc = __builtin_nontemporal_load(ee + (size_t)ec * 64 + l);
    float evd = __builtin_nontemporal_load(ee + (size_t)ed * 64 + l);
    float xaa = x1[(size_t)sa * 128 + l], xba = x1[(size_t)sa * 128 + 64 + l];
    float xab = x1[(size_t)sb * 128 + l], xbb = x1[(size_t)sb * 128 + 64 + l];
    float xac = x1[(size_t)sc * 128 + l], xbc = x1[(size_t)sc * 128 + 64 + l];
    float xad = x1[(size_t)sd * 128 + l], xbd = x1[(size_t)sd * 128 + 64 + l];
    rsum += (wa + wb) + (wc + wdv);
    s3 += wa * eva + wb * evb + wc * evc + wdv * evd;
    sxa += wa * xaa + wb * xab + wc * xac + wdv * xad;
    sxb += wa * xba + wb * xbb + wc * xbc + wdv * xbd;
  }
  for (; p < i1; ++p) {
    int ea = e2[p];
    float wa = wbuf[ea];
    int sa = edge_src[ea];
    rsum += wa;
    s3 += wa * __builtin_nontemporal_load(ee + (size_t)ea * 64 + l);
    sxa += wa * x1[(size_t)sa * 128 + l];
    sxb += wa * x1[(size_t)sa * 128 + 64 + l];
  }
  red[wv][l] = sxa; red[wv][64 + l] = sxb; red[wv][128 + l] = s3;
  if (l == 0) red[wv][192] = rsum;
  __syncthreads();
  if (tid < 193) {
    float v = red[0][tid] + red[1][tid] + red[2][tid] + red[3][tid];
    if (v != 0.f) atomicAdd(&acc2[t * 256 + tid], v);
  }
}

// ---------------- dst finalize: bf16-pack sbuf2 ----------------
__global__ __launch_bounds__(256) void k_dst_final(const float* __restrict__ acc2,
                                                   u32* __restrict__ sbuf2bf,
                                                   float* __restrict__ rs2) {
  int t = blockIdx.x, tid = threadIdx.x;
  float rtot = acc2[t * 256 + 192];
  float scale = rtot > 0.f ? 1.0f / rtot : 0.f;
  if (tid < 192) {
    float o = acc2[t * 256 + tid] * scale;
    float pr = __shfl_xor(o, 1);
    if (!(tid & 1)) sbuf2bf[t * 96 + (tid >> 1)] = pack_bf16x2(o, pr);
  }
  if (tid == 192) rs2[t] = rtot;
}

// ---------------- src-grouped pure gather pass; bf16-pack sbuf1 ----------------
__global__ __launch_bounds__(256) void k_src(const float* __restrict__ x2,
                                             const float* __restrict__ ee,
                                             const float* __restrict__ wbuf,
                                             const int* __restrict__ edge_dst,
                                             const int* __restrict__ rp1,
                                             const int* __restrict__ e1,
                                             u32* __restrict__ sbuf1bf,
                                             float* __restrict__ rs1) {
  int wid = (blockIdx.x * 256 + threadIdx.x) >> 6;
  int l = threadIdx.x & 63;
  if (wid >= N1V) return;
  int start = rp1[wid], end = rp1[wid + 1];
  float s2a = 0.f, s2b = 0.f, s1 = 0.f, rsum = 0.f;
  int p = start;
  for (; p + 4 <= end; p += 4) {
    int ea = e1[p], eb = e1[p + 1], ec = e1[p + 2], ed = e1[p + 3];
    float wa = wbuf[ea], wb = wbuf[eb], wc = wbuf[ec], wdv = wbuf[ed];
    int da = edge_dst[ea], db = edge_dst[eb], dc = edge_dst[ec], dd = edge_dst[ed];
    float eva = __builtin_nontemporal_load(ee + (size_t)ea * 64 + l);
    float evb = __builtin_nontemporal_load(ee + (size_t)eb * 64 + l);
    float evc = __builtin_nontemporal_load(ee + (size_t)ec * 64 + l);
    float evd = __builtin_nontemporal_load(ee + (size_t)ed * 64 + l);
    float xaa = x2[(size_t)da * 128 + l], xba = x2[(size_t)da * 128 + 64 + l];
    float xab = x2[(size_t)db * 128 + l], xbb = x2[(size_t)db * 128 + 64 + l];
    float xac = x2[(size_t)dc * 128 + l], xbc = x2[(size_t)dc * 128 + 64 + l];
    float xad = x2[(size_t)dd * 128 + l], xbd = x2[(size_t)dd * 128 + 64 + l];
    rsum += (wa + wb) + (wc + wdv);
    s1 += wa * eva + wb * evb + wc * evc + wdv * evd;
    s2a += wa * xaa + wb * xab + wc * xac + wdv * xad;
    s2b += wa * xba + wb * xbb + wc * xbc + wdv * xbd;
  }
  for (; p < end; ++p) {
    int ea = e1[p];
    float wa = wbuf[ea];
    int da = edge_dst[ea];
    rsum += wa;
    s1 += wa * __builtin_nontemporal_load(ee + (size_t)ea * 64 + l);
    s2a += wa * x2[(size_t)da * 128 + l];
    s2b += wa * x2[(size_t)da * 128 + 64 + l];
  }
  float scale = (end > start) ? 1.0f / rsum : 0.f;
  float o2a = s2a * scale, o2b = s2b * scale, o1v = s1 * scale;
  float p2a = __shfl_xor(o2a, 1), p2b = __shfl_xor(o2b, 1), p1v = __shfl_xor(o1v, 1);
  if (!(l & 1)) {
    u32* baseo = sbuf1bf + (size_t)wid * 96;
    baseo[(l >> 1)] = pack_bf16x2(o2a, p2a);
    baseo[32 + (l >> 1)] = pack_bf16x2(o2b, p2b);
    baseo[64 + (l >> 1)] = pack_bf16x2(o1v, p1v);
  }
  if (l == 0) rs1[wid] = (end > start) ? rsum : 0.f;
}

// ---------------- MFMA output GEMM: out = mask * elu(A[M,320]bf16 @ a^Tbf16) ----------------
__global__ __launch_bounds__(256) void k_gemm(const u32* __restrict__ Xbf,   // row = 64 u32
                                              const u32* __restrict__ Sbf,   // row = 96 u32
                                              const u32* __restrict__ abf,   // [128][160] u32
                                              const float* __restrict__ rs,
                                              float* __restrict__ out,
                                              int M, int mode) {
  __shared__ short Bt[128 * 40];   // [n=128][k=32 bf16 + pad 8]
  int tid = threadIdx.x;
  int w = tid >> 6, l = tid & 63;
  int r = l & 15, cchunk = l >> 4;          // 0..3
  int row0 = blockIdx.x * 64;
  int gi = row0 + w * 16 + r;               // A-row this lane loads
  int gclamp = min(gi, M - 1);
  f32x4v acc[8];
#pragma unroll
  for (int i = 0; i < 8; ++i) acc[i] = (f32x4v){0.f, 0.f, 0.f, 0.f};

  for (int ks = 0; ks < 10; ++ks) {
    if (ks) __syncthreads();
    {
      int n = tid >> 1, half = tid & 1;
      const u32* srcp = abf + n * 160 + ks * 16 + half * 8;
      u32* dstp = (u32*)&Bt[n * 40] + half * 8;
      *(uint4*)(dstp) = *(const uint4*)(srcp);
      *(uint4*)(dstp + 4) = *(const uint4*)(srcp + 4);
    }
    __syncthreads();
    int ck = ks * 4 + cchunk;                // 8-elem chunk index, 0..39
    const u32* ap;
    if (mode == 0) {
      ap = (ck < 16) ? (Xbf + (size_t)gclamp * 64 + ck * 4)
                     : (Sbf + (size_t)gclamp * 96 + (ck - 16) * 4);
    } else {
      ap = (ck < 16) ? (Sbf + (size_t)gclamp * 96 + ck * 4)
         : (ck < 32) ? (Xbf + (size_t)gclamp * 64 + (ck - 16) * 4)
                     : (Sbf + (size_t)gclamp * 96 + 64 + (ck - 32) * 4);
    }
    bf16x8 afrag = *(const bf16x8*)ap;
#pragma unroll
    for (int nt = 0; nt < 8; ++nt) {
      bf16x8 bfrag = *(const bf16x8*)&Bt[(nt * 16 + r) * 40 + cchunk * 8];
      acc[nt] = __builtin_amdgcn_mfma_f32_16x16x32_bf16(afrag, bfrag, acc[nt], 0, 0, 0);
    }
  }
  int baser = row0 + w * 16 + cchunk * 4;
#pragma unroll
  for (int rr = 0; rr < 4; ++rr) {
    int go = baser + rr;
    if (go < M) {
      float rsv = rs[go];
      bool ok = rsv > 0.f;
#pragma unroll
      for (int nt = 0; nt < 8; ++nt) {
        float h = acc[nt][rr];
        float v = ok ? (h > 0.f ? h : expm1f(h)) : 0.f;
        out[(size_t)go * 128 + nt * 16 + r] = v;
      }
    }
  }
}

// =====================================================================================

static inline size_t align_up(size_t x, size_t a) { return (x + a - 1) & ~(a - 1); }

extern "C" void kernel_launch(void* const* d_in, const int* in_sizes, int n_in,
                              void* d_out, int out_size, void* d_ws, size_t ws_size,
                              hipStream_t stream) {
  const float* x1 = (const float*)d_in[0];
  const float* x2 = (const float*)d_in[1];
  const float* ee = (const float*)d_in[2];
  const float* a = (const float*)d_in[3];
  const float* a2 = (const float*)d_in[4];
  const int* esrc = (const int*)d_in[5];
  const int* edst = (const int*)d_in[6];
  float* out = (float*)d_out;

  char* base = (char*)d_ws;
  size_t off = 0;
  auto alloc = [&](size_t bytes) -> char* {
    char* p = base + off;
    off = align_up(off + bytes, 256);
    return p;
  };
  float* c = (float*)alloc(320 * 4);
  float* z1g = (float*)alloc(N1V * 4);
  float* z2g = (float*)alloc(512 * 4);
  u32* x1bf = (u32*)alloc((size_t)N1V * 64 * 4);      // 25.6 MB
  u32* x2bf = (u32*)alloc((size_t)N2V * 64 * 4);
  u32* abf = (u32*)alloc(128 * 160 * 4);              // 80 KB
  int* rp1 = (int*)alloc((N1V + 1) * 4);
  int* cur1 = (int*)alloc(N1V * 4);
  int* rp2 = (int*)alloc(512 * 4);
  int* partials = (int*)alloc(64 * 4);
  int* hblk = (int*)alloc((size_t)NB * 512 * 4);      // 4 MB
  int* tot2 = (int*)alloc(512 * 4);
  int* e1 = (int*)alloc(NEV * 4);
  int* e2 = (int*)alloc(NEV * 4);
  float* wbuf = (float*)alloc(NEV * 4);
  float* rs1 = (float*)alloc(N1V * 4);
  float* rs2 = (float*)alloc(512 * 4);
  u32* sbuf1bf = (u32*)alloc((size_t)N1V * 96 * 4);   // 38.4 MB
  u32* sbuf2bf = (u32*)alloc(512 * 96 * 4);
  float* acc2 = (float*)alloc(512 * 256 * 4);
  (void)ws_size; (void)out_size; (void)n_in; (void)in_sizes;

  hipMemsetAsync(cur1, 0, N1V * 4, stream);
  hipMemsetAsync(acc2, 0, 512 * 256 * 4, stream);

  hipLaunchKernelGGL(k_prep, dim3(2), dim3(256), 0, stream, a, a2, c);
  hipLaunchKernelGGL(k_conv, dim3((1600000 + 5120 + 8000 + 255) / 256), dim3(256), 0, stream,
                     x1, x2, a, x1bf, x2bf, abf);
  hipLaunchKernelGGL(k_z2, dim3(125), dim3(256), 0, stream, x2, c, z2g);
  hipLaunchKernelGGL(k_z1, dim3(25000), dim3(256), 0, stream, x1, c, z1g);
  hipLaunchKernelGGL(k_histw, dim3(NB), dim3(256), 0, stream,
                     esrc, edst, ee, z1g, z2g, c, cur1, hblk, wbuf);
  hipLaunchKernelGGL(k_colscan, dim3(512), dim3(256), 0, stream, hblk, tot2);

  const int nScanBlocks = (N1V + 2047) / 2048;  // 49
  hipLaunchKernelGGL(k_scanA, dim3(nScanBlocks), dim3(256), 0, stream, cur1, rp1, partials, N1V);
  hipLaunchKernelGGL(k_scanB, dim3(1), dim3(512), 0, stream, partials, nScanBlocks, tot2, rp2);
  hipLaunchKernelGGL(k_scanC, dim3((N1V + 255) / 256), dim3(256), 0, stream, rp1, cur1, partials, N1V, NEV);
  hipLaunchKernelGGL(k_scatter, dim3(NB), dim3(256), 0, stream,
                     esrc, edst, cur1, hblk, rp2, e1, e2);

  hipLaunchKernelGGL(k_dst, dim3(N2V * CHD), dim3(256), 0, stream,
                     x1, ee, wbuf, esrc, rp2, e2, acc2);
  hipLaunchKernelGGL(k_dst_final, dim3(N2V), dim3(256), 0, stream, acc2, sbuf2bf, rs2);

  hipLaunchKernelGGL(k_src, dim3(N1V / 4), dim3(256), 0, stream,
                     x2, ee, wbuf, edst, rp1, e1, sbuf1bf, rs1);

  hipLaunchKernelGGL(k_gemm, dim3((N1V + 63) / 64), dim3(256), 0, stream,
                     x1bf, sbuf1bf, abf, rs1, out, N1V, 0);
  hipLaunchKernelGGL(k_gemm, dim3((N2V + 63) / 64), dim3(256), 0, stream,
                     x2bf, sbuf2bf, abf, rs2, out + (size_t)N1V * 128, N2V, 1);
}

// Round 15
// 468.283 us; speedup vs baseline: 1.7005x; 1.0372x over previous
//
#include <hip/hip_runtime.h>

#define N1V 100000
#define N2V 500
#define NEV 1000000
#define ALPHAV 0.2f
#define NB 2048       // histogram/scatter blocks
#define CHUNK 489     // ceil(NEV/NB)
#define CHD 8         // dst chunks per type

typedef float f32x4 __attribute__((ext_vector_type(4)));
typedef unsigned int u32;
typedef unsigned short u16;
using bf16x8 = __attribute__((ext_vector_type(8))) short;   // 8 bf16 (4 VGPRs)
using f32x4v = __attribute__((ext_vector_type(4))) float;

__device__ __forceinline__ float wave_sum(float v) {
#pragma unroll
  for (int off = 32; off > 0; off >>= 1) v += __shfl_xor(v, off, 64);
  return v;
}

__device__ __forceinline__ u32 pack_bf16x2(float a, float b) {
  u32 ua = __float_as_uint(a), ub = __float_as_uint(b);
  u32 ra = (ua + 0x7FFFu + ((ua >> 16) & 1u)) >> 16;
  u32 rb = (ub + 0x7FFFu + ((ub >> 16) & 1u)) >> 16;
  return ra | (rb << 16);
}

__device__ __forceinline__ float bf16_to_f(u16 h) {
  return __uint_as_float(((u32)h) << 16);
}

// ---------------- prep: c[320] = a^T @ a_2 ----------------
__global__ __launch_bounds__(256) void k_prep(const float* __restrict__ a,
                                              const float* __restrict__ a2,
                                              float* __restrict__ c) {
  int p = blockIdx.x * 256 + threadIdx.x;
  if (p < 320) {
    float s = 0.f;
    for (int k = 0; k < 128; ++k) s += a2[k] * a[k * 320 + p];
    c[p] = s;
  }
}

// ---------------- bf16 conversions: x1, a, x2 ----------------
__global__ __launch_bounds__(256) void k_conv(const float* __restrict__ x1,
                                              const float* __restrict__ x2,
                                              const float* __restrict__ a,
                                              u32* __restrict__ x1bf,
                                              u32* __restrict__ x2bf,
                                              u32* __restrict__ abf) {
  size_t gid = (size_t)blockIdx.x * 256 + threadIdx.x;
  const size_t n_x1 = (size_t)N1V * 128 / 8;   // 1,600,000
  const size_t n_a = 128 * 320 / 8;            // 5,120
  const size_t n_x2 = (size_t)N2V * 128 / 8;   // 8,000
  const float* srcp; u32* dstp; size_t idx;
  if (gid < n_x1) { srcp = x1; dstp = x1bf; idx = gid; }
  else if (gid < n_x1 + n_a) { srcp = a; dstp = abf; idx = gid - n_x1; }
  else if (gid < n_x1 + n_a + n_x2) { srcp = x2; dstp = x2bf; idx = gid - n_x1 - n_a; }
  else return;
  const f32x4* s = (const f32x4*)(srcp + idx * 8);
  f32x4 v0 = s[0], v1 = s[1];
  uint4 o;
  o.x = pack_bf16x2(v0.x, v0.y); o.y = pack_bf16x2(v0.z, v0.w);
  o.z = pack_bf16x2(v1.x, v1.y); o.w = pack_bf16x2(v1.z, v1.w);
  *(uint4*)(dstp + idx * 4) = o;
}

// ---------------- z2[t] = x2[t].c2 ; z1[i] = x1[i].c1 ----------------
__global__ __launch_bounds__(256) void k_z2(const float* __restrict__ x2,
                                            const float* __restrict__ c,
                                            float* __restrict__ z2g) {
  int w = (blockIdx.x * 256 + threadIdx.x) >> 6;
  int l = threadIdx.x & 63;
  if (w >= N2V) return;
  float p = x2[(size_t)w * 128 + l] * c[128 + l] + x2[(size_t)w * 128 + 64 + l] * c[192 + l];
  float s = wave_sum(p);
  if (l == 0) z2g[w] = s;
}

__global__ __launch_bounds__(256) void k_z1(const float* __restrict__ x1,
                                            const float* __restrict__ c,
                                            float* __restrict__ z1g) {
  int w = (blockIdx.x * 256 + threadIdx.x) >> 6;
  int l = threadIdx.x & 63;
  if (w >= N1V) return;
  float p = x1[(size_t)w * 128 + l] * c[l] + x1[(size_t)w * 128 + 64 + l] * c[64 + l];
  float s = wave_sum(p);
  if (l == 0) z1g[w] = s;
}

// ---------------- fused linear pass: histograms + w + coalesced bf16 transcode ----------------
__global__ __launch_bounds__(256) void k_histw(const int* __restrict__ src,
                                               const int* __restrict__ dst,
                                               const float* __restrict__ ee,
                                               const float* __restrict__ z1g,
                                               const float* __restrict__ z2g,
                                               const float* __restrict__ c,
                                               int* __restrict__ c1,
                                               int* __restrict__ hblk,
                                               float* __restrict__ wbuf,
                                               u32* __restrict__ eeh) {
  __shared__ float tile[128 * 65];
  __shared__ int h[512];
  for (int i = threadIdx.x; i < 512; i += 256) h[i] = 0;
  int tid = threadIdx.x;
  int half = tid & 1, j = tid >> 1;
  float creg[32];
#pragma unroll
  for (int k = 0; k < 32; ++k) creg[k] = c[256 + half * 32 + k];
  __syncthreads();

  int b = blockIdx.x;
  int b0 = b * CHUNK, b1 = min(b0 + CHUNK, NEV);
  for (int ts = b0; ts < b1; ts += 128) {
    int nt = min(128, b1 - ts);
    __syncthreads();
    // stage: coalesced f32x4 reads -> LDS stride 65
#pragma unroll
    for (int i = 0; i < 8; ++i) {
      int idx = i * 256 + tid;          // 0..2047 -> (row, 16B-chunk)
      int r = idx >> 4, cc = idx & 15;
      if (r < nt) {
        f32x4 v = __builtin_nontemporal_load((const f32x4*)(ee + (size_t)(ts + r) * 64) + cc);
        int basef = r * 65 + cc * 4;
        tile[basef + 0] = v.x; tile[basef + 1] = v.y;
        tile[basef + 2] = v.z; tile[basef + 3] = v.w;
      }
    }
    __syncthreads();
    // dot + w
    if (j < nt) {
      float dotv = 0.f;
      int basef = j * 65 + half * 32;
#pragma unroll
      for (int k = 0; k < 32; ++k) dotv += tile[basef + k] * creg[k];
      dotv += __shfl_xor(dotv, 1);
      if (half == 0) {
        int e = ts + j;
        int sv = src[e], d = dst[e];
        float z = z1g[sv] + z2g[d] + dotv;
        float zp = z > 0.f ? z : ALPHAV * z;
        wbuf[e] = __expf(-zp);
        atomicAdd(&c1[sv], 1);
        atomicAdd(&h[d], 1);
      }
    }
    // transcode: tile -> eeh bf16, coalesced uint4 stores (16B/lane)
#pragma unroll
    for (int i = 0; i < 4; ++i) {
      int idx4 = i * 256 + tid;          // 0..1023: row = idx4>>3, q8 = idx4&7
      int r = idx4 >> 3, q8 = idx4 & 7;
      if (r < nt) {
        int basef = r * 65 + q8 * 8;
        uint4 o;
        o.x = pack_bf16x2(tile[basef + 0], tile[basef + 1]);
        o.y = pack_bf16x2(tile[basef + 2], tile[basef + 3]);
        o.z = pack_bf16x2(tile[basef + 4], tile[basef + 5]);
        o.w = pack_bf16x2(tile[basef + 6], tile[basef + 7]);
        *(uint4*)(eeh + (size_t)(ts + r) * 32 + q8 * 4) = o;
      }
    }
  }
  __syncthreads();
  for (int i = threadIdx.x; i < 512; i += 256) hblk[(size_t)b * 512 + i] = h[i];
}

// ---------------- column scan over NB blocks ----------------
__global__ __launch_bounds__(256) void k_colscan(int* __restrict__ hblk,
                                                 int* __restrict__ tot2) {
  __shared__ int s[256];
  int t = blockIdx.x;
  int tid = threadIdx.x;
  int v[8]; int tot = 0;
#pragma unroll
  for (int j = 0; j < 8; ++j) {
    int b = tid * 8 + j;
    v[j] = hblk[(size_t)b * 512 + t];
    tot += v[j];
  }
  s[tid] = tot; __syncthreads();
  for (int off = 1; off < 256; off <<= 1) {
    int tv = (tid >= off) ? s[tid - off] : 0;
    __syncthreads();
    if (tid >= off) s[tid] += tv;
    __syncthreads();
  }
  int run = s[tid] - tot;
#pragma unroll
  for (int j = 0; j < 8; ++j) {
    int b = tid * 8 + j;
    hblk[(size_t)b * 512 + t] = run;
    run += v[j];
  }
  if (tid == 255) tot2[t] = run;
}

// ---------------- scan for src counts ----------------
__global__ __launch_bounds__(256) void k_scanA(const int* __restrict__ cnt,
                                               int* __restrict__ outp,
                                               int* __restrict__ partials, int n) {
  __shared__ int s[256];
  int tid = threadIdx.x;
  int base = blockIdx.x * 2048 + tid * 8;
  int v[8]; int tot = 0;
#pragma unroll
  for (int j = 0; j < 8; ++j) { int idx = base + j; v[j] = (idx < n) ? cnt[idx] : 0; tot += v[j]; }
  s[tid] = tot; __syncthreads();
  for (int off = 1; off < 256; off <<= 1) {
    int tv = 0;
    if (tid >= off) tv = s[tid - off];
    __syncthreads();
    if (tid >= off) s[tid] += tv;
    __syncthreads();
  }
  int run = s[tid] - tot;
#pragma unroll
  for (int j = 0; j < 8; ++j) { int idx = base + j; if (idx < n) outp[idx] = run; run += v[j]; }
  if (tid == 255) partials[blockIdx.x] = s[255];
}

__global__ __launch_bounds__(512) void k_scanB(int* __restrict__ partials, int nPart,
                                               const int* __restrict__ tot2,
                                               int* __restrict__ rp2) {
  __shared__ int s[512];
  int tid = threadIdx.x;
  int v = (tid < N2V) ? tot2[tid] : 0;
  s[tid] = v; __syncthreads();
  for (int off = 1; off < 512; off <<= 1) {
    int tv = 0;
    if (tid >= off) tv = s[tid - off];
    __syncthreads();
    if (tid >= off) s[tid] += tv;
    __syncthreads();
  }
  if (tid < N2V) rp2[tid] = s[tid] - v;
  if (tid == N2V - 1) rp2[N2V] = s[tid];
  if (tid == 0) {
    int run = 0;
    for (int b = 0; b < nPart; ++b) { int t = partials[b]; partials[b] = run; run += t; }
  }
}

__global__ __launch_bounds__(256) void k_scanC(int* __restrict__ rp, int* __restrict__ cur,
                                               const int* __restrict__ partials, int n, int total) {
  int i = blockIdx.x * 256 + threadIdx.x;
  if (i < n) {
    int v = rp[i] + partials[i >> 11];
    rp[i] = v; cur[i] = v;
  }
  if (i == 0) rp[n] = total;
}

// ---------------- light scatter: CSR placement only ----------------
__global__ __launch_bounds__(256) void k_scatter(const int* __restrict__ src,
                                                 const int* __restrict__ dst,
                                                 int* __restrict__ cur1,
                                                 const int* __restrict__ hblk,
                                                 const int* __restrict__ rp2,
                                                 int* __restrict__ e1, int* __restrict__ e2) {
  __shared__ int h[512];
  __shared__ int basep[512];
  int b = blockIdx.x;
  int b0 = b * CHUNK, b1 = min(b0 + CHUNK, NEV);
  for (int i = threadIdx.x; i < 512; i += 256) {
    basep[i] = ((i < N2V) ? rp2[i] : 0) + hblk[(size_t)b * 512 + i];
    h[i] = 0;
  }
  __syncthreads();
  for (int e = b0 + threadIdx.x; e < b1; e += 256) {
    int sv = src[e], d = dst[e];
    int p = atomicAdd(&cur1[sv], 1);
    e1[p] = e;
    int loc = atomicAdd(&h[d], 1);
    e2[basep[d] + loc] = e;
  }
}

// ---------------- dst-grouped pure gather pass (bf16 ee) ----------------
__global__ __launch_bounds__(256) void k_dst(const float* __restrict__ x1,
                                             const u16* __restrict__ eeh,
                                             const float* __restrict__ wbuf,
                                             const int* __restrict__ edge_src,
                                             const int* __restrict__ rp2,
                                             const int* __restrict__ e2,
                                             float* __restrict__ acc2) {
  __shared__ float red[4][224];
  int t = blockIdx.x / CHD;
  int chunk = blockIdx.x % CHD;
  int tid = threadIdx.x, wv = tid >> 6, l = tid & 63;
  int start = rp2[t], end = rp2[t + 1];
  int n = end - start;
  int sub = chunk * 4 + wv;                                  // 0..31
  int i0 = start + (int)(((long long)n * sub) >> 5);
  int i1 = start + (int)(((long long)n * (sub + 1)) >> 5);
  float sxa = 0.f, sxb = 0.f, s3 = 0.f, rsum = 0.f;
  int p = i0;
  for (; p + 4 <= i1; p += 4) {
    int ea = e2[p], eb = e2[p + 1], ec = e2[p + 2], ed = e2[p + 3];
    float wa = wbuf[ea], wb = wbuf[eb], wc = wbuf[ec], wdv = wbuf[ed];
    int sa = edge_src[ea], sb = edge_src[eb], sc = edge_src[ec], sd = edge_src[ed];
    float eva = bf16_to_f(eeh[(size_t)ea * 64 + l]);
    float evb = bf16_to_f(eeh[(size_t)eb * 64 + l]);
    float evc = bf16_to_f(eeh[(size_t)ec * 64 + l]);
    float evd = bf16_to_f(eeh[(size_t)ed * 64 + l]);
    float xaa = x1[(size_t)sa * 128 + l], xba = x1[(size_t)sa * 128 + 64 + l];
    float xab = x1[(size_t)sb * 128 + l], xbb = x1[(size_t)sb * 128 + 64 + l];
    float xac = x1[(size_t)sc * 128 + l], xbc = x1[(size_t)sc * 128 + 64 + l];
    float xad = x1[(size_t)sd * 128 + l], xbd = x1[(size_t)sd * 128 + 64 + l];
    rsum += (wa + wb) + (wc + wdv);
    s3 += wa * eva + wb * evb + wc * evc + wdv * evd;
    sxa += wa * xaa + wb * xab + wc * xac + wdv * xad;
    sxb += wa * xba + wb * xbb + wc * xbc + wdv * xbd;
  }
  for (; p < i1; ++p) {
    int ea = e2[p];
    float wa = wbuf[ea];
    int sa = edge_src[ea];
    rsum += wa;
    s3 += wa * bf16_to_f(eeh[(size_t)ea * 64 + l]);
    sxa += wa * x1[(size_t)sa * 128 + l];
    sxb += wa * x1[(size_t)sa * 128 + 64 + l];
  }
  red[wv][l] = sxa; red[wv][64 + l] = sxb; red[wv][128 + l] = s3;
  if (l == 0) red[wv][192] = rsum;
  __syncthreads();
  if (tid < 193) {
    float v = red[0][tid] + red[1][tid] + red[2][tid] + red[3][tid];
    if (v != 0.f) atomicAdd(&acc2[t * 256 + tid], v);
  }
}

// ---------------- dst finalize: bf16-pack sbuf2 ----------------
__global__ __launch_bounds__(256) void k_dst_final(const float* __restrict__ acc2,
                                                   u32* __restrict__ sbuf2bf,
                                                   float* __restrict__ rs2) {
  int t = blockIdx.x, tid = threadIdx.x;
  float rtot = acc2[t * 256 + 192];
  float scale = rtot > 0.f ? 1.0f / rtot : 0.f;
  if (tid < 192) {
    float o = acc2[t * 256 + tid] * scale;
    float pr = __shfl_xor(o, 1);
    if (!(tid & 1)) sbuf2bf[t * 96 + (tid >> 1)] = pack_bf16x2(o, pr);
  }
  if (tid == 192) rs2[t] = rtot;
}

// ---------------- src-grouped pure gather pass (bf16 ee); bf16-pack sbuf1 ----------------
__global__ __launch_bounds__(256) void k_src(const float* __restrict__ x2,
                                             const u16* __restrict__ eeh,
                                             const float* __restrict__ wbuf,
                                             const int* __restrict__ edge_dst,
                                             const int* __restrict__ rp1,
                                             const int* __restrict__ e1,
                                             u32* __restrict__ sbuf1bf,
                                             float* __restrict__ rs1) {
  int wid = (blockIdx.x * 256 + threadIdx.x) >> 6;
  int l = threadIdx.x & 63;
  if (wid >= N1V) return;
  int start = rp1[wid], end = rp1[wid + 1];
  float s2a = 0.f, s2b = 0.f, s1 = 0.f, rsum = 0.f;
  int p = start;
  for (; p + 4 <= end; p += 4) {
    int ea = e1[p], eb = e1[p + 1], ec = e1[p + 2], ed = e1[p + 3];
    float wa = wbuf[ea], wb = wbuf[eb], wc = wbuf[ec], wdv = wbuf[ed];
    int da = edge_dst[ea], db = edge_dst[eb], dc = edge_dst[ec], dd = edge_dst[ed];
    float eva = bf16_to_f(eeh[(size_t)ea * 64 + l]);
    float evb = bf16_to_f(eeh[(size_t)eb * 64 + l]);
    float evc = bf16_to_f(eeh[(size_t)ec * 64 + l]);
    float evd = bf16_to_f(eeh[(size_t)ed * 64 + l]);
    float xaa = x2[(size_t)da * 128 + l], xba = x2[(size_t)da * 128 + 64 + l];
    float xab = x2[(size_t)db * 128 + l], xbb = x2[(size_t)db * 128 + 64 + l];
    float xac = x2[(size_t)dc * 128 + l], xbc = x2[(size_t)dc * 128 + 64 + l];
    float xad = x2[(size_t)dd * 128 + l], xbd = x2[(size_t)dd * 128 + 64 + l];
    rsum += (wa + wb) + (wc + wdv);
    s1 += wa * eva + wb * evb + wc * evc + wdv * evd;
    s2a += wa * xaa + wb * xab + wc * xac + wdv * xad;
    s2b += wa * xba + wb * xbb + wc * xbc + wdv * xbd;
  }
  for (; p < end; ++p) {
    int ea = e1[p];
    float wa = wbuf[ea];
    int da = edge_dst[ea];
    rsum += wa;
    s1 += wa * bf16_to_f(eeh[(size_t)ea * 64 + l]);
    s2a += wa * x2[(size_t)da * 128 + l];
    s2b += wa * x2[(size_t)da * 128 + 64 + l];
  }
  float scale = (end > start) ? 1.0f / rsum : 0.f;
  float o2a = s2a * scale, o2b = s2b * scale, o1v = s1 * scale;
  float p2a = __shfl_xor(o2a, 1), p2b = __shfl_xor(o2b, 1), p1v = __shfl_xor(o1v, 1);
  if (!(l & 1)) {
    u32* baseo = sbuf1bf + (size_t)wid * 96;
    baseo[(l >> 1)] = pack_bf16x2(o2a, p2a);
    baseo[32 + (l >> 1)] = pack_bf16x2(o2b, p2b);
    baseo[64 + (l >> 1)] = pack_bf16x2(o1v, p1v);
  }
  if (l == 0) rs1[wid] = (end > start) ? rsum : 0.f;
}

// ---------------- MFMA output GEMM: out = mask * elu(A[M,320]bf16 @ a^Tbf16) ----------------
__global__ __launch_bounds__(256) void k_gemm(const u32* __restrict__ Xbf,   // row = 64 u32
                                              const u32* __restrict__ Sbf,   // row = 96 u32
                                              const u32* __restrict__ abf,   // [128][160] u32
                                              const float* __restrict__ rs,
                                              float* __restrict__ out,
                                              int M, int mode) {
  __shared__ short Bt[128 * 40];   // [n=128][k=32 bf16 + pad 8]
  int tid = threadIdx.x;
  int w = tid >> 6, l = tid & 63;
  int r = l & 15, cchunk = l >> 4;          // 0..3
  int row0 = blockIdx.x * 64;
  int gi = row0 + w * 16 + r;               // A-row this lane loads
  int gclamp = min(gi, M - 1);
  f32x4v acc[8];
#pragma unroll
  for (int i = 0; i < 8; ++i) acc[i] = (f32x4v){0.f, 0.f, 0.f, 0.f};

  for (int ks = 0; ks < 10; ++ks) {
    if (ks) __syncthreads();
    {
      int n = tid >> 1, half = tid & 1;
      const u32* srcp = abf + n * 160 + ks * 16 + half * 8;
      u32* dstp = (u32*)&Bt[n * 40] + half * 8;
      *(uint4*)(dstp) = *(const uint4*)(srcp);
      *(uint4*)(dstp + 4) = *(const uint4*)(srcp + 4);
    }
    __syncthreads();
    int ck = ks * 4 + cchunk;                // 8-elem chunk index, 0..39
    const u32* ap;
    if (mode == 0) {
      ap = (ck < 16) ? (Xbf + (size_t)gclamp * 64 + ck * 4)
                     : (Sbf + (size_t)gclamp * 96 + (ck - 16) * 4);
    } else {
      ap = (ck < 16) ? (Sbf + (size_t)gclamp * 96 + ck * 4)
         : (ck < 32) ? (Xbf + (size_t)gclamp * 64 + (ck - 16) * 4)
                     : (Sbf + (size_t)gclamp * 96 + 64 + (ck - 32) * 4);
    }
    bf16x8 afrag = *(const bf16x8*)ap;
#pragma unroll
    for (int nt = 0; nt < 8; ++nt) {
      bf16x8 bfrag = *(const bf16x8*)&Bt[(nt * 16 + r) * 40 + cchunk * 8];
      acc[nt] = __builtin_amdgcn_mfma_f32_16x16x32_bf16(afrag, bfrag, acc[nt], 0, 0, 0);
    }
  }
  int baser = row0 + w * 16 + cchunk * 4;
#pragma unroll
  for (int rr = 0; rr < 4; ++rr) {
    int go = baser + rr;
    if (go < M) {
      float rsv = rs[go];
      bool ok = rsv > 0.f;
#pragma unroll
      for (int nt = 0; nt < 8; ++nt) {
        float h = acc[nt][rr];
        float v = ok ? (h > 0.f ? h : expm1f(h)) : 0.f;
        out[(size_t)go * 128 + nt * 16 + r] = v;
      }
    }
  }
}

// =====================================================================================

static inline size_t align_up(size_t x, size_t a) { return (x + a - 1) & ~(a - 1); }

extern "C" void kernel_launch(void* const* d_in, const int* in_sizes, int n_in,
                              void* d_out, int out_size, void* d_ws, size_t ws_size,
                              hipStream_t stream) {
  const float* x1 = (const float*)d_in[0];
  const float* x2 = (const float*)d_in[1];
  const float* ee = (const float*)d_in[2];
  const float* a = (const float*)d_in[3];
  const float* a2 = (const float*)d_in[4];
  const int* esrc = (const int*)d_in[5];
  const int* edst = (const int*)d_in[6];
  float* out = (float*)d_out;

  char* base = (char*)d_ws;
  size_t off = 0;
  auto alloc = [&](size_t bytes) -> char* {
    char* p = base + off;
    off = align_up(off + bytes, 256);
    return p;
  };
  float* c = (float*)alloc(320 * 4);
  float* z1g = (float*)alloc(N1V * 4);
  float* z2g = (float*)alloc(512 * 4);
  u32* x1bf = (u32*)alloc((size_t)N1V * 64 * 4);      // 25.6 MB
  u32* x2bf = (u32*)alloc((size_t)N2V * 64 * 4);
  u32* abf = (u32*)alloc(128 * 160 * 4);              // 80 KB
  int* rp1 = (int*)alloc((N1V + 1) * 4);
  int* cur1 = (int*)alloc(N1V * 4);
  int* rp2 = (int*)alloc(512 * 4);
  int* partials = (int*)alloc(64 * 4);
  int* hblk = (int*)alloc((size_t)NB * 512 * 4);      // 4 MB
  int* tot2 = (int*)alloc(512 * 4);
  int* e1 = (int*)alloc(NEV * 4);
  int* e2 = (int*)alloc(NEV * 4);
  float* wbuf = (float*)alloc(NEV * 4);
  u32* eeh = (u32*)alloc((size_t)NEV * 128);          // 128 MB (bf16 ee)
  float* rs1 = (float*)alloc(N1V * 4);
  float* rs2 = (float*)alloc(512 * 4);
  u32* sbuf1bf = (u32*)alloc((size_t)N1V * 96 * 4);   // 38.4 MB
  u32* sbuf2bf = (u32*)alloc(512 * 96 * 4);
  float* acc2 = (float*)alloc(512 * 256 * 4);
  (void)ws_size; (void)out_size; (void)n_in; (void)in_sizes;

  hipMemsetAsync(cur1, 0, N1V * 4, stream);
  hipMemsetAsync(acc2, 0, 512 * 256 * 4, stream);

  hipLaunchKernelGGL(k_prep, dim3(2), dim3(256), 0, stream, a, a2, c);
  hipLaunchKernelGGL(k_conv, dim3((1600000 + 5120 + 8000 + 255) / 256), dim3(256), 0, stream,
                     x1, x2, a, x1bf, x2bf, abf);
  hipLaunchKernelGGL(k_z2, dim3(125), dim3(256), 0, stream, x2, c, z2g);
  hipLaunchKernelGGL(k_z1, dim3(25000), dim3(256), 0, stream, x1, c, z1g);
  hipLaunchKernelGGL(k_histw, dim3(NB), dim3(256), 0, stream,
                     esrc, edst, ee, z1g, z2g, c, cur1, hblk, wbuf, eeh);
  hipLaunchKernelGGL(k_colscan, dim3(512), dim3(256), 0, stream, hblk, tot2);

  const int nScanBlocks = (N1V + 2047) / 2048;  // 49
  hipLaunchKernelGGL(k_scanA, dim3(nScanBlocks), dim3(256), 0, stream, cur1, rp1, partials, N1V);
  hipLaunchKernelGGL(k_scanB, dim3(1), dim3(512), 0, stream, partials, nScanBlocks, tot2, rp2);
  hipLaunchKernelGGL(k_scanC, dim3((N1V + 255) / 256), dim3(256), 0, stream, rp1, cur1, partials, N1V, NEV);
  hipLaunchKernelGGL(k_scatter, dim3(NB), dim3(256), 0, stream,
                     esrc, edst, cur1, hblk, rp2, e1, e2);

  hipLaunchKernelGGL(k_dst, dim3(N2V * CHD), dim3(256), 0, stream,
                     x1, (const u16*)eeh, wbuf, esrc, rp2, e2, acc2);
  hipLaunchKernelGGL(k_dst_final, dim3(N2V), dim3(256), 0, stream, acc2, sbuf2bf, rs2);

  hipLaunchKernelGGL(k_src, dim3(N1V / 4), dim3(256), 0, stream,
                     x2, (const u16*)eeh, wbuf, edst, rp1, e1, sbuf1bf, rs1);

  hipLaunchKernelGGL(k_gemm, dim3((N1V + 63) / 64), dim3(256), 0, stream,
                     x1bf, sbuf1bf, abf, rs1, out, N1V, 0);
  hipLaunchKernelGGL(k_gemm, dim3((N2V + 63) / 64), dim3(256), 0, stream,
                     x2bf, sbuf2bf, abf, rs2, out + (size_t)N1V * 128, N2V, 1);
}

// Round 16
// 448.807 us; speedup vs baseline: 1.7743x; 1.0434x over previous
//
#include <hip/hip_runtime.h>

#define N1V 100000
#define N2V 500
#define NEV 1000000
#define ALPHAV 0.2f
#define NB 2048       // histogram/scatter blocks
#define CHUNK 489     // ceil(NEV/NB)
#define CHD 8         // dst chunks per type

typedef float f32x4 __attribute__((ext_vector_type(4)));
typedef unsigned int u32;
typedef unsigned short u16;
typedef u32 u32x2 __attribute__((ext_vector_type(2)));
using bf16x8 = __attribute__((ext_vector_type(8))) short;   // 8 bf16 (4 VGPRs)
using f32x4v = __attribute__((ext_vector_type(4))) float;

__device__ __forceinline__ u32 pack_bf16x2(float a, float b) {
  u32 ua = __float_as_uint(a), ub = __float_as_uint(b);
  u32 ra = (ua + 0x7FFFu + ((ua >> 16) & 1u)) >> 16;
  u32 rb = (ub + 0x7FFFu + ((ub >> 16) & 1u)) >> 16;
  return ra | (rb << 16);
}

__device__ __forceinline__ float bf16_to_f(u16 h) {
  return __uint_as_float(((u32)h) << 16);
}

// ---------------- prep: c[320] = a^T @ a_2 ----------------
__global__ __launch_bounds__(256) void k_prep(const float* __restrict__ a,
                                              const float* __restrict__ a2,
                                              float* __restrict__ c) {
  int p = blockIdx.x * 256 + threadIdx.x;
  if (p < 320) {
    float s = 0.f;
    for (int k = 0; k < 128; ++k) s += a2[k] * a[k * 320 + p];
    c[p] = s;
  }
}

// ---------------- fused bf16 conversions + z1/z2 dots ----------------
// region x1: thread = (row, chunk of 8 floats); 16-lane shfl butterfly -> z1g
// region a:  convert only; region x2: convert + z2 dot.
__global__ __launch_bounds__(256) void k_conv(const float* __restrict__ x1,
                                              const float* __restrict__ x2,
                                              const float* __restrict__ a,
                                              const float* __restrict__ c,
                                              u32* __restrict__ x1bf,
                                              u32* __restrict__ x2bf,
                                              u32* __restrict__ abf,
                                              float* __restrict__ z1g,
                                              float* __restrict__ z2g) {
  size_t gid = (size_t)blockIdx.x * 256 + threadIdx.x;
  const size_t n_x1 = (size_t)N1V * 16;        // 1,600,000 (64-aligned)
  const size_t n_a = 128 * 320 / 8;            // 5,120 (64-aligned)
  const size_t n_x2 = (size_t)N2V * 16;        // 8,000
  if (gid < n_x1) {
    size_t row = gid >> 4; int chunk = (int)(gid & 15);
    const f32x4* s = (const f32x4*)(x1 + row * 128 + chunk * 8);
    f32x4 v0 = s[0], v1 = s[1];
    uint4 o;
    o.x = pack_bf16x2(v0.x, v0.y); o.y = pack_bf16x2(v0.z, v0.w);
    o.z = pack_bf16x2(v1.x, v1.y); o.w = pack_bf16x2(v1.z, v1.w);
    *(uint4*)(x1bf + row * 64 + chunk * 4) = o;
    const float* cp = c + chunk * 8;
    float d = v0.x * cp[0] + v0.y * cp[1] + v0.z * cp[2] + v0.w * cp[3] +
              v1.x * cp[4] + v1.y * cp[5] + v1.z * cp[6] + v1.w * cp[7];
#pragma unroll
    for (int off = 1; off < 16; off <<= 1) d += __shfl_xor(d, off, 64);
    if (chunk == 0) z1g[row] = d;
  } else if (gid < n_x1 + n_a) {
    size_t idx = gid - n_x1;
    const f32x4* s = (const f32x4*)(a + idx * 8);
    f32x4 v0 = s[0], v1 = s[1];
    uint4 o;
    o.x = pack_bf16x2(v0.x, v0.y); o.y = pack_bf16x2(v0.z, v0.w);
    o.z = pack_bf16x2(v1.x, v1.y); o.w = pack_bf16x2(v1.z, v1.w);
    *(uint4*)(abf + idx * 4) = o;
  } else if (gid < n_x1 + n_a + n_x2) {
    size_t idx = gid - n_x1 - n_a;
    size_t row = idx >> 4; int chunk = (int)(idx & 15);
    const f32x4* s = (const f32x4*)(x2 + row * 128 + chunk * 8);
    f32x4 v0 = s[0], v1 = s[1];
    uint4 o;
    o.x = pack_bf16x2(v0.x, v0.y); o.y = pack_bf16x2(v0.z, v0.w);
    o.z = pack_bf16x2(v1.x, v1.y); o.w = pack_bf16x2(v1.z, v1.w);
    *(uint4*)(x2bf + row * 64 + chunk * 4) = o;
    const float* cp = c + 128 + chunk * 8;
    float d = v0.x * cp[0] + v0.y * cp[1] + v0.z * cp[2] + v0.w * cp[3] +
              v1.x * cp[4] + v1.y * cp[5] + v1.z * cp[6] + v1.w * cp[7];
#pragma unroll
    for (int off = 1; off < 16; off <<= 1) d += __shfl_xor(d, off, 64);
    if (chunk == 0) z2g[row] = d;
  }
}

// ---------------- fused linear pass: histograms + w + in-stage bf16 transcode ----------------
__global__ __launch_bounds__(256) void k_histw(const int* __restrict__ src,
                                               const int* __restrict__ dst,
                                               const float* __restrict__ ee,
                                               const float* __restrict__ z1g,
                                               const float* __restrict__ z2g,
                                               const float* __restrict__ c,
                                               int* __restrict__ c1,
                                               int* __restrict__ hblk,
                                               float* __restrict__ wbuf,
                                               u32* __restrict__ eeh) {
  __shared__ float tile[128 * 65];
  __shared__ int h[512];
  for (int i = threadIdx.x; i < 512; i += 256) h[i] = 0;
  int tid = threadIdx.x;
  int half = tid & 1, j = tid >> 1;
  float creg[32];
#pragma unroll
  for (int k = 0; k < 32; ++k) creg[k] = c[256 + half * 32 + k];
  __syncthreads();

  int b = blockIdx.x;
  int b0 = b * CHUNK, b1 = min(b0 + CHUNK, NEV);
  for (int ts = b0; ts < b1; ts += 128) {
    int nt = min(128, b1 - ts);
    __syncthreads();
    // stage: coalesced f32x4 reads -> LDS stride 65, + register transcode to eeh
#pragma unroll
    for (int i = 0; i < 8; ++i) {
      int idx = i * 256 + tid;          // 0..2047 -> (row, 16B-chunk)
      int r = idx >> 4, cc = idx & 15;
      if (r < nt) {
        f32x4 v = __builtin_nontemporal_load((const f32x4*)(ee + (size_t)(ts + r) * 64) + cc);
        int basef = r * 65 + cc * 4;
        tile[basef + 0] = v.x; tile[basef + 1] = v.y;
        tile[basef + 2] = v.z; tile[basef + 3] = v.w;
        u32x2 o;
        o.x = pack_bf16x2(v.x, v.y);
        o.y = pack_bf16x2(v.z, v.w);
        *(u32x2*)(eeh + (size_t)(ts + r) * 32 + cc * 2) = o;
      }
    }
    __syncthreads();
    // dot + w
    if (j < nt) {
      float dotv = 0.f;
      int basef = j * 65 + half * 32;
#pragma unroll
      for (int k = 0; k < 32; ++k) dotv += tile[basef + k] * creg[k];
      dotv += __shfl_xor(dotv, 1);
      if (half == 0) {
        int e = ts + j;
        int sv = src[e], d = dst[e];
        float z = z1g[sv] + z2g[d] + dotv;
        float zp = z > 0.f ? z : ALPHAV * z;
        wbuf[e] = __expf(-zp);
        atomicAdd(&c1[sv], 1);
        atomicAdd(&h[d], 1);
      }
    }
  }
  __syncthreads();
  for (int i = threadIdx.x; i < 512; i += 256) hblk[(size_t)b * 512 + i] = h[i];
}

// ---------------- column scan over NB blocks ----------------
__global__ __launch_bounds__(256) void k_colscan(int* __restrict__ hblk,
                                                 int* __restrict__ tot2) {
  __shared__ int s[256];
  int t = blockIdx.x;
  int tid = threadIdx.x;
  int v[8]; int tot = 0;
#pragma unroll
  for (int j = 0; j < 8; ++j) {
    int b = tid * 8 + j;
    v[j] = hblk[(size_t)b * 512 + t];
    tot += v[j];
  }
  s[tid] = tot; __syncthreads();
  for (int off = 1; off < 256; off <<= 1) {
    int tv = (tid >= off) ? s[tid - off] : 0;
    __syncthreads();
    if (tid >= off) s[tid] += tv;
    __syncthreads();
  }
  int run = s[tid] - tot;
#pragma unroll
  for (int j = 0; j < 8; ++j) {
    int b = tid * 8 + j;
    hblk[(size_t)b * 512 + t] = run;
    run += v[j];
  }
  if (tid == 255) tot2[t] = run;
}

// ---------------- scan for src counts ----------------
__global__ __launch_bounds__(256) void k_scanA(const int* __restrict__ cnt,
                                               int* __restrict__ outp,
                                               int* __restrict__ partials, int n) {
  __shared__ int s[256];
  int tid = threadIdx.x;
  int base = blockIdx.x * 2048 + tid * 8;
  int v[8]; int tot = 0;
#pragma unroll
  for (int j = 0; j < 8; ++j) { int idx = base + j; v[j] = (idx < n) ? cnt[idx] : 0; tot += v[j]; }
  s[tid] = tot; __syncthreads();
  for (int off = 1; off < 256; off <<= 1) {
    int tv = 0;
    if (tid >= off) tv = s[tid - off];
    __syncthreads();
    if (tid >= off) s[tid] += tv;
    __syncthreads();
  }
  int run = s[tid] - tot;
#pragma unroll
  for (int j = 0; j < 8; ++j) { int idx = base + j; if (idx < n) outp[idx] = run; run += v[j]; }
  if (tid == 255) partials[blockIdx.x] = s[255];
}

__global__ __launch_bounds__(512) void k_scanB(int* __restrict__ partials, int nPart,
                                               const int* __restrict__ tot2,
                                               int* __restrict__ rp2) {
  __shared__ int s[512];
  int tid = threadIdx.x;
  int v = (tid < N2V) ? tot2[tid] : 0;
  s[tid] = v; __syncthreads();
  for (int off = 1; off < 512; off <<= 1) {
    int tv = 0;
    if (tid >= off) tv = s[tid - off];
    __syncthreads();
    if (tid >= off) s[tid] += tv;
    __syncthreads();
  }
  if (tid < N2V) rp2[tid] = s[tid] - v;
  if (tid == N2V - 1) rp2[N2V] = s[tid];
  if (tid == 0) {
    int run = 0;
    for (int b = 0; b < nPart; ++b) { int t = partials[b]; partials[b] = run; run += t; }
  }
}

__global__ __launch_bounds__(256) void k_scanC(int* __restrict__ rp, int* __restrict__ cur,
                                               const int* __restrict__ partials, int n, int total) {
  int i = blockIdx.x * 256 + threadIdx.x;
  if (i < n) {
    int v = rp[i] + partials[i >> 11];
    rp[i] = v; cur[i] = v;
  }
  if (i == 0) rp[n] = total;
}

// ---------------- light scatter: CSR placement only ----------------
__global__ __launch_bounds__(256) void k_scatter(const int* __restrict__ src,
                                                 const int* __restrict__ dst,
                                                 int* __restrict__ cur1,
                                                 const int* __restrict__ hblk,
                                                 const int* __restrict__ rp2,
                                                 int* __restrict__ e1, int* __restrict__ e2) {
  __shared__ int h[512];
  __shared__ int basep[512];
  int b = blockIdx.x;
  int b0 = b * CHUNK, b1 = min(b0 + CHUNK, NEV);
  for (int i = threadIdx.x; i < 512; i += 256) {
    basep[i] = ((i < N2V) ? rp2[i] : 0) + hblk[(size_t)b * 512 + i];
    h[i] = 0;
  }
  __syncthreads();
  for (int e = b0 + threadIdx.x; e < b1; e += 256) {
    int sv = src[e], d = dst[e];
    int p = atomicAdd(&cur1[sv], 1);
    e1[p] = e;
    int loc = atomicAdd(&h[d], 1);
    e2[basep[d] + loc] = e;
  }
}

// ---------------- dst-grouped pure gather pass (bf16 ee) ----------------
__global__ __launch_bounds__(256) void k_dst(const float* __restrict__ x1,
                                             const u16* __restrict__ eeh,
                                             const float* __restrict__ wbuf,
                                             const int* __restrict__ edge_src,
                                             const int* __restrict__ rp2,
                                             const int* __restrict__ e2,
                                             float* __restrict__ acc2) {
  __shared__ float red[4][224];
  int t = blockIdx.x / CHD;
  int chunk = blockIdx.x % CHD;
  int tid = threadIdx.x, wv = tid >> 6, l = tid & 63;
  int start = rp2[t], end = rp2[t + 1];
  int n = end - start;
  int sub = chunk * 4 + wv;                                  // 0..31
  int i0 = start + (int)(((long long)n * sub) >> 5);
  int i1 = start + (int)(((long long)n * (sub + 1)) >> 5);
  float sxa = 0.f, sxb = 0.f, s3 = 0.f, rsum = 0.f;
  int p = i0;
  for (; p + 4 <= i1; p += 4) {
    int ea = e2[p], eb = e2[p + 1], ec = e2[p + 2], ed = e2[p + 3];
    float wa = wbuf[ea], wb = wbuf[eb], wc = wbuf[ec], wdv = wbuf[ed];
    int sa = edge_src[ea], sb = edge_src[eb], sc = edge_src[ec], sd = edge_src[ed];
    float eva = bf16_to_f(eeh[(size_t)ea * 64 + l]);
    float evb = bf16_to_f(eeh[(size_t)eb * 64 + l]);
    float evc = bf16_to_f(eeh[(size_t)ec * 64 + l]);
    float evd = bf16_to_f(eeh[(size_t)ed * 64 + l]);
    float xaa = x1[(size_t)sa * 128 + l], xba = x1[(size_t)sa * 128 + 64 + l];
    float xab = x1[(size_t)sb * 128 + l], xbb = x1[(size_t)sb * 128 + 64 + l];
    float xac = x1[(size_t)sc * 128 + l], xbc = x1[(size_t)sc * 128 + 64 + l];
    float xad = x1[(size_t)sd * 128 + l], xbd = x1[(size_t)sd * 128 + 64 + l];
    rsum += (wa + wb) + (wc + wdv);
    s3 += wa * eva + wb * evb + wc * evc + wdv * evd;
    sxa += wa * xaa + wb * xab + wc * xac + wdv * xad;
    sxb += wa * xba + wb * xbb + wc * xbc + wdv * xbd;
  }
  for (; p < i1; ++p) {
    int ea = e2[p];
    float wa = wbuf[ea];
    int sa = edge_src[ea];
    rsum += wa;
    s3 += wa * bf16_to_f(eeh[(size_t)ea * 64 + l]);
    sxa += wa * x1[(size_t)sa * 128 + l];
    sxb += wa * x1[(size_t)sa * 128 + 64 + l];
  }
  red[wv][l] = sxa; red[wv][64 + l] = sxb; red[wv][128 + l] = s3;
  if (l == 0) red[wv][192] = rsum;
  __syncthreads();
  if (tid < 193) {
    float v = red[0][tid] + red[1][tid] + red[2][tid] + red[3][tid];
    if (v != 0.f) atomicAdd(&acc2[t * 256 + tid], v);
  }
}

// ---------------- dst finalize: bf16-pack sbuf2 ----------------
__global__ __launch_bounds__(256) void k_dst_final(const float* __restrict__ acc2,
                                                   u32* __restrict__ sbuf2bf,
                                                   float* __restrict__ rs2) {
  int t = blockIdx.x, tid = threadIdx.x;
  float rtot = acc2[t * 256 + 192];
  float scale = rtot > 0.f ? 1.0f / rtot : 0.f;
  if (tid < 192) {
    float o = acc2[t * 256 + tid] * scale;
    float pr = __shfl_xor(o, 1);
    if (!(tid & 1)) sbuf2bf[t * 96 + (tid >> 1)] = pack_bf16x2(o, pr);
  }
  if (tid == 192) rs2[t] = rtot;
}

// ---------------- src-grouped pure gather pass (bf16 ee); bf16-pack sbuf1 ----------------
__global__ __launch_bounds__(256) void k_src(const float* __restrict__ x2,
                                             const u16* __restrict__ eeh,
                                             const float* __restrict__ wbuf,
                                             const int* __restrict__ edge_dst,
                                             const int* __restrict__ rp1,
                                             const int* __restrict__ e1,
                                             u32* __restrict__ sbuf1bf,
                                             float* __restrict__ rs1) {
  int wid = (blockIdx.x * 256 + threadIdx.x) >> 6;
  int l = threadIdx.x & 63;
  if (wid >= N1V) return;
  int start = rp1[wid], end = rp1[wid + 1];
  float s2a = 0.f, s2b = 0.f, s1 = 0.f, rsum = 0.f;
  int p = start;
  for (; p + 4 <= end; p += 4) {
    int ea = e1[p], eb = e1[p + 1], ec = e1[p + 2], ed = e1[p + 3];
    float wa = wbuf[ea], wb = wbuf[eb], wc = wbuf[ec], wdv = wbuf[ed];
    int da = edge_dst[ea], db = edge_dst[eb], dc = edge_dst[ec], dd = edge_dst[ed];
    float eva = bf16_to_f(eeh[(size_t)ea * 64 + l]);
    float evb = bf16_to_f(eeh[(size_t)eb * 64 + l]);
    float evc = bf16_to_f(eeh[(size_t)ec * 64 + l]);
    float evd = bf16_to_f(eeh[(size_t)ed * 64 + l]);
    float xaa = x2[(size_t)da * 128 + l], xba = x2[(size_t)da * 128 + 64 + l];
    float xab = x2[(size_t)db * 128 + l], xbb = x2[(size_t)db * 128 + 64 + l];
    float xac = x2[(size_t)dc * 128 + l], xbc = x2[(size_t)dc * 128 + 64 + l];
    float xad = x2[(size_t)dd * 128 + l], xbd = x2[(size_t)dd * 128 + 64 + l];
    rsum += (wa + wb) + (wc + wdv);
    s1 += wa * eva + wb * evb + wc * evc + wdv * evd;
    s2a += wa * xaa + wb * xab + wc * xac + wdv * xad;
    s2b += wa * xba + wb * xbb + wc * xbc + wdv * xbd;
  }
  for (; p < end; ++p) {
    int ea = e1[p];
    float wa = wbuf[ea];
    int da = edge_dst[ea];
    rsum += wa;
    s1 += wa * bf16_to_f(eeh[(size_t)ea * 64 + l]);
    s2a += wa * x2[(size_t)da * 128 + l];
    s2b += wa * x2[(size_t)da * 128 + 64 + l];
  }
  float scale = (end > start) ? 1.0f / rsum : 0.f;
  float o2a = s2a * scale, o2b = s2b * scale, o1v = s1 * scale;
  float p2a = __shfl_xor(o2a, 1), p2b = __shfl_xor(o2b, 1), p1v = __shfl_xor(o1v, 1);
  if (!(l & 1)) {
    u32* baseo = sbuf1bf + (size_t)wid * 96;
    baseo[(l >> 1)] = pack_bf16x2(o2a, p2a);
    baseo[32 + (l >> 1)] = pack_bf16x2(o2b, p2b);
    baseo[64 + (l >> 1)] = pack_bf16x2(o1v, p1v);
  }
  if (l == 0) rs1[wid] = (end > start) ? rsum : 0.f;
}

// ---------------- MFMA output GEMM: out = mask * elu(A[M,320]bf16 @ a^Tbf16) ----------------
__global__ __launch_bounds__(256) void k_gemm(const u32* __restrict__ Xbf,   // row = 64 u32
                                              const u32* __restrict__ Sbf,   // row = 96 u32
                                              const u32* __restrict__ abf,   // [128][160] u32
                                              const float* __restrict__ rs,
                                              float* __restrict__ out,
                                              int M, int mode) {
  __shared__ short Bt[128 * 40];   // [n=128][k=32 bf16 + pad 8]
  int tid = threadIdx.x;
  int w = tid >> 6, l = tid & 63;
  int r = l & 15, cchunk = l >> 4;          // 0..3
  int row0 = blockIdx.x * 64;
  int gi = row0 + w * 16 + r;               // A-row this lane loads
  int gclamp = min(gi, M - 1);
  f32x4v acc[8];
#pragma unroll
  for (int i = 0; i < 8; ++i) acc[i] = (f32x4v){0.f, 0.f, 0.f, 0.f};

  for (int ks = 0; ks < 10; ++ks) {
    if (ks) __syncthreads();
    {
      int n = tid >> 1, half = tid & 1;
      const u32* srcp = abf + n * 160 + ks * 16 + half * 8;
      u32* dstp = (u32*)&Bt[n * 40] + half * 8;
      *(uint4*)(dstp) = *(const uint4*)(srcp);
      *(uint4*)(dstp + 4) = *(const uint4*)(srcp + 4);
    }
    __syncthreads();
    int ck = ks * 4 + cchunk;                // 8-elem chunk index, 0..39
    const u32* ap;
    if (mode == 0) {
      ap = (ck < 16) ? (Xbf + (size_t)gclamp * 64 + ck * 4)
                     : (Sbf + (size_t)gclamp * 96 + (ck - 16) * 4);
    } else {
      ap = (ck < 16) ? (Sbf + (size_t)gclamp * 96 + ck * 4)
         : (ck < 32) ? (Xbf + (size_t)gclamp * 64 + (ck - 16) * 4)
                     : (Sbf + (size_t)gclamp * 96 + 64 + (ck - 32) * 4);
    }
    bf16x8 afrag = *(const bf16x8*)ap;
#pragma unroll
    for (int nt = 0; nt < 8; ++nt) {
      bf16x8 bfrag = *(const bf16x8*)&Bt[(nt * 16 + r) * 40 + cchunk * 8];
      acc[nt] = __builtin_amdgcn_mfma_f32_16x16x32_bf16(afrag, bfrag, acc[nt], 0, 0, 0);
    }
  }
  int baser = row0 + w * 16 + cchunk * 4;
#pragma unroll
  for (int rr = 0; rr < 4; ++rr) {
    int go = baser + rr;
    if (go < M) {
      float rsv = rs[go];
      bool ok = rsv > 0.f;
#pragma unroll
      for (int nt = 0; nt < 8; ++nt) {
        float h = acc[nt][rr];
        float v = ok ? (h > 0.f ? h : expm1f(h)) : 0.f;
        out[(size_t)go * 128 + nt * 16 + r] = v;
      }
    }
  }
}

// =====================================================================================

static inline size_t align_up(size_t x, size_t a) { return (x + a - 1) & ~(a - 1); }

extern "C" void kernel_launch(void* const* d_in, const int* in_sizes, int n_in,
                              void* d_out, int out_size, void* d_ws, size_t ws_size,
                              hipStream_t stream) {
  const float* x1 = (const float*)d_in[0];
  const float* x2 = (const float*)d_in[1];
  const float* ee = (const float*)d_in[2];
  const float* a = (const float*)d_in[3];
  const float* a2 = (const float*)d_in[4];
  const int* esrc = (const int*)d_in[5];
  const int* edst = (const int*)d_in[6];
  float* out = (float*)d_out;

  char* base = (char*)d_ws;
  size_t off = 0;
  auto alloc = [&](size_t bytes) -> char* {
    char* p = base + off;
    off = align_up(off + bytes, 256);
    return p;
  };
  float* c = (float*)alloc(320 * 4);
  float* z1g = (float*)alloc(N1V * 4);
  float* z2g = (float*)alloc(512 * 4);
  u32* x1bf = (u32*)alloc((size_t)N1V * 64 * 4);      // 25.6 MB
  u32* x2bf = (u32*)alloc((size_t)N2V * 64 * 4);
  u32* abf = (u32*)alloc(128 * 160 * 4);              // 80 KB
  int* rp1 = (int*)alloc((N1V + 1) * 4);
  int* cur1 = (int*)alloc(N1V * 4);
  int* rp2 = (int*)alloc(512 * 4);
  int* partials = (int*)alloc(64 * 4);
  int* hblk = (int*)alloc((size_t)NB * 512 * 4);      // 4 MB
  int* tot2 = (int*)alloc(512 * 4);
  int* e1 = (int*)alloc(NEV * 4);
  int* e2 = (int*)alloc(NEV * 4);
  float* wbuf = (float*)alloc(NEV * 4);
  u32* eeh = (u32*)alloc((size_t)NEV * 128);          // 128 MB (bf16 ee)
  float* rs1 = (float*)alloc(N1V * 4);
  float* rs2 = (float*)alloc(512 * 4);
  u32* sbuf1bf = (u32*)alloc((size_t)N1V * 96 * 4);   // 38.4 MB
  u32* sbuf2bf = (u32*)alloc(512 * 96 * 4);
  float* acc2 = (float*)alloc(512 * 256 * 4);
  (void)ws_size; (void)out_size; (void)n_in; (void)in_sizes;

  hipMemsetAsync(cur1, 0, N1V * 4, stream);
  hipMemsetAsync(acc2, 0, 512 * 256 * 4, stream);

  hipLaunchKernelGGL(k_prep, dim3(2), dim3(256), 0, stream, a, a2, c);
  hipLaunchKernelGGL(k_conv, dim3((1600000 + 5120 + 8000 + 255) / 256), dim3(256), 0, stream,
                     x1, x2, a, c, x1bf, x2bf, abf, z1g, z2g);
  hipLaunchKernelGGL(k_histw, dim3(NB), dim3(256), 0, stream,
                     esrc, edst, ee, z1g, z2g, c, cur1, hblk, wbuf, eeh);
  hipLaunchKernelGGL(k_colscan, dim3(512), dim3(256), 0, stream, hblk, tot2);

  const int nScanBlocks = (N1V + 2047) / 2048;  // 49
  hipLaunchKernelGGL(k_scanA, dim3(nScanBlocks), dim3(256), 0, stream, cur1, rp1, partials, N1V);
  hipLaunchKernelGGL(k_scanB, dim3(1), dim3(512), 0, stream, partials, nScanBlocks, tot2, rp2);
  hipLaunchKernelGGL(k_scanC, dim3((N1V + 255) / 256), dim3(256), 0, stream, rp1, cur1, partials, N1V, NEV);
  hipLaunchKernelGGL(k_scatter, dim3(NB), dim3(256), 0, stream,
                     esrc, edst, cur1, hblk, rp2, e1, e2);

  hipLaunchKernelGGL(k_dst, dim3(N2V * CHD), dim3(256), 0, stream,
                     x1, (const u16*)eeh, wbuf, esrc, rp2, e2, acc2);
  hipLaunchKernelGGL(k_dst_final, dim3(N2V), dim3(256), 0, stream, acc2, sbuf2bf, rs2);

  hipLaunchKernelGGL(k_src, dim3(N1V / 4), dim3(256), 0, stream,
                     x2, (const u16*)eeh, wbuf, edst, rp1, e1, sbuf1bf, rs1);

  hipLaunchKernelGGL(k_gemm, dim3((N1V + 63) / 64), dim3(256), 0, stream,
                     x1bf, sbuf1bf, abf, rs1, out, N1V, 0);
  hipLaunchKernelGGL(k_gemm, dim3((N2V + 63) / 64), dim3(256), 0, stream,
                     x2bf, sbuf2bf, abf, rs2, out + (size_t)N1V * 128, N2V, 1);
}

// Round 17
// 447.578 us; speedup vs baseline: 1.7792x; 1.0027x over previous
//
#include <hip/hip_runtime.h>

#define N1V 100000
#define N2V 500
#define NEV 1000000
#define ALPHAV 0.2f
#define NB 2048       // histogram/scatter blocks
#define CHUNK 489     // ceil(NEV/NB)
#define CHD 8         // dst chunks per type

typedef float f32x4 __attribute__((ext_vector_type(4)));
typedef unsigned int u32;
typedef unsigned short u16;
typedef u32 u32x2 __attribute__((ext_vector_type(2)));
using bf16x8 = __attribute__((ext_vector_type(8))) short;   // 8 bf16 (4 VGPRs)
using f32x4v = __attribute__((ext_vector_type(4))) float;

__device__ __forceinline__ u32 pack_bf16x2(float a, float b) {
  u32 ua = __float_as_uint(a), ub = __float_as_uint(b);
  u32 ra = (ua + 0x7FFFu + ((ua >> 16) & 1u)) >> 16;
  u32 rb = (ub + 0x7FFFu + ((ub >> 16) & 1u)) >> 16;
  return ra | (rb << 16);
}

__device__ __forceinline__ float bf16_lo(u32 v) { return __uint_as_float(v << 16); }
__device__ __forceinline__ float bf16_hi(u32 v) { return __uint_as_float(v & 0xFFFF0000u); }
__device__ __forceinline__ float bf16_to_f(u16 h) {
  return __uint_as_float(((u32)h) << 16);
}

// ---------------- prep: c[320] = a^T @ a_2 ----------------
__global__ __launch_bounds__(256) void k_prep(const float* __restrict__ a,
                                              const float* __restrict__ a2,
                                              float* __restrict__ c) {
  int p = blockIdx.x * 256 + threadIdx.x;
  if (p < 320) {
    float s = 0.f;
    for (int k = 0; k < 128; ++k) s += a2[k] * a[k * 320 + p];
    c[p] = s;
  }
}

// ---------------- fused bf16 conversions + z1/z2 dots ----------------
__global__ __launch_bounds__(256) void k_conv(const float* __restrict__ x1,
                                              const float* __restrict__ x2,
                                              const float* __restrict__ a,
                                              const float* __restrict__ c,
                                              u32* __restrict__ x1bf,
                                              u32* __restrict__ x2bf,
                                              u32* __restrict__ abf,
                                              float* __restrict__ z1g,
                                              float* __restrict__ z2g) {
  size_t gid = (size_t)blockIdx.x * 256 + threadIdx.x;
  const size_t n_x1 = (size_t)N1V * 16;        // 1,600,000 (64-aligned)
  const size_t n_a = 128 * 320 / 8;            // 5,120 (64-aligned)
  const size_t n_x2 = (size_t)N2V * 16;        // 8,000
  if (gid < n_x1) {
    size_t row = gid >> 4; int chunk = (int)(gid & 15);
    const f32x4* s = (const f32x4*)(x1 + row * 128 + chunk * 8);
    f32x4 v0 = s[0], v1 = s[1];
    uint4 o;
    o.x = pack_bf16x2(v0.x, v0.y); o.y = pack_bf16x2(v0.z, v0.w);
    o.z = pack_bf16x2(v1.x, v1.y); o.w = pack_bf16x2(v1.z, v1.w);
    *(uint4*)(x1bf + row * 64 + chunk * 4) = o;
    const float* cp = c + chunk * 8;
    float d = v0.x * cp[0] + v0.y * cp[1] + v0.z * cp[2] + v0.w * cp[3] +
              v1.x * cp[4] + v1.y * cp[5] + v1.z * cp[6] + v1.w * cp[7];
#pragma unroll
    for (int off = 1; off < 16; off <<= 1) d += __shfl_xor(d, off, 64);
    if (chunk == 0) z1g[row] = d;
  } else if (gid < n_x1 + n_a) {
    size_t idx = gid - n_x1;
    const f32x4* s = (const f32x4*)(a + idx * 8);
    f32x4 v0 = s[0], v1 = s[1];
    uint4 o;
    o.x = pack_bf16x2(v0.x, v0.y); o.y = pack_bf16x2(v0.z, v0.w);
    o.z = pack_bf16x2(v1.x, v1.y); o.w = pack_bf16x2(v1.z, v1.w);
    *(uint4*)(abf + idx * 4) = o;
  } else if (gid < n_x1 + n_a + n_x2) {
    size_t idx = gid - n_x1 - n_a;
    size_t row = idx >> 4; int chunk = (int)(idx & 15);
    const f32x4* s = (const f32x4*)(x2 + row * 128 + chunk * 8);
    f32x4 v0 = s[0], v1 = s[1];
    uint4 o;
    o.x = pack_bf16x2(v0.x, v0.y); o.y = pack_bf16x2(v0.z, v0.w);
    o.z = pack_bf16x2(v1.x, v1.y); o.w = pack_bf16x2(v1.z, v1.w);
    *(uint4*)(x2bf + row * 64 + chunk * 4) = o;
    const float* cp = c + 128 + chunk * 8;
    float d = v0.x * cp[0] + v0.y * cp[1] + v0.z * cp[2] + v0.w * cp[3] +
              v1.x * cp[4] + v1.y * cp[5] + v1.z * cp[6] + v1.w * cp[7];
#pragma unroll
    for (int off = 1; off < 16; off <<= 1) d += __shfl_xor(d, off, 64);
    if (chunk == 0) z2g[row] = d;
  }
}

// ---------------- fused linear pass: histograms + w + in-stage bf16 transcode ----------------
__global__ __launch_bounds__(256) void k_histw(const int* __restrict__ src,
                                               const int* __restrict__ dst,
                                               const float* __restrict__ ee,
                                               const float* __restrict__ z1g,
                                               const float* __restrict__ z2g,
                                               const float* __restrict__ c,
                                               int* __restrict__ c1,
                                               int* __restrict__ hblk,
                                               float* __restrict__ wbuf,
                                               u32* __restrict__ eeh) {
  __shared__ float tile[128 * 65];
  __shared__ int h[512];
  for (int i = threadIdx.x; i < 512; i += 256) h[i] = 0;
  int tid = threadIdx.x;
  int half = tid & 1, j = tid >> 1;
  float creg[32];
#pragma unroll
  for (int k = 0; k < 32; ++k) creg[k] = c[256 + half * 32 + k];
  __syncthreads();

  int b = blockIdx.x;
  int b0 = b * CHUNK, b1 = min(b0 + CHUNK, NEV);
  for (int ts = b0; ts < b1; ts += 128) {
    int nt = min(128, b1 - ts);
    __syncthreads();
#pragma unroll
    for (int i = 0; i < 8; ++i) {
      int idx = i * 256 + tid;          // 0..2047 -> (row, 16B-chunk)
      int r = idx >> 4, cc = idx & 15;
      if (r < nt) {
        f32x4 v = __builtin_nontemporal_load((const f32x4*)(ee + (size_t)(ts + r) * 64) + cc);
        int basef = r * 65 + cc * 4;
        tile[basef + 0] = v.x; tile[basef + 1] = v.y;
        tile[basef + 2] = v.z; tile[basef + 3] = v.w;
        u32x2 o;
        o.x = pack_bf16x2(v.x, v.y);
        o.y = pack_bf16x2(v.z, v.w);
        *(u32x2*)(eeh + (size_t)(ts + r) * 32 + cc * 2) = o;
      }
    }
    __syncthreads();
    if (j < nt) {
      float dotv = 0.f;
      int basef = j * 65 + half * 32;
#pragma unroll
      for (int k = 0; k < 32; ++k) dotv += tile[basef + k] * creg[k];
      dotv += __shfl_xor(dotv, 1);
      if (half == 0) {
        int e = ts + j;
        int sv = src[e], d = dst[e];
        float z = z1g[sv] + z2g[d] + dotv;
        float zp = z > 0.f ? z : ALPHAV * z;
        wbuf[e] = __expf(-zp);
        atomicAdd(&c1[sv], 1);
        atomicAdd(&h[d], 1);
      }
    }
  }
  __syncthreads();
  for (int i = threadIdx.x; i < 512; i += 256) hblk[(size_t)b * 512 + i] = h[i];
}

// ---------------- column scan over NB blocks ----------------
__global__ __launch_bounds__(256) void k_colscan(int* __restrict__ hblk,
                                                 int* __restrict__ tot2) {
  __shared__ int s[256];
  int t = blockIdx.x;
  int tid = threadIdx.x;
  int v[8]; int tot = 0;
#pragma unroll
  for (int j = 0; j < 8; ++j) {
    int b = tid * 8 + j;
    v[j] = hblk[(size_t)b * 512 + t];
    tot += v[j];
  }
  s[tid] = tot; __syncthreads();
  for (int off = 1; off < 256; off <<= 1) {
    int tv = (tid >= off) ? s[tid - off] : 0;
    __syncthreads();
    if (tid >= off) s[tid] += tv;
    __syncthreads();
  }
  int run = s[tid] - tot;
#pragma unroll
  for (int j = 0; j < 8; ++j) {
    int b = tid * 8 + j;
    hblk[(size_t)b * 512 + t] = run;
    run += v[j];
  }
  if (tid == 255) tot2[t] = run;
}

// ---------------- scan for src counts ----------------
__global__ __launch_bounds__(256) void k_scanA(const int* __restrict__ cnt,
                                               int* __restrict__ outp,
                                               int* __restrict__ partials, int n) {
  __shared__ int s[256];
  int tid = threadIdx.x;
  int base = blockIdx.x * 2048 + tid * 8;
  int v[8]; int tot = 0;
#pragma unroll
  for (int j = 0; j < 8; ++j) { int idx = base + j; v[j] = (idx < n) ? cnt[idx] : 0; tot += v[j]; }
  s[tid] = tot; __syncthreads();
  for (int off = 1; off < 256; off <<= 1) {
    int tv = 0;
    if (tid >= off) tv = s[tid - off];
    __syncthreads();
    if (tid >= off) s[tid] += tv;
    __syncthreads();
  }
  int run = s[tid] - tot;
#pragma unroll
  for (int j = 0; j < 8; ++j) { int idx = base + j; if (idx < n) outp[idx] = run; run += v[j]; }
  if (tid == 255) partials[blockIdx.x] = s[255];
}

__global__ __launch_bounds__(512) void k_scanB(int* __restrict__ partials, int nPart,
                                               const int* __restrict__ tot2,
                                               int* __restrict__ rp2) {
  __shared__ int s[512];
  int tid = threadIdx.x;
  int v = (tid < N2V) ? tot2[tid] : 0;
  s[tid] = v; __syncthreads();
  for (int off = 1; off < 512; off <<= 1) {
    int tv = 0;
    if (tid >= off) tv = s[tid - off];
    __syncthreads();
    if (tid >= off) s[tid] += tv;
    __syncthreads();
  }
  if (tid < N2V) rp2[tid] = s[tid] - v;
  if (tid == N2V - 1) rp2[N2V] = s[tid];
  if (tid == 0) {
    int run = 0;
    for (int b = 0; b < nPart; ++b) { int t = partials[b]; partials[b] = run; run += t; }
  }
}

__global__ __launch_bounds__(256) void k_scanC(int* __restrict__ rp, int* __restrict__ cur,
                                               const int* __restrict__ partials, int n, int total) {
  int i = blockIdx.x * 256 + threadIdx.x;
  if (i < n) {
    int v = rp[i] + partials[i >> 11];
    rp[i] = v; cur[i] = v;
  }
  if (i == 0) rp[n] = total;
}

// ---------------- light scatter: CSR placement only ----------------
__global__ __launch_bounds__(256) void k_scatter(const int* __restrict__ src,
                                                 const int* __restrict__ dst,
                                                 int* __restrict__ cur1,
                                                 const int* __restrict__ hblk,
                                                 const int* __restrict__ rp2,
                                                 int* __restrict__ e1, int* __restrict__ e2) {
  __shared__ int h[512];
  __shared__ int basep[512];
  int b = blockIdx.x;
  int b0 = b * CHUNK, b1 = min(b0 + CHUNK, NEV);
  for (int i = threadIdx.x; i < 512; i += 256) {
    basep[i] = ((i < N2V) ? rp2[i] : 0) + hblk[(size_t)b * 512 + i];
    h[i] = 0;
  }
  __syncthreads();
  for (int e = b0 + threadIdx.x; e < b1; e += 256) {
    int sv = src[e], d = dst[e];
    int p = atomicAdd(&cur1[sv], 1);
    e1[p] = e;
    int loc = atomicAdd(&h[d], 1);
    e2[basep[d] + loc] = e;
  }
}

// ---------------- dst-grouped gather pass, lane-paired (u32 ee, float2 x1) ----------------
__global__ __launch_bounds__(256) void k_dst(const float* __restrict__ x1,
                                             const u32* __restrict__ eeh32,
                                             const float* __restrict__ wbuf,
                                             const int* __restrict__ edge_src,
                                             const int* __restrict__ rp2,
                                             const int* __restrict__ e2,
                                             float* __restrict__ acc2) {
  __shared__ float red[4][224];
  int t = blockIdx.x / CHD;
  int chunk = blockIdx.x % CHD;
  int tid = threadIdx.x, wv = tid >> 6, l = tid & 63;
  int pl = l & 31, hi = l >> 5;
  int start = rp2[t], end = rp2[t + 1];
  int n = end - start;
  int sub = chunk * 4 + wv;                                  // 0..31
  int i0 = start + (int)(((long long)n * sub) >> 5);
  int i1 = start + (int)(((long long)n * (sub + 1)) >> 5);
  float sxaa = 0.f, sxab = 0.f, sxba = 0.f, sxbb = 0.f, s3a = 0.f, s3b = 0.f, rsum = 0.f;
  int p = i0;
  for (; p + 4 <= i1; p += 4) {
    int ea = e2[p + hi], eb = e2[p + 2 + hi];
    float wa = wbuf[ea], wb = wbuf[eb];
    int sa = edge_src[ea], sb = edge_src[eb];
    u32 va = eeh32[(size_t)ea * 32 + pl];
    u32 vb = eeh32[(size_t)eb * 32 + pl];
    float2 xaa = *(const float2*)(x1 + (size_t)sa * 128 + pl * 2);
    float2 xab = *(const float2*)(x1 + (size_t)sa * 128 + 64 + pl * 2);
    float2 xba = *(const float2*)(x1 + (size_t)sb * 128 + pl * 2);
    float2 xbb = *(const float2*)(x1 + (size_t)sb * 128 + 64 + pl * 2);
    rsum += wa + wb;
    s3a += wa * bf16_lo(va) + wb * bf16_lo(vb);
    s3b += wa * bf16_hi(va) + wb * bf16_hi(vb);
    sxaa += wa * xaa.x + wb * xba.x; sxab += wa * xaa.y + wb * xba.y;
    sxba += wa * xab.x + wb * xbb.x; sxbb += wa * xab.y + wb * xbb.y;
  }
  for (; p < i1; p += 2) {
    int q = p + hi;
    bool ok = q < i1;
    int ea = e2[ok ? q : i0];
    float wa = ok ? wbuf[ea] : 0.f;
    int sa = edge_src[ea];
    u32 va = eeh32[(size_t)ea * 32 + pl];
    float2 xaa = *(const float2*)(x1 + (size_t)sa * 128 + pl * 2);
    float2 xab = *(const float2*)(x1 + (size_t)sa * 128 + 64 + pl * 2);
    rsum += wa;
    s3a += wa * bf16_lo(va);
    s3b += wa * bf16_hi(va);
    sxaa += wa * xaa.x; sxab += wa * xaa.y;
    sxba += wa * xab.x; sxbb += wa * xab.y;
  }
  sxaa += __shfl_xor(sxaa, 32); sxab += __shfl_xor(sxab, 32);
  sxba += __shfl_xor(sxba, 32); sxbb += __shfl_xor(sxbb, 32);
  s3a += __shfl_xor(s3a, 32);  s3b += __shfl_xor(s3b, 32);
  rsum += __shfl_xor(rsum, 32);
  if (hi == 0) {
    red[wv][2 * pl] = sxaa;       red[wv][2 * pl + 1] = sxab;
    red[wv][64 + 2 * pl] = sxba;  red[wv][64 + 2 * pl + 1] = sxbb;
    red[wv][128 + 2 * pl] = s3a;  red[wv][128 + 2 * pl + 1] = s3b;
    if (pl == 0) red[wv][192] = rsum;
  }
  __syncthreads();
  if (tid < 193) {
    float v = red[0][tid] + red[1][tid] + red[2][tid] + red[3][tid];
    if (v != 0.f) atomicAdd(&acc2[t * 256 + tid], v);
  }
}

// ---------------- dst finalize: bf16-pack sbuf2 ----------------
__global__ __launch_bounds__(256) void k_dst_final(const float* __restrict__ acc2,
                                                   u32* __restrict__ sbuf2bf,
                                                   float* __restrict__ rs2) {
  int t = blockIdx.x, tid = threadIdx.x;
  float rtot = acc2[t * 256 + 192];
  float scale = rtot > 0.f ? 1.0f / rtot : 0.f;
  if (tid < 192) {
    float o = acc2[t * 256 + tid] * scale;
    float pr = __shfl_xor(o, 1);
    if (!(tid & 1)) sbuf2bf[t * 96 + (tid >> 1)] = pack_bf16x2(o, pr);
  }
  if (tid == 192) rs2[t] = rtot;
}

// ---------------- src-grouped gather pass, lane-paired; bf16-pack sbuf1 ----------------
__global__ __launch_bounds__(256) void k_src(const float* __restrict__ x2,
                                             const u32* __restrict__ eeh32,
                                             const float* __restrict__ wbuf,
                                             const int* __restrict__ edge_dst,
                                             const int* __restrict__ rp1,
                                             const int* __restrict__ e1,
                                             u32* __restrict__ sbuf1bf,
                                             float* __restrict__ rs1) {
  int wid = (blockIdx.x * 256 + threadIdx.x) >> 6;
  int l = threadIdx.x & 63;
  if (wid >= N1V) return;
  int pl = l & 31, hi = l >> 5;
  int start = rp1[wid], end = rp1[wid + 1];
  float s2aa = 0.f, s2ab = 0.f, s2ba = 0.f, s2bb = 0.f, s1a = 0.f, s1b = 0.f, rsum = 0.f;
  int p = start;
  for (; p + 4 <= end; p += 4) {
    int ea = e1[p + hi], eb = e1[p + 2 + hi];
    float wa = wbuf[ea], wb = wbuf[eb];
    int da = edge_dst[ea], db = edge_dst[eb];
    u32 va = eeh32[(size_t)ea * 32 + pl];
    u32 vb = eeh32[(size_t)eb * 32 + pl];
    float2 xaa = *(const float2*)(x2 + (size_t)da * 128 + pl * 2);
    float2 xab = *(const float2*)(x2 + (size_t)da * 128 + 64 + pl * 2);
    float2 xba = *(const float2*)(x2 + (size_t)db * 128 + pl * 2);
    float2 xbb = *(const float2*)(x2 + (size_t)db * 128 + 64 + pl * 2);
    rsum += wa + wb;
    s1a += wa * bf16_lo(va) + wb * bf16_lo(vb);
    s1b += wa * bf16_hi(va) + wb * bf16_hi(vb);
    s2aa += wa * xaa.x + wb * xba.x; s2ab += wa * xaa.y + wb * xba.y;
    s2ba += wa * xab.x + wb * xbb.x; s2bb += wa * xab.y + wb * xbb.y;
  }
  for (; p < end; p += 2) {
    int q = p + hi;
    bool ok = q < end;
    int ea = e1[ok ? q : start];
    float wa = ok ? wbuf[ea] : 0.f;
    int da = edge_dst[ea];
    u32 va = eeh32[(size_t)ea * 32 + pl];
    float2 xaa = *(const float2*)(x2 + (size_t)da * 128 + pl * 2);
    float2 xab = *(const float2*)(x2 + (size_t)da * 128 + 64 + pl * 2);
    rsum += wa;
    s1a += wa * bf16_lo(va);
    s1b += wa * bf16_hi(va);
    s2aa += wa * xaa.x; s2ab += wa * xaa.y;
    s2ba += wa * xab.x; s2bb += wa * xab.y;
  }
  s2aa += __shfl_xor(s2aa, 32); s2ab += __shfl_xor(s2ab, 32);
  s2ba += __shfl_xor(s2ba, 32); s2bb += __shfl_xor(s2bb, 32);
  s1a += __shfl_xor(s1a, 32);  s1b += __shfl_xor(s1b, 32);
  rsum += __shfl_xor(rsum, 32);
  float scale = (end > start) ? 1.0f / rsum : 0.f;
  if (hi == 0) {
    u32* baseo = sbuf1bf + (size_t)wid * 96;
    baseo[pl] = pack_bf16x2(s2aa * scale, s2ab * scale);
    baseo[32 + pl] = pack_bf16x2(s2ba * scale, s2bb * scale);
    baseo[64 + pl] = pack_bf16x2(s1a * scale, s1b * scale);
    if (pl == 0) rs1[wid] = (end > start) ? rsum : 0.f;
  }
}

// ---------------- MFMA output GEMM: out = mask * elu(A[M,320]bf16 @ a^Tbf16) ----------------
__global__ __launch_bounds__(256) void k_gemm(const u32* __restrict__ Xbf,   // row = 64 u32
                                              const u32* __restrict__ Sbf,   // row = 96 u32
                                              const u32* __restrict__ abf,   // [128][160] u32
                                              const float* __restrict__ rs,
                                              float* __restrict__ out,
                                              int M, int mode) {
  __shared__ short Bt[128 * 40];   // [n=128][k=32 bf16 + pad 8]
  int tid = threadIdx.x;
  int w = tid >> 6, l = tid & 63;
  int r = l & 15, cchunk = l >> 4;          // 0..3
  int row0 = blockIdx.x * 64;
  int gi = row0 + w * 16 + r;               // A-row this lane loads
  int gclamp = min(gi, M - 1);
  f32x4v acc[8];
#pragma unroll
  for (int i = 0; i < 8; ++i) acc[i] = (f32x4v){0.f, 0.f, 0.f, 0.f};

  for (int ks = 0; ks < 10; ++ks) {
    if (ks) __syncthreads();
    {
      int n = tid >> 1, half = tid & 1;
      const u32* srcp = abf + n * 160 + ks * 16 + half * 8;
      u32* dstp = (u32*)&Bt[n * 40] + half * 8;
      *(uint4*)(dstp) = *(const uint4*)(srcp);
      *(uint4*)(dstp + 4) = *(const uint4*)(srcp + 4);
    }
    __syncthreads();
    int ck = ks * 4 + cchunk;                // 8-elem chunk index, 0..39
    const u32* ap;
    if (mode == 0) {
      ap = (ck < 16) ? (Xbf + (size_t)gclamp * 64 + ck * 4)
                     : (Sbf + (size_t)gclamp * 96 + (ck - 16) * 4);
    } else {
      ap = (ck < 16) ? (Sbf + (size_t)gclamp * 96 + ck * 4)
         : (ck < 32) ? (Xbf + (size_t)gclamp * 64 + (ck - 16) * 4)
                     : (Sbf + (size_t)gclamp * 96 + 64 + (ck - 32) * 4);
    }
    bf16x8 afrag = *(const bf16x8*)ap;
#pragma unroll
    for (int nt = 0; nt < 8; ++nt) {
      bf16x8 bfrag = *(const bf16x8*)&Bt[(nt * 16 + r) * 40 + cchunk * 8];
      acc[nt] = __builtin_amdgcn_mfma_f32_16x16x32_bf16(afrag, bfrag, acc[nt], 0, 0, 0);
    }
  }
  int baser = row0 + w * 16 + cchunk * 4;
#pragma unroll
  for (int rr = 0; rr < 4; ++rr) {
    int go = baser + rr;
    if (go < M) {
      float rsv = rs[go];
      bool ok = rsv > 0.f;
#pragma unroll
      for (int nt = 0; nt < 8; ++nt) {
        float h = acc[nt][rr];
        float v = ok ? (h > 0.f ? h : expm1f(h)) : 0.f;
        out[(size_t)go * 128 + nt * 16 + r] = v;
      }
    }
  }
}

// =====================================================================================

static inline size_t align_up(size_t x, size_t a) { return (x + a - 1) & ~(a - 1); }

extern "C" void kernel_launch(void* const* d_in, const int* in_sizes, int n_in,
                              void* d_out, int out_size, void* d_ws, size_t ws_size,
                              hipStream_t stream) {
  const float* x1 = (const float*)d_in[0];
  const float* x2 = (const float*)d_in[1];
  const float* ee = (const float*)d_in[2];
  const float* a = (const float*)d_in[3];
  const float* a2 = (const float*)d_in[4];
  const int* esrc = (const int*)d_in[5];
  const int* edst = (const int*)d_in[6];
  float* out = (float*)d_out;

  char* base = (char*)d_ws;
  size_t off = 0;
  auto alloc = [&](size_t bytes) -> char* {
    char* p = base + off;
    off = align_up(off + bytes, 256);
    return p;
  };
  float* c = (float*)alloc(320 * 4);
  float* z1g = (float*)alloc(N1V * 4);
  float* z2g = (float*)alloc(512 * 4);
  u32* x1bf = (u32*)alloc((size_t)N1V * 64 * 4);      // 25.6 MB
  u32* x2bf = (u32*)alloc((size_t)N2V * 64 * 4);
  u32* abf = (u32*)alloc(128 * 160 * 4);              // 80 KB
  int* rp1 = (int*)alloc((N1V + 1) * 4);
  int* cur1 = (int*)alloc(N1V * 4);
  int* rp2 = (int*)alloc(512 * 4);
  int* partials = (int*)alloc(64 * 4);
  int* hblk = (int*)alloc((size_t)NB * 512 * 4);      // 4 MB
  int* tot2 = (int*)alloc(512 * 4);
  int* e1 = (int*)alloc(NEV * 4);
  int* e2 = (int*)alloc(NEV * 4);
  float* wbuf = (float*)alloc(NEV * 4);
  u32* eeh = (u32*)alloc((size_t)NEV * 128);          // 128 MB (bf16 ee)
  float* rs1 = (float*)alloc(N1V * 4);
  float* rs2 = (float*)alloc(512 * 4);
  u32* sbuf1bf = (u32*)alloc((size_t)N1V * 96 * 4);   // 38.4 MB
  u32* sbuf2bf = (u32*)alloc(512 * 96 * 4);
  float* acc2 = (float*)alloc(512 * 256 * 4);
  (void)ws_size; (void)out_size; (void)n_in; (void)in_sizes;

  hipMemsetAsync(cur1, 0, N1V * 4, stream);
  hipMemsetAsync(acc2, 0, 512 * 256 * 4, stream);

  hipLaunchKernelGGL(k_prep, dim3(2), dim3(256), 0, stream, a, a2, c);
  hipLaunchKernelGGL(k_conv, dim3((1600000 + 5120 + 8000 + 255) / 256), dim3(256), 0, stream,
                     x1, x2, a, c, x1bf, x2bf, abf, z1g, z2g);
  hipLaunchKernelGGL(k_histw, dim3(NB), dim3(256), 0, stream,
                     esrc, edst, ee, z1g, z2g, c, cur1, hblk, wbuf, eeh);
  hipLaunchKernelGGL(k_colscan, dim3(512), dim3(256), 0, stream, hblk, tot2);

  const int nScanBlocks = (N1V + 2047) / 2048;  // 49
  hipLaunchKernelGGL(k_scanA, dim3(nScanBlocks), dim3(256), 0, stream, cur1, rp1, partials, N1V);
  hipLaunchKernelGGL(k_scanB, dim3(1), dim3(512), 0, stream, partials, nScanBlocks, tot2, rp2);
  hipLaunchKernelGGL(k_scanC, dim3((N1V + 255) / 256), dim3(256), 0, stream, rp1, cur1, partials, N1V, NEV);
  hipLaunchKernelGGL(k_scatter, dim3(NB), dim3(256), 0, stream,
                     esrc, edst, cur1, hblk, rp2, e1, e2);

  hipLaunchKernelGGL(k_dst, dim3(N2V * CHD), dim3(256), 0, stream,
                     x1, eeh, wbuf, esrc, rp2, e2, acc2);
  hipLaunchKernelGGL(k_dst_final, dim3(N2V), dim3(256), 0, stream, acc2, sbuf2bf, rs2);

  hipLaunchKernelGGL(k_src, dim3(N1V / 4), dim3(256), 0, stream,
                     x2, eeh, wbuf, edst, rp1, e1, sbuf1bf, rs1);

  hipLaunchKernelGGL(k_gemm, dim3((N1V + 63) / 64), dim3(256), 0, stream,
                     x1bf, sbuf1bf, abf, rs1, out, N1V, 0);
  hipLaunchKernelGGL(k_gemm, dim3((N2V + 63) / 64), dim3(256), 0, stream,
                     x2bf, sbuf2bf, abf, rs2, out + (size_t)N1V * 128, N2V, 1);
}

// Round 18
// 432.084 us; speedup vs baseline: 1.8430x; 1.0359x over previous
//
#include <hip/hip_runtime.h>

#define N1V 100000
#define N2V 500
#define NEV 1000000
#define ALPHAV 0.2f
#define NB 2048       // histogram/scatter blocks
#define CHUNK 489     // ceil(NEV/NB)
#define CHD 8         // dst chunks per type
#define NDSTB (N2V * CHD)          // 4000 dst blocks
#define NSRCB (N1V / 4)            // 25000 src blocks
#define NGEMM1 ((N1V + 63) / 64)   // 1563
#define NGEMM2 ((N2V + 63) / 64)   // 8

typedef float f32x4 __attribute__((ext_vector_type(4)));
typedef unsigned int u32;
typedef unsigned short u16;
typedef u32 u32x2 __attribute__((ext_vector_type(2)));
using bf16x8 = __attribute__((ext_vector_type(8))) short;   // 8 bf16 (4 VGPRs)
using f32x4v = __attribute__((ext_vector_type(4))) float;

__device__ __forceinline__ u32 pack_bf16x2(float a, float b) {
  u32 ua = __float_as_uint(a), ub = __float_as_uint(b);
  u32 ra = (ua + 0x7FFFu + ((ua >> 16) & 1u)) >> 16;
  u32 rb = (ub + 0x7FFFu + ((ub >> 16) & 1u)) >> 16;
  return ra | (rb << 16);
}

__device__ __forceinline__ float bf16_lo(u32 v) { return __uint_as_float(v << 16); }
__device__ __forceinline__ float bf16_hi(u32 v) { return __uint_as_float(v & 0xFFFF0000u); }

// ---------------- prep: c[320] = a^T @ a_2 ----------------
__global__ __launch_bounds__(256) void k_prep(const float* __restrict__ a,
                                              const float* __restrict__ a2,
                                              float* __restrict__ c) {
  int p = blockIdx.x * 256 + threadIdx.x;
  if (p < 320) {
    float s = 0.f;
    for (int k = 0; k < 128; ++k) s += a2[k] * a[k * 320 + p];
    c[p] = s;
  }
}

// ---------------- fused bf16 conversions + z1/z2 dots ----------------
__global__ __launch_bounds__(256) void k_conv(const float* __restrict__ x1,
                                              const float* __restrict__ x2,
                                              const float* __restrict__ a,
                                              const float* __restrict__ c,
                                              u32* __restrict__ x1bf,
                                              u32* __restrict__ x2bf,
                                              u32* __restrict__ abf,
                                              float* __restrict__ z1g,
                                              float* __restrict__ z2g) {
  size_t gid = (size_t)blockIdx.x * 256 + threadIdx.x;
  const size_t n_x1 = (size_t)N1V * 16;        // 1,600,000 (64-aligned)
  const size_t n_a = 128 * 320 / 8;            // 5,120 (64-aligned)
  const size_t n_x2 = (size_t)N2V * 16;        // 8,000
  if (gid < n_x1) {
    size_t row = gid >> 4; int chunk = (int)(gid & 15);
    const f32x4* s = (const f32x4*)(x1 + row * 128 + chunk * 8);
    f32x4 v0 = s[0], v1 = s[1];
    uint4 o;
    o.x = pack_bf16x2(v0.x, v0.y); o.y = pack_bf16x2(v0.z, v0.w);
    o.z = pack_bf16x2(v1.x, v1.y); o.w = pack_bf16x2(v1.z, v1.w);
    *(uint4*)(x1bf + row * 64 + chunk * 4) = o;
    const float* cp = c + chunk * 8;
    float d = v0.x * cp[0] + v0.y * cp[1] + v0.z * cp[2] + v0.w * cp[3] +
              v1.x * cp[4] + v1.y * cp[5] + v1.z * cp[6] + v1.w * cp[7];
#pragma unroll
    for (int off = 1; off < 16; off <<= 1) d += __shfl_xor(d, off, 64);
    if (chunk == 0) z1g[row] = d;
  } else if (gid < n_x1 + n_a) {
    size_t idx = gid - n_x1;
    const f32x4* s = (const f32x4*)(a + idx * 8);
    f32x4 v0 = s[0], v1 = s[1];
    uint4 o;
    o.x = pack_bf16x2(v0.x, v0.y); o.y = pack_bf16x2(v0.z, v0.w);
    o.z = pack_bf16x2(v1.x, v1.y); o.w = pack_bf16x2(v1.z, v1.w);
    *(uint4*)(abf + idx * 4) = o;
  } else if (gid < n_x1 + n_a + n_x2) {
    size_t idx = gid - n_x1 - n_a;
    size_t row = idx >> 4; int chunk = (int)(idx & 15);
    const f32x4* s = (const f32x4*)(x2 + row * 128 + chunk * 8);
    f32x4 v0 = s[0], v1 = s[1];
    uint4 o;
    o.x = pack_bf16x2(v0.x, v0.y); o.y = pack_bf16x2(v0.z, v0.w);
    o.z = pack_bf16x2(v1.x, v1.y); o.w = pack_bf16x2(v1.z, v1.w);
    *(uint4*)(x2bf + row * 64 + chunk * 4) = o;
    const float* cp = c + 128 + chunk * 8;
    float d = v0.x * cp[0] + v0.y * cp[1] + v0.z * cp[2] + v0.w * cp[3] +
              v1.x * cp[4] + v1.y * cp[5] + v1.z * cp[6] + v1.w * cp[7];
#pragma unroll
    for (int off = 1; off < 16; off <<= 1) d += __shfl_xor(d, off, 64);
    if (chunk == 0) z2g[row] = d;
  }
}

// ---------------- linear pass: histograms + w + bf16 transcode (register-direct) ----------------
// lane (r=lane>>4, cc=lane&15): 4 edges/wave/iter, dot via 16-lane butterfly, no tile LDS.
__global__ __launch_bounds__(256) void k_histw(const int* __restrict__ src,
                                               const int* __restrict__ dst,
                                               const float* __restrict__ ee,
                                               const float* __restrict__ z1g,
                                               const float* __restrict__ z2g,
                                               const float* __restrict__ c,
                                               int* __restrict__ c1,
                                               int* __restrict__ hblk,
                                               float* __restrict__ wbuf,
                                               u32* __restrict__ eeh) {
  __shared__ int h[512];
  for (int i = threadIdx.x; i < 512; i += 256) h[i] = 0;
  int tid = threadIdx.x;
  int wave = tid >> 6, lane = tid & 63;
  int r = lane >> 4, cc = lane & 15;
  float c0 = c[256 + cc * 4 + 0], c1r = c[256 + cc * 4 + 1];
  float c2 = c[256 + cc * 4 + 2], c3 = c[256 + cc * 4 + 3];
  __syncthreads();

  int b = blockIdx.x;
  int b0 = b * CHUNK, b1 = min(b0 + CHUNK, NEV);
  for (int eb = b0 + wave * 4; eb < b1; eb += 16) {
    int e = eb + r;
    bool ok = e < b1;
    int ec = ok ? e : b0;
    f32x4 v = __builtin_nontemporal_load((const f32x4*)(ee + (size_t)ec * 64) + cc);
    float d = v.x * c0 + v.y * c1r + v.z * c2 + v.w * c3;
#pragma unroll
    for (int off = 1; off < 16; off <<= 1) d += __shfl_xor(d, off, 64);
    if (ok) {
      u32x2 o;
      o.x = pack_bf16x2(v.x, v.y);
      o.y = pack_bf16x2(v.z, v.w);
      *(u32x2*)(eeh + (size_t)ec * 32 + cc * 2) = o;
      if (cc == 0) {
        int sv = src[e], dv = dst[e];
        float z = z1g[sv] + z2g[dv] + d;
        float zp = z > 0.f ? z : ALPHAV * z;
        wbuf[e] = __expf(-zp);
        atomicAdd(&c1[sv], 1);
        atomicAdd(&h[dv], 1);
      }
    }
  }
  __syncthreads();
  for (int i = threadIdx.x; i < 512; i += 256) hblk[(size_t)b * 512 + i] = h[i];
}

// ---------------- column scan over NB blocks ----------------
__global__ __launch_bounds__(256) void k_colscan(int* __restrict__ hblk,
                                                 int* __restrict__ tot2) {
  __shared__ int s[256];
  int t = blockIdx.x;
  int tid = threadIdx.x;
  int v[8]; int tot = 0;
#pragma unroll
  for (int j = 0; j < 8; ++j) {
    int b = tid * 8 + j;
    v[j] = hblk[(size_t)b * 512 + t];
    tot += v[j];
  }
  s[tid] = tot; __syncthreads();
  for (int off = 1; off < 256; off <<= 1) {
    int tv = (tid >= off) ? s[tid - off] : 0;
    __syncthreads();
    if (tid >= off) s[tid] += tv;
    __syncthreads();
  }
  int run = s[tid] - tot;
#pragma unroll
  for (int j = 0; j < 8; ++j) {
    int b = tid * 8 + j;
    hblk[(size_t)b * 512 + t] = run;
    run += v[j];
  }
  if (tid == 255) tot2[t] = run;
}

// ---------------- scan for src counts ----------------
__global__ __launch_bounds__(256) void k_scanA(const int* __restrict__ cnt,
                                               int* __restrict__ outp,
                                               int* __restrict__ partials, int n) {
  __shared__ int s[256];
  int tid = threadIdx.x;
  int base = blockIdx.x * 2048 + tid * 8;
  int v[8]; int tot = 0;
#pragma unroll
  for (int j = 0; j < 8; ++j) { int idx = base + j; v[j] = (idx < n) ? cnt[idx] : 0; tot += v[j]; }
  s[tid] = tot; __syncthreads();
  for (int off = 1; off < 256; off <<= 1) {
    int tv = 0;
    if (tid >= off) tv = s[tid - off];
    __syncthreads();
    if (tid >= off) s[tid] += tv;
    __syncthreads();
  }
  int run = s[tid] - tot;
#pragma unroll
  for (int j = 0; j < 8; ++j) { int idx = base + j; if (idx < n) outp[idx] = run; run += v[j]; }
  if (tid == 255) partials[blockIdx.x] = s[255];
}

__global__ __launch_bounds__(512) void k_scanB(int* __restrict__ partials, int nPart,
                                               const int* __restrict__ tot2,
                                               int* __restrict__ rp2) {
  __shared__ int s[512];
  int tid = threadIdx.x;
  int v = (tid < N2V) ? tot2[tid] : 0;
  s[tid] = v; __syncthreads();
  for (int off = 1; off < 512; off <<= 1) {
    int tv = 0;
    if (tid >= off) tv = s[tid - off];
    __syncthreads();
    if (tid >= off) s[tid] += tv;
    __syncthreads();
  }
  if (tid < N2V) rp2[tid] = s[tid] - v;
  if (tid == N2V - 1) rp2[N2V] = s[tid];
  if (tid == 0) {
    int run = 0;
    for (int b = 0; b < nPart; ++b) { int t = partials[b]; partials[b] = run; run += t; }
  }
}

__global__ __launch_bounds__(256) void k_scanC(int* __restrict__ rp, int* __restrict__ cur,
                                               const int* __restrict__ partials, int n, int total) {
  int i = blockIdx.x * 256 + threadIdx.x;
  if (i < n) {
    int v = rp[i] + partials[i >> 11];
    rp[i] = v; cur[i] = v;
  }
  if (i == 0) rp[n] = total;
}

// ---------------- light scatter: CSR placement only ----------------
__global__ __launch_bounds__(256) void k_scatter(const int* __restrict__ src,
                                                 const int* __restrict__ dst,
                                                 int* __restrict__ cur1,
                                                 const int* __restrict__ hblk,
                                                 const int* __restrict__ rp2,
                                                 int* __restrict__ e1, int* __restrict__ e2) {
  __shared__ int h[512];
  __shared__ int basep[512];
  int b = blockIdx.x;
  int b0 = b * CHUNK, b1 = min(b0 + CHUNK, NEV);
  for (int i = threadIdx.x; i < 512; i += 256) {
    basep[i] = ((i < N2V) ? rp2[i] : 0) + hblk[(size_t)b * 512 + i];
    h[i] = 0;
  }
  __syncthreads();
  for (int e = b0 + threadIdx.x; e < b1; e += 256) {
    int sv = src[e], d = dst[e];
    int p = atomicAdd(&cur1[sv], 1);
    e1[p] = e;
    int loc = atomicAdd(&h[d], 1);
    e2[basep[d] + loc] = e;
  }
}

// ---------------- fused gather pass: blocks [0,NDSTB) = dst role, rest = src role ----------------
__global__ __launch_bounds__(256) void k_gather(const float* __restrict__ x1,
                                                const float* __restrict__ x2,
                                                const u32* __restrict__ eeh32,
                                                const float* __restrict__ wbuf,
                                                const int* __restrict__ edge_src,
                                                const int* __restrict__ edge_dst,
                                                const int* __restrict__ rp2,
                                                const int* __restrict__ e2,
                                                const int* __restrict__ rp1,
                                                const int* __restrict__ e1,
                                                float* __restrict__ acc2,
                                                u32* __restrict__ sbuf1bf,
                                                float* __restrict__ rs1) {
  __shared__ float red[4][224];
  int tid = threadIdx.x;
  int l = tid & 63;
  int pl = l & 31, hi = l >> 5;

  if (blockIdx.x < NDSTB) {
    // ---------- dst role ----------
    int t = blockIdx.x / CHD;
    int chunk = blockIdx.x % CHD;
    int wv = tid >> 6;
    int start = rp2[t], end = rp2[t + 1];
    int n = end - start;
    int sub = chunk * 4 + wv;                                  // 0..31
    int i0 = start + (int)(((long long)n * sub) >> 5);
    int i1 = start + (int)(((long long)n * (sub + 1)) >> 5);
    float sxaa = 0.f, sxab = 0.f, sxba = 0.f, sxbb = 0.f, s3a = 0.f, s3b = 0.f, rsum = 0.f;
    int p = i0;
    for (; p + 4 <= i1; p += 4) {
      int ea = e2[p + hi], eb = e2[p + 2 + hi];
      float wa = wbuf[ea], wb = wbuf[eb];
      int sa = edge_src[ea], sb = edge_src[eb];
      u32 va = eeh32[(size_t)ea * 32 + pl];
      u32 vb = eeh32[(size_t)eb * 32 + pl];
      float2 xaa = *(const float2*)(x1 + (size_t)sa * 128 + pl * 2);
      float2 xab = *(const float2*)(x1 + (size_t)sa * 128 + 64 + pl * 2);
      float2 xba = *(const float2*)(x1 + (size_t)sb * 128 + pl * 2);
      float2 xbb = *(const float2*)(x1 + (size_t)sb * 128 + 64 + pl * 2);
      rsum += wa + wb;
      s3a += wa * bf16_lo(va) + wb * bf16_lo(vb);
      s3b += wa * bf16_hi(va) + wb * bf16_hi(vb);
      sxaa += wa * xaa.x + wb * xba.x; sxab += wa * xaa.y + wb * xba.y;
      sxba += wa * xab.x + wb * xbb.x; sxbb += wa * xab.y + wb * xbb.y;
    }
    for (; p < i1; p += 2) {
      int q = p + hi;
      bool ok = q < i1;
      int ea = e2[ok ? q : i0];
      float wa = ok ? wbuf[ea] : 0.f;
      int sa = edge_src[ea];
      u32 va = eeh32[(size_t)ea * 32 + pl];
      float2 xaa = *(const float2*)(x1 + (size_t)sa * 128 + pl * 2);
      float2 xab = *(const float2*)(x1 + (size_t)sa * 128 + 64 + pl * 2);
      rsum += wa;
      s3a += wa * bf16_lo(va);
      s3b += wa * bf16_hi(va);
      sxaa += wa * xaa.x; sxab += wa * xaa.y;
      sxba += wa * xab.x; sxbb += wa * xab.y;
    }
    sxaa += __shfl_xor(sxaa, 32); sxab += __shfl_xor(sxab, 32);
    sxba += __shfl_xor(sxba, 32); sxbb += __shfl_xor(sxbb, 32);
    s3a += __shfl_xor(s3a, 32);  s3b += __shfl_xor(s3b, 32);
    rsum += __shfl_xor(rsum, 32);
    if (hi == 0) {
      red[wv][2 * pl] = sxaa;       red[wv][2 * pl + 1] = sxab;
      red[wv][64 + 2 * pl] = sxba;  red[wv][64 + 2 * pl + 1] = sxbb;
      red[wv][128 + 2 * pl] = s3a;  red[wv][128 + 2 * pl + 1] = s3b;
      if (pl == 0) red[wv][192] = rsum;
    }
    __syncthreads();
    if (tid < 193) {
      float v = red[0][tid] + red[1][tid] + red[2][tid] + red[3][tid];
      if (v != 0.f) atomicAdd(&acc2[t * 256 + tid], v);
    }
  } else {
    // ---------- src role ----------
    int bid = blockIdx.x - NDSTB;
    int wid = (bid * 256 + tid) >> 6;
    if (wid >= N1V) return;
    int start = rp1[wid], end = rp1[wid + 1];
    float s2aa = 0.f, s2ab = 0.f, s2ba = 0.f, s2bb = 0.f, s1a = 0.f, s1b = 0.f, rsum = 0.f;
    int p = start;
    for (; p + 4 <= end; p += 4) {
      int ea = e1[p + hi], eb = e1[p + 2 + hi];
      float wa = wbuf[ea], wb = wbuf[eb];
      int da = edge_dst[ea], db = edge_dst[eb];
      u32 va = eeh32[(size_t)ea * 32 + pl];
      u32 vb = eeh32[(size_t)eb * 32 + pl];
      float2 xaa = *(const float2*)(x2 + (size_t)da * 128 + pl * 2);
      float2 xab = *(const float2*)(x2 + (size_t)da * 128 + 64 + pl * 2);
      float2 xba = *(const float2*)(x2 + (size_t)db * 128 + pl * 2);
      float2 xbb = *(const float2*)(x2 + (size_t)db * 128 + 64 + pl * 2);
      rsum += wa + wb;
      s1a += wa * bf16_lo(va) + wb * bf16_lo(vb);
      s1b += wa * bf16_hi(va) + wb * bf16_hi(vb);
      s2aa += wa * xaa.x + wb * xba.x; s2ab += wa * xaa.y + wb * xba.y;
      s2ba += wa * xab.x + wb * xbb.x; s2bb += wa * xab.y + wb * xbb.y;
    }
    for (; p < end; p += 2) {
      int q = p + hi;
      bool ok = q < end;
      int ea = e1[ok ? q : start];
      float wa = ok ? wbuf[ea] : 0.f;
      int da = edge_dst[ea];
      u32 va = eeh32[(size_t)ea * 32 + pl];
      float2 xaa = *(const float2*)(x2 + (size_t)da * 128 + pl * 2);
      float2 xab = *(const float2*)(x2 + (size_t)da * 128 + 64 + pl * 2);
      rsum += wa;
      s1a += wa * bf16_lo(va);
      s1b += wa * bf16_hi(va);
      s2aa += wa * xaa.x; s2ab += wa * xaa.y;
      s2ba += wa * xab.x; s2bb += wa * xab.y;
    }
    s2aa += __shfl_xor(s2aa, 32); s2ab += __shfl_xor(s2ab, 32);
    s2ba += __shfl_xor(s2ba, 32); s2bb += __shfl_xor(s2bb, 32);
    s1a += __shfl_xor(s1a, 32);  s1b += __shfl_xor(s1b, 32);
    rsum += __shfl_xor(rsum, 32);
    float scale = (end > start) ? 1.0f / rsum : 0.f;
    if (hi == 0) {
      u32* baseo = sbuf1bf + (size_t)wid * 96;
      baseo[pl] = pack_bf16x2(s2aa * scale, s2ab * scale);
      baseo[32 + pl] = pack_bf16x2(s2ba * scale, s2bb * scale);
      baseo[64 + pl] = pack_bf16x2(s1a * scale, s1b * scale);
      if (pl == 0) rs1[wid] = (end > start) ? rsum : 0.f;
    }
  }
}

// ---------------- dst finalize: bf16-pack sbuf2 ----------------
__global__ __launch_bounds__(256) void k_dst_final(const float* __restrict__ acc2,
                                                   u32* __restrict__ sbuf2bf,
                                                   float* __restrict__ rs2) {
  int t = blockIdx.x, tid = threadIdx.x;
  float rtot = acc2[t * 256 + 192];
  float scale = rtot > 0.f ? 1.0f / rtot : 0.f;
  if (tid < 192) {
    float o = acc2[t * 256 + tid] * scale;
    float pr = __shfl_xor(o, 1);
    if (!(tid & 1)) sbuf2bf[t * 96 + (tid >> 1)] = pack_bf16x2(o, pr);
  }
  if (tid == 192) rs2[t] = rtot;
}

// ---------------- MFMA output GEMM, both modes in one launch ----------------
__global__ __launch_bounds__(256) void k_gemm(const u32* __restrict__ x1bf,
                                              const u32* __restrict__ sbuf1bf,
                                              const u32* __restrict__ x2bf,
                                              const u32* __restrict__ sbuf2bf,
                                              const u32* __restrict__ abf,   // [128][160] u32
                                              const float* __restrict__ rs1,
                                              const float* __restrict__ rs2,
                                              float* __restrict__ outall) {
  __shared__ short Bt[128 * 40];   // [n=128][k=32 bf16 + pad 8]
  int tid = threadIdx.x;
  int w = tid >> 6, l = tid & 63;
  int r = l & 15, cchunk = l >> 4;          // 0..3
  int mode, row0, M;
  const u32 *Xbf, *Sbf;
  const float* rs;
  float* out;
  if (blockIdx.x < NGEMM1) {
    mode = 0; row0 = blockIdx.x * 64; M = N1V;
    Xbf = x1bf; Sbf = sbuf1bf; rs = rs1; out = outall;
  } else {
    mode = 1; row0 = (blockIdx.x - NGEMM1) * 64; M = N2V;
    Xbf = x2bf; Sbf = sbuf2bf; rs = rs2; out = outall + (size_t)N1V * 128;
  }
  int gi = row0 + w * 16 + r;               // A-row this lane loads
  int gclamp = min(gi, M - 1);
  f32x4v acc[8];
#pragma unroll
  for (int i = 0; i < 8; ++i) acc[i] = (f32x4v){0.f, 0.f, 0.f, 0.f};

  for (int ks = 0; ks < 10; ++ks) {
    if (ks) __syncthreads();
    {
      int n = tid >> 1, half = tid & 1;
      const u32* srcp = abf + n * 160 + ks * 16 + half * 8;
      u32* dstp = (u32*)&Bt[n * 40] + half * 8;
      *(uint4*)(dstp) = *(const uint4*)(srcp);
      *(uint4*)(dstp + 4) = *(const uint4*)(srcp + 4);
    }
    __syncthreads();
    int ck = ks * 4 + cchunk;                // 8-elem chunk index, 0..39
    const u32* ap;
    if (mode == 0) {
      ap = (ck < 16) ? (Xbf + (size_t)gclamp * 64 + ck * 4)
                     : (Sbf + (size_t)gclamp * 96 + (ck - 16) * 4);
    } else {
      ap = (ck < 16) ? (Sbf + (size_t)gclamp * 96 + ck * 4)
         : (ck < 32) ? (Xbf + (size_t)gclamp * 64 + (ck - 16) * 4)
                     : (Sbf + (size_t)gclamp * 96 + 64 + (ck - 32) * 4);
    }
    bf16x8 afrag = *(const bf16x8*)ap;
#pragma unroll
    for (int nt = 0; nt < 8; ++nt) {
      bf16x8 bfrag = *(const bf16x8*)&Bt[(nt * 16 + r) * 40 + cchunk * 8];
      acc[nt] = __builtin_amdgcn_mfma_f32_16x16x32_bf16(afrag, bfrag, acc[nt], 0, 0, 0);
    }
  }
  int baser = row0 + w * 16 + cchunk * 4;
#pragma unroll
  for (int rr = 0; rr < 4; ++rr) {
    int go = baser + rr;
    if (go < M) {
      float rsv = rs[go];
      bool ok = rsv > 0.f;
#pragma unroll
      for (int nt = 0; nt < 8; ++nt) {
        float h = acc[nt][rr];
        float v = ok ? (h > 0.f ? h : expm1f(h)) : 0.f;
        out[(size_t)go * 128 + nt * 16 + r] = v;
      }
    }
  }
}

// =====================================================================================

static inline size_t align_up(size_t x, size_t a) { return (x + a - 1) & ~(a - 1); }

extern "C" void kernel_launch(void* const* d_in, const int* in_sizes, int n_in,
                              void* d_out, int out_size, void* d_ws, size_t ws_size,
                              hipStream_t stream) {
  const float* x1 = (const float*)d_in[0];
  const float* x2 = (const float*)d_in[1];
  const float* ee = (const float*)d_in[2];
  const float* a = (const float*)d_in[3];
  const float* a2 = (const float*)d_in[4];
  const int* esrc = (const int*)d_in[5];
  const int* edst = (const int*)d_in[6];
  float* out = (float*)d_out;

  char* base = (char*)d_ws;
  size_t off = 0;
  auto alloc = [&](size_t bytes) -> char* {
    char* p = base + off;
    off = align_up(off + bytes, 256);
    return p;
  };
  float* c = (float*)alloc(320 * 4);
  float* z1g = (float*)alloc(N1V * 4);
  float* z2g = (float*)alloc(512 * 4);
  u32* x1bf = (u32*)alloc((size_t)N1V * 64 * 4);      // 25.6 MB
  u32* x2bf = (u32*)alloc((size_t)N2V * 64 * 4);
  u32* abf = (u32*)alloc(128 * 160 * 4);              // 80 KB
  int* rp1 = (int*)alloc((N1V + 1) * 4);
  int* cur1 = (int*)alloc(N1V * 4);
  int* rp2 = (int*)alloc(512 * 4);
  int* partials = (int*)alloc(64 * 4);
  int* hblk = (int*)alloc((size_t)NB * 512 * 4);      // 4 MB
  int* tot2 = (int*)alloc(512 * 4);
  int* e1 = (int*)alloc(NEV * 4);
  int* e2 = (int*)alloc(NEV * 4);
  float* wbuf = (float*)alloc(NEV * 4);
  u32* eeh = (u32*)alloc((size_t)NEV * 128);          // 128 MB (bf16 ee)
  float* rs1 = (float*)alloc(N1V * 4);
  float* rs2 = (float*)alloc(512 * 4);
  u32* sbuf1bf = (u32*)alloc((size_t)N1V * 96 * 4);   // 38.4 MB
  u32* sbuf2bf = (u32*)alloc(512 * 96 * 4);
  float* acc2 = (float*)alloc(512 * 256 * 4);
  (void)ws_size; (void)out_size; (void)n_in; (void)in_sizes;

  hipMemsetAsync(cur1, 0, N1V * 4, stream);
  hipMemsetAsync(acc2, 0, 512 * 256 * 4, stream);

  hipLaunchKernelGGL(k_prep, dim3(2), dim3(256), 0, stream, a, a2, c);
  hipLaunchKernelGGL(k_conv, dim3((1600000 + 5120 + 8000 + 255) / 256), dim3(256), 0, stream,
                     x1, x2, a, c, x1bf, x2bf, abf, z1g, z2g);
  hipLaunchKernelGGL(k_histw, dim3(NB), dim3(256), 0, stream,
                     esrc, edst, ee, z1g, z2g, c, cur1, hblk, wbuf, eeh);
  hipLaunchKernelGGL(k_colscan, dim3(512), dim3(256), 0, stream, hblk, tot2);

  const int nScanBlocks = (N1V + 2047) / 2048;  // 49
  hipLaunchKernelGGL(k_scanA, dim3(nScanBlocks), dim3(256), 0, stream, cur1, rp1, partials, N1V);
  hipLaunchKernelGGL(k_scanB, dim3(1), dim3(512), 0, stream, partials, nScanBlocks, tot2, rp2);
  hipLaunchKernelGGL(k_scanC, dim3((N1V + 255) / 256), dim3(256), 0, stream, rp1, cur1, partials, N1V, NEV);
  hipLaunchKernelGGL(k_scatter, dim3(NB), dim3(256), 0, stream,
                     esrc, edst, cur1, hblk, rp2, e1, e2);

  hipLaunchKernelGGL(k_gather, dim3(NDSTB + NSRCB), dim3(256), 0, stream,
                     x1, x2, eeh, wbuf, esrc, edst, rp2, e2, rp1, e1,
                     acc2, sbuf1bf, rs1);
  hipLaunchKernelGGL(k_dst_final, dim3(N2V), dim3(256), 0, stream, acc2, sbuf2bf, rs2);

  hipLaunchKernelGGL(k_gemm, dim3(NGEMM1 + NGEMM2), dim3(256), 0, stream,
                     x1bf, sbuf1bf, x2bf, sbuf2bf, abf, rs1, rs2, out);
}

// Round 19
// 384.048 us; speedup vs baseline: 2.0735x; 1.1251x over previous
//
#include <hip/hip_runtime.h>

#define N1V 100000
#define N2V 500
#define NEV 1000000
#define ALPHAV 0.2f
#define NB 2048       // histogram/scatter blocks
#define CHUNK 489     // ceil(NEV/NB)
#define CHD 8         // dst chunks per type
#define NDSTB (N2V * CHD)          // 4000 dst blocks
#define NSRCB (N1V / 4)            // 25000 src blocks
#define NGEMM1 ((N1V + 63) / 64)   // 1563
#define NGEMM2 ((N2V + 63) / 64)   // 8

typedef float f32x4 __attribute__((ext_vector_type(4)));
typedef unsigned int u32;
typedef unsigned short u16;
typedef u32 u32x2 __attribute__((ext_vector_type(2)));
using bf16x8 = __attribute__((ext_vector_type(8))) short;   // 8 bf16 (4 VGPRs)
using f32x4v = __attribute__((ext_vector_type(4))) float;

__device__ __forceinline__ u32 pack_bf16x2(float a, float b) {
  u32 ua = __float_as_uint(a), ub = __float_as_uint(b);
  u32 ra = (ua + 0x7FFFu + ((ua >> 16) & 1u)) >> 16;
  u32 rb = (ub + 0x7FFFu + ((ub >> 16) & 1u)) >> 16;
  return ra | (rb << 16);
}

__device__ __forceinline__ float bf16_lo(u32 v) { return __uint_as_float(v << 16); }
__device__ __forceinline__ float bf16_hi(u32 v) { return __uint_as_float(v & 0xFFFF0000u); }

// ---------------- prep: c[320] = a^T @ a_2 ----------------
__global__ __launch_bounds__(256) void k_prep(const float* __restrict__ a,
                                              const float* __restrict__ a2,
                                              float* __restrict__ c) {
  int p = blockIdx.x * 256 + threadIdx.x;
  if (p < 320) {
    float s = 0.f;
    for (int k = 0; k < 128; ++k) s += a2[k] * a[k * 320 + p];
    c[p] = s;
  }
}

// ---------------- fused bf16 conversions + z1/z2 dots ----------------
__global__ __launch_bounds__(256) void k_conv(const float* __restrict__ x1,
                                              const float* __restrict__ x2,
                                              const float* __restrict__ a,
                                              const float* __restrict__ c,
                                              u32* __restrict__ x1bf,
                                              u32* __restrict__ x2bf,
                                              u32* __restrict__ abf,
                                              float* __restrict__ z1g,
                                              float* __restrict__ z2g) {
  size_t gid = (size_t)blockIdx.x * 256 + threadIdx.x;
  const size_t n_x1 = (size_t)N1V * 16;        // 1,600,000 (64-aligned)
  const size_t n_a = 128 * 320 / 8;            // 5,120 (64-aligned)
  const size_t n_x2 = (size_t)N2V * 16;        // 8,000
  if (gid < n_x1) {
    size_t row = gid >> 4; int chunk = (int)(gid & 15);
    const f32x4* s = (const f32x4*)(x1 + row * 128 + chunk * 8);
    f32x4 v0 = s[0], v1 = s[1];
    uint4 o;
    o.x = pack_bf16x2(v0.x, v0.y); o.y = pack_bf16x2(v0.z, v0.w);
    o.z = pack_bf16x2(v1.x, v1.y); o.w = pack_bf16x2(v1.z, v1.w);
    *(uint4*)(x1bf + row * 64 + chunk * 4) = o;
    const float* cp = c + chunk * 8;
    float d = v0.x * cp[0] + v0.y * cp[1] + v0.z * cp[2] + v0.w * cp[3] +
              v1.x * cp[4] + v1.y * cp[5] + v1.z * cp[6] + v1.w * cp[7];
#pragma unroll
    for (int off = 1; off < 16; off <<= 1) d += __shfl_xor(d, off, 64);
    if (chunk == 0) z1g[row] = d;
  } else if (gid < n_x1 + n_a) {
    size_t idx = gid - n_x1;
    const f32x4* s = (const f32x4*)(a + idx * 8);
    f32x4 v0 = s[0], v1 = s[1];
    uint4 o;
    o.x = pack_bf16x2(v0.x, v0.y); o.y = pack_bf16x2(v0.z, v0.w);
    o.z = pack_bf16x2(v1.x, v1.y); o.w = pack_bf16x2(v1.z, v1.w);
    *(uint4*)(abf + idx * 4) = o;
  } else if (gid < n_x1 + n_a + n_x2) {
    size_t idx = gid - n_x1 - n_a;
    size_t row = idx >> 4; int chunk = (int)(idx & 15);
    const f32x4* s = (const f32x4*)(x2 + row * 128 + chunk * 8);
    f32x4 v0 = s[0], v1 = s[1];
    uint4 o;
    o.x = pack_bf16x2(v0.x, v0.y); o.y = pack_bf16x2(v0.z, v0.w);
    o.z = pack_bf16x2(v1.x, v1.y); o.w = pack_bf16x2(v1.z, v1.w);
    *(uint4*)(x2bf + row * 64 + chunk * 4) = o;
    const float* cp = c + 128 + chunk * 8;
    float d = v0.x * cp[0] + v0.y * cp[1] + v0.z * cp[2] + v0.w * cp[3] +
              v1.x * cp[4] + v1.y * cp[5] + v1.z * cp[6] + v1.w * cp[7];
#pragma unroll
    for (int off = 1; off < 16; off <<= 1) d += __shfl_xor(d, off, 64);
    if (chunk == 0) z2g[row] = d;
  }
}

// ---------------- linear pass: histograms + w + bf16 transcode (register-direct) ----------------
__global__ __launch_bounds__(256) void k_histw(const int* __restrict__ src,
                                               const int* __restrict__ dst,
                                               const float* __restrict__ ee,
                                               const float* __restrict__ z1g,
                                               const float* __restrict__ z2g,
                                               const float* __restrict__ c,
                                               int* __restrict__ c1,
                                               int* __restrict__ hblk,
                                               float* __restrict__ wbuf,
                                               u32* __restrict__ eeh) {
  __shared__ int h[512];
  for (int i = threadIdx.x; i < 512; i += 256) h[i] = 0;
  int tid = threadIdx.x;
  int wave = tid >> 6, lane = tid & 63;
  int r = lane >> 4, cc = lane & 15;
  float c0 = c[256 + cc * 4 + 0], c1r = c[256 + cc * 4 + 1];
  float c2 = c[256 + cc * 4 + 2], c3 = c[256 + cc * 4 + 3];
  __syncthreads();

  int b = blockIdx.x;
  int b0 = b * CHUNK, b1 = min(b0 + CHUNK, NEV);
  for (int eb = b0 + wave * 4; eb < b1; eb += 16) {
    int e = eb + r;
    bool ok = e < b1;
    int ec = ok ? e : b0;
    f32x4 v = __builtin_nontemporal_load((const f32x4*)(ee + (size_t)ec * 64) + cc);
    float d = v.x * c0 + v.y * c1r + v.z * c2 + v.w * c3;
#pragma unroll
    for (int off = 1; off < 16; off <<= 1) d += __shfl_xor(d, off, 64);
    if (ok) {
      u32x2 o;
      o.x = pack_bf16x2(v.x, v.y);
      o.y = pack_bf16x2(v.z, v.w);
      *(u32x2*)(eeh + (size_t)ec * 32 + cc * 2) = o;
      if (cc == 0) {
        int sv = src[e], dv = dst[e];
        float z = z1g[sv] + z2g[dv] + d;
        float zp = z > 0.f ? z : ALPHAV * z;
        wbuf[e] = __expf(-zp);
        atomicAdd(&c1[sv], 1);
        atomicAdd(&h[dv], 1);
      }
    }
  }
  __syncthreads();
  for (int i = threadIdx.x; i < 512; i += 256) hblk[(size_t)b * 512 + i] = h[i];
}

// ---------------- column scan over NB blocks ----------------
__global__ __launch_bounds__(256) void k_colscan(int* __restrict__ hblk,
                                                 int* __restrict__ tot2) {
  __shared__ int s[256];
  int t = blockIdx.x;
  int tid = threadIdx.x;
  int v[8]; int tot = 0;
#pragma unroll
  for (int j = 0; j < 8; ++j) {
    int b = tid * 8 + j;
    v[j] = hblk[(size_t)b * 512 + t];
    tot += v[j];
  }
  s[tid] = tot; __syncthreads();
  for (int off = 1; off < 256; off <<= 1) {
    int tv = (tid >= off) ? s[tid - off] : 0;
    __syncthreads();
    if (tid >= off) s[tid] += tv;
    __syncthreads();
  }
  int run = s[tid] - tot;
#pragma unroll
  for (int j = 0; j < 8; ++j) {
    int b = tid * 8 + j;
    hblk[(size_t)b * 512 + t] = run;
    run += v[j];
  }
  if (tid == 255) tot2[t] = run;
}

// ---------------- scan for src counts ----------------
__global__ __launch_bounds__(256) void k_scanA(const int* __restrict__ cnt,
                                               int* __restrict__ outp,
                                               int* __restrict__ partials, int n) {
  __shared__ int s[256];
  int tid = threadIdx.x;
  int base = blockIdx.x * 2048 + tid * 8;
  int v[8]; int tot = 0;
#pragma unroll
  for (int j = 0; j < 8; ++j) { int idx = base + j; v[j] = (idx < n) ? cnt[idx] : 0; tot += v[j]; }
  s[tid] = tot; __syncthreads();
  for (int off = 1; off < 256; off <<= 1) {
    int tv = 0;
    if (tid >= off) tv = s[tid - off];
    __syncthreads();
    if (tid >= off) s[tid] += tv;
    __syncthreads();
  }
  int run = s[tid] - tot;
#pragma unroll
  for (int j = 0; j < 8; ++j) { int idx = base + j; if (idx < n) outp[idx] = run; run += v[j]; }
  if (tid == 255) partials[blockIdx.x] = s[255];
}

__global__ __launch_bounds__(512) void k_scanB(int* __restrict__ partials, int nPart,
                                               const int* __restrict__ tot2,
                                               int* __restrict__ rp2) {
  __shared__ int s[512];
  int tid = threadIdx.x;
  int v = (tid < N2V) ? tot2[tid] : 0;
  s[tid] = v; __syncthreads();
  for (int off = 1; off < 512; off <<= 1) {
    int tv = 0;
    if (tid >= off) tv = s[tid - off];
    __syncthreads();
    if (tid >= off) s[tid] += tv;
    __syncthreads();
  }
  if (tid < N2V) rp2[tid] = s[tid] - v;
  if (tid == N2V - 1) rp2[N2V] = s[tid];
  if (tid == 0) {
    int run = 0;
    for (int b = 0; b < nPart; ++b) { int t = partials[b]; partials[b] = run; run += t; }
  }
}

__global__ __launch_bounds__(256) void k_scanC(int* __restrict__ rp, int* __restrict__ cur,
                                               const int* __restrict__ partials, int n, int total) {
  int i = blockIdx.x * 256 + threadIdx.x;
  if (i < n) {
    int v = rp[i] + partials[i >> 11];
    rp[i] = v; cur[i] = v;
  }
  if (i == 0) rp[n] = total;
}

// ---------------- light scatter: CSR placement only ----------------
__global__ __launch_bounds__(256) void k_scatter(const int* __restrict__ src,
                                                 const int* __restrict__ dst,
                                                 int* __restrict__ cur1,
                                                 const int* __restrict__ hblk,
                                                 const int* __restrict__ rp2,
                                                 int* __restrict__ e1, int* __restrict__ e2) {
  __shared__ int h[512];
  __shared__ int basep[512];
  int b = blockIdx.x;
  int b0 = b * CHUNK, b1 = min(b0 + CHUNK, NEV);
  for (int i = threadIdx.x; i < 512; i += 256) {
    basep[i] = ((i < N2V) ? rp2[i] : 0) + hblk[(size_t)b * 512 + i];
    h[i] = 0;
  }
  __syncthreads();
  for (int e = b0 + threadIdx.x; e < b1; e += 256) {
    int sv = src[e], d = dst[e];
    int p = atomicAdd(&cur1[sv], 1);
    e1[p] = e;
    int loc = atomicAdd(&h[d], 1);
    e2[basep[d] + loc] = e;
  }
}

// ---------------- fused gather pass (bf16 x rows): dst role then src role ----------------
__global__ __launch_bounds__(256) void k_gather(const u32* __restrict__ x1bf,
                                                const u32* __restrict__ x2bf,
                                                const u32* __restrict__ eeh32,
                                                const float* __restrict__ wbuf,
                                                const int* __restrict__ edge_src,
                                                const int* __restrict__ edge_dst,
                                                const int* __restrict__ rp2,
                                                const int* __restrict__ e2,
                                                const int* __restrict__ rp1,
                                                const int* __restrict__ e1,
                                                float* __restrict__ acc2,
                                                u32* __restrict__ sbuf1bf,
                                                float* __restrict__ rs1) {
  __shared__ float red[4][224];
  int tid = threadIdx.x;
  int l = tid & 63;
  int pl = l & 31, hi = l >> 5;

  if (blockIdx.x < NDSTB) {
    // ---------- dst role ----------
    int t = blockIdx.x / CHD;
    int chunk = blockIdx.x % CHD;
    int wv = tid >> 6;
    int start = rp2[t], end = rp2[t + 1];
    int n = end - start;
    int sub = chunk * 4 + wv;                                  // 0..31
    int i0 = start + (int)(((long long)n * sub) >> 5);
    int i1 = start + (int)(((long long)n * (sub + 1)) >> 5);
    float sxaa = 0.f, sxab = 0.f, sxba = 0.f, sxbb = 0.f, s3a = 0.f, s3b = 0.f, rsum = 0.f;
    int p = i0;
    for (; p + 4 <= i1; p += 4) {
      int ea = e2[p + hi], eb = e2[p + 2 + hi];
      float wa = wbuf[ea], wb = wbuf[eb];
      int sa = edge_src[ea], sb = edge_src[eb];
      u32 va = eeh32[(size_t)ea * 32 + pl];
      u32 vb = eeh32[(size_t)eb * 32 + pl];
      u32 xaa = x1bf[(size_t)sa * 64 + pl];
      u32 xab = x1bf[(size_t)sa * 64 + 32 + pl];
      u32 xba = x1bf[(size_t)sb * 64 + pl];
      u32 xbb = x1bf[(size_t)sb * 64 + 32 + pl];
      rsum += wa + wb;
      s3a += wa * bf16_lo(va) + wb * bf16_lo(vb);
      s3b += wa * bf16_hi(va) + wb * bf16_hi(vb);
      sxaa += wa * bf16_lo(xaa) + wb * bf16_lo(xba);
      sxab += wa * bf16_hi(xaa) + wb * bf16_hi(xba);
      sxba += wa * bf16_lo(xab) + wb * bf16_lo(xbb);
      sxbb += wa * bf16_hi(xab) + wb * bf16_hi(xbb);
    }
    for (; p < i1; p += 2) {
      int q = p + hi;
      bool ok = q < i1;
      int ea = e2[ok ? q : i0];
      float wa = ok ? wbuf[ea] : 0.f;
      int sa = edge_src[ea];
      u32 va = eeh32[(size_t)ea * 32 + pl];
      u32 xaa = x1bf[(size_t)sa * 64 + pl];
      u32 xab = x1bf[(size_t)sa * 64 + 32 + pl];
      rsum += wa;
      s3a += wa * bf16_lo(va);
      s3b += wa * bf16_hi(va);
      sxaa += wa * bf16_lo(xaa); sxab += wa * bf16_hi(xaa);
      sxba += wa * bf16_lo(xab); sxbb += wa * bf16_hi(xab);
    }
    sxaa += __shfl_xor(sxaa, 32); sxab += __shfl_xor(sxab, 32);
    sxba += __shfl_xor(sxba, 32); sxbb += __shfl_xor(sxbb, 32);
    s3a += __shfl_xor(s3a, 32);  s3b += __shfl_xor(s3b, 32);
    rsum += __shfl_xor(rsum, 32);
    if (hi == 0) {
      red[wv][2 * pl] = sxaa;       red[wv][2 * pl + 1] = sxab;
      red[wv][64 + 2 * pl] = sxba;  red[wv][64 + 2 * pl + 1] = sxbb;
      red[wv][128 + 2 * pl] = s3a;  red[wv][128 + 2 * pl + 1] = s3b;
      if (pl == 0) red[wv][192] = rsum;
    }
    __syncthreads();
    if (tid < 193) {
      float v = red[0][tid] + red[1][tid] + red[2][tid] + red[3][tid];
      if (v != 0.f) atomicAdd(&acc2[t * 256 + tid], v);
    }
  } else {
    // ---------- src role ----------
    int bid = blockIdx.x - NDSTB;
    int wid = (bid * 256 + tid) >> 6;
    if (wid >= N1V) return;
    int start = rp1[wid], end = rp1[wid + 1];
    float s2aa = 0.f, s2ab = 0.f, s2ba = 0.f, s2bb = 0.f, s1a = 0.f, s1b = 0.f, rsum = 0.f;
    int p = start;
    for (; p + 4 <= end; p += 4) {
      int ea = e1[p + hi], eb = e1[p + 2 + hi];
      float wa = wbuf[ea], wb = wbuf[eb];
      int da = edge_dst[ea], db = edge_dst[eb];
      u32 va = eeh32[(size_t)ea * 32 + pl];
      u32 vb = eeh32[(size_t)eb * 32 + pl];
      u32 xaa = x2bf[(size_t)da * 64 + pl];
      u32 xab = x2bf[(size_t)da * 64 + 32 + pl];
      u32 xba = x2bf[(size_t)db * 64 + pl];
      u32 xbb = x2bf[(size_t)db * 64 + 32 + pl];
      rsum += wa + wb;
      s1a += wa * bf16_lo(va) + wb * bf16_lo(vb);
      s1b += wa * bf16_hi(va) + wb * bf16_hi(vb);
      s2aa += wa * bf16_lo(xaa) + wb * bf16_lo(xba);
      s2ab += wa * bf16_hi(xaa) + wb * bf16_hi(xba);
      s2ba += wa * bf16_lo(xab) + wb * bf16_lo(xbb);
      s2bb += wa * bf16_hi(xab) + wb * bf16_hi(xbb);
    }
    for (; p < end; p += 2) {
      int q = p + hi;
      bool ok = q < end;
      int ea = e1[ok ? q : start];
      float wa = ok ? wbuf[ea] : 0.f;
      int da = edge_dst[ea];
      u32 va = eeh32[(size_t)ea * 32 + pl];
      u32 xaa = x2bf[(size_t)da * 64 + pl];
      u32 xab = x2bf[(size_t)da * 64 + 32 + pl];
      rsum += wa;
      s1a += wa * bf16_lo(va);
      s1b += wa * bf16_hi(va);
      s2aa += wa * bf16_lo(xaa); s2ab += wa * bf16_hi(xaa);
      s2ba += wa * bf16_lo(xab); s2bb += wa * bf16_hi(xab);
    }
    s2aa += __shfl_xor(s2aa, 32); s2ab += __shfl_xor(s2ab, 32);
    s2ba += __shfl_xor(s2ba, 32); s2bb += __shfl_xor(s2bb, 32);
    s1a += __shfl_xor(s1a, 32);  s1b += __shfl_xor(s1b, 32);
    rsum += __shfl_xor(rsum, 32);
    float scale = (end > start) ? 1.0f / rsum : 0.f;
    if (hi == 0) {
      u32* baseo = sbuf1bf + (size_t)wid * 96;
      baseo[pl] = pack_bf16x2(s2aa * scale, s2ab * scale);
      baseo[32 + pl] = pack_bf16x2(s2ba * scale, s2bb * scale);
      baseo[64 + pl] = pack_bf16x2(s1a * scale, s1b * scale);
      if (pl == 0) rs1[wid] = (end > start) ? rsum : 0.f;
    }
  }
}

// ---------------- dst finalize: bf16-pack sbuf2 ----------------
__global__ __launch_bounds__(256) void k_dst_final(const float* __restrict__ acc2,
                                                   u32* __restrict__ sbuf2bf,
                                                   float* __restrict__ rs2) {
  int t = blockIdx.x, tid = threadIdx.x;
  float rtot = acc2[t * 256 + 192];
  float scale = rtot > 0.f ? 1.0f / rtot : 0.f;
  if (tid < 192) {
    float o = acc2[t * 256 + tid] * scale;
    float pr = __shfl_xor(o, 1);
    if (!(tid & 1)) sbuf2bf[t * 96 + (tid >> 1)] = pack_bf16x2(o, pr);
  }
  if (tid == 192) rs2[t] = rtot;
}

// ---------------- MFMA output GEMM, both modes in one launch ----------------
__global__ __launch_bounds__(256) void k_gemm(const u32* __restrict__ x1bf,
                                              const u32* __restrict__ sbuf1bf,
                                              const u32* __restrict__ x2bf,
                                              const u32* __restrict__ sbuf2bf,
                                              const u32* __restrict__ abf,   // [128][160] u32
                                              const float* __restrict__ rs1,
                                              const float* __restrict__ rs2,
                                              float* __restrict__ outall) {
  __shared__ short Bt[128 * 40];   // [n=128][k=32 bf16 + pad 8]
  int tid = threadIdx.x;
  int w = tid >> 6, l = tid & 63;
  int r = l & 15, cchunk = l >> 4;          // 0..3
  int mode, row0, M;
  const u32 *Xbf, *Sbf;
  const float* rs;
  float* out;
  if (blockIdx.x < NGEMM1) {
    mode = 0; row0 = blockIdx.x * 64; M = N1V;
    Xbf = x1bf; Sbf = sbuf1bf; rs = rs1; out = outall;
  } else {
    mode = 1; row0 = (blockIdx.x - NGEMM1) * 64; M = N2V;
    Xbf = x2bf; Sbf = sbuf2bf; rs = rs2; out = outall + (size_t)N1V * 128;
  }
  int gi = row0 + w * 16 + r;               // A-row this lane loads
  int gclamp = min(gi, M - 1);
  f32x4v acc[8];
#pragma unroll
  for (int i = 0; i < 8; ++i) acc[i] = (f32x4v){0.f, 0.f, 0.f, 0.f};

  for (int ks = 0; ks < 10; ++ks) {
    if (ks) __syncthreads();
    {
      int n = tid >> 1, half = tid & 1;
      const u32* srcp = abf + n * 160 + ks * 16 + half * 8;
      u32* dstp = (u32*)&Bt[n * 40] + half * 8;
      *(uint4*)(dstp) = *(const uint4*)(srcp);
      *(uint4*)(dstp + 4) = *(const uint4*)(srcp + 4);
    }
    __syncthreads();
    int ck = ks * 4 + cchunk;                // 8-elem chunk index, 0..39
    const u32* ap;
    if (mode == 0) {
      ap = (ck < 16) ? (Xbf + (size_t)gclamp * 64 + ck * 4)
                     : (Sbf + (size_t)gclamp * 96 + (ck - 16) * 4);
    } else {
      ap = (ck < 16) ? (Sbf + (size_t)gclamp * 96 + ck * 4)
         : (ck < 32) ? (Xbf + (size_t)gclamp * 64 + (ck - 16) * 4)
                     : (Sbf + (size_t)gclamp * 96 + 64 + (ck - 32) * 4);
    }
    bf16x8 afrag = *(const bf16x8*)ap;
#pragma unroll
    for (int nt = 0; nt < 8; ++nt) {
      bf16x8 bfrag = *(const bf16x8*)&Bt[(nt * 16 + r) * 40 + cchunk * 8];
      acc[nt] = __builtin_amdgcn_mfma_f32_16x16x32_bf16(afrag, bfrag, acc[nt], 0, 0, 0);
    }
  }
  int baser = row0 + w * 16 + cchunk * 4;
#pragma unroll
  for (int rr = 0; rr < 4; ++rr) {
    int go = baser + rr;
    if (go < M) {
      float rsv = rs[go];
      bool ok = rsv > 0.f;
#pragma unroll
      for (int nt = 0; nt < 8; ++nt) {
        float h = acc[nt][rr];
        float v = ok ? (h > 0.f ? h : expm1f(h)) : 0.f;
        out[(size_t)go * 128 + nt * 16 + r] = v;
      }
    }
  }
}

// =====================================================================================

static inline size_t align_up(size_t x, size_t a) { return (x + a - 1) & ~(a - 1); }

extern "C" void kernel_launch(void* const* d_in, const int* in_sizes, int n_in,
                              void* d_out, int out_size, void* d_ws, size_t ws_size,
                              hipStream_t stream) {
  const float* x1 = (const float*)d_in[0];
  const float* x2 = (const float*)d_in[1];
  const float* ee = (const float*)d_in[2];
  const float* a = (const float*)d_in[3];
  const float* a2 = (const float*)d_in[4];
  const int* esrc = (const int*)d_in[5];
  const int* edst = (const int*)d_in[6];
  float* out = (float*)d_out;

  char* base = (char*)d_ws;
  size_t off = 0;
  auto alloc = [&](size_t bytes) -> char* {
    char* p = base + off;
    off = align_up(off + bytes, 256);
    return p;
  };
  float* c = (float*)alloc(320 * 4);
  float* z1g = (float*)alloc(N1V * 4);
  float* z2g = (float*)alloc(512 * 4);
  u32* x1bf = (u32*)alloc((size_t)N1V * 64 * 4);      // 25.6 MB
  u32* x2bf = (u32*)alloc((size_t)N2V * 64 * 4);
  u32* abf = (u32*)alloc(128 * 160 * 4);              // 80 KB
  int* rp1 = (int*)alloc((N1V + 1) * 4);
  int* cur1 = (int*)alloc(N1V * 4);
  int* rp2 = (int*)alloc(512 * 4);
  int* partials = (int*)alloc(64 * 4);
  int* hblk = (int*)alloc((size_t)NB * 512 * 4);      // 4 MB
  int* tot2 = (int*)alloc(512 * 4);
  int* e1 = (int*)alloc(NEV * 4);
  int* e2 = (int*)alloc(NEV * 4);
  float* wbuf = (float*)alloc(NEV * 4);
  u32* eeh = (u32*)alloc((size_t)NEV * 128);          // 128 MB (bf16 ee)
  float* rs1 = (float*)alloc(N1V * 4);
  float* rs2 = (float*)alloc(512 * 4);
  u32* sbuf1bf = (u32*)alloc((size_t)N1V * 96 * 4);   // 38.4 MB
  u32* sbuf2bf = (u32*)alloc(512 * 96 * 4);
  float* acc2 = (float*)alloc(512 * 256 * 4);
  (void)ws_size; (void)out_size; (void)n_in; (void)in_sizes;

  hipMemsetAsync(cur1, 0, N1V * 4, stream);
  hipMemsetAsync(acc2, 0, 512 * 256 * 4, stream);

  hipLaunchKernelGGL(k_prep, dim3(2), dim3(256), 0, stream, a, a2, c);
  hipLaunchKernelGGL(k_conv, dim3((1600000 + 5120 + 8000 + 255) / 256), dim3(256), 0, stream,
                     x1, x2, a, c, x1bf, x2bf, abf, z1g, z2g);
  hipLaunchKernelGGL(k_histw, dim3(NB), dim3(256), 0, stream,
                     esrc, edst, ee, z1g, z2g, c, cur1, hblk, wbuf, eeh);
  hipLaunchKernelGGL(k_colscan, dim3(512), dim3(256), 0, stream, hblk, tot2);

  const int nScanBlocks = (N1V + 2047) / 2048;  // 49
  hipLaunchKernelGGL(k_scanA, dim3(nScanBlocks), dim3(256), 0, stream, cur1, rp1, partials, N1V);
  hipLaunchKernelGGL(k_scanB, dim3(1), dim3(512), 0, stream, partials, nScanBlocks, tot2, rp2);
  hipLaunchKernelGGL(k_scanC, dim3((N1V + 255) / 256), dim3(256), 0, stream, rp1, cur1, partials, N1V, NEV);
  hipLaunchKernelGGL(k_scatter, dim3(NB), dim3(256), 0, stream,
                     esrc, edst, cur1, hblk, rp2, e1, e2);

  hipLaunchKernelGGL(k_gather, dim3(NDSTB + NSRCB), dim3(256), 0, stream,
                     x1bf, x2bf, eeh, wbuf, esrc, edst, rp2, e2, rp1, e1,
                     acc2, sbuf1bf, rs1);
  hipLaunchKernelGGL(k_dst_final, dim3(N2V), dim3(256), 0, stream, acc2, sbuf2bf, rs2);

  hipLaunchKernelGGL(k_gemm, dim3(NGEMM1 + NGEMM2), dim3(256), 0, stream,
                     x1bf, sbuf1bf, x2bf, sbuf2bf, abf, rs1, rs2, out);
}

// Round 20
// 370.090 us; speedup vs baseline: 2.1517x; 1.0377x over previous
//
#include <hip/hip_runtime.h>

#define N1V 100000
#define N2V 500
#define NEV 1000000
#define ALPHAV 0.2f
#define NB 2048       // histogram/scatter blocks
#define CHUNK 489     // ceil(NEV/NB)
#define CHD 8         // dst chunks per type
#define NDSTB (N2V * CHD)          // 4000 dst blocks
#define NSRCB (N1V / 4)            // 25000 src blocks
#define NGEMM1 ((N1V + 63) / 64)   // 1563
#define NGEMM2 ((N2V + 63) / 64)   // 8

typedef float f32x4 __attribute__((ext_vector_type(4)));
typedef unsigned int u32;
typedef unsigned short u16;
typedef u32 u32x2 __attribute__((ext_vector_type(2)));
using bf16x8 = __attribute__((ext_vector_type(8))) short;   // 8 bf16 (4 VGPRs)
using f32x4v = __attribute__((ext_vector_type(4))) float;

__device__ __forceinline__ u32 pack_bf16x2(float a, float b) {
  u32 ua = __float_as_uint(a), ub = __float_as_uint(b);
  u32 ra = (ua + 0x7FFFu + ((ua >> 16) & 1u)) >> 16;
  u32 rb = (ub + 0x7FFFu + ((ub >> 16) & 1u)) >> 16;
  return ra | (rb << 16);
}

__device__ __forceinline__ float bf16_lo(u32 v) { return __uint_as_float(v << 16); }
__device__ __forceinline__ float bf16_hi(u32 v) { return __uint_as_float(v & 0xFFFF0000u); }

// ---------------- prep: c[320] = a^T @ a_2 ----------------
__global__ __launch_bounds__(256) void k_prep(const float* __restrict__ a,
                                              const float* __restrict__ a2,
                                              float* __restrict__ c) {
  int p = blockIdx.x * 256 + threadIdx.x;
  if (p < 320) {
    float s = 0.f;
    for (int k = 0; k < 128; ++k) s += a2[k] * a[k * 320 + p];
    c[p] = s;
  }
}

// ---------------- fused bf16 conversions + z1/z2 dots ----------------
__global__ __launch_bounds__(256) void k_conv(const float* __restrict__ x1,
                                              const float* __restrict__ x2,
                                              const float* __restrict__ a,
                                              const float* __restrict__ c,
                                              u32* __restrict__ x1bf,
                                              u32* __restrict__ x2bf,
                                              u32* __restrict__ abf,
                                              float* __restrict__ z1g,
                                              float* __restrict__ z2g) {
  size_t gid = (size_t)blockIdx.x * 256 + threadIdx.x;
  const size_t n_x1 = (size_t)N1V * 16;        // 1,600,000 (64-aligned)
  const size_t n_a = 128 * 320 / 8;            // 5,120 (64-aligned)
  const size_t n_x2 = (size_t)N2V * 16;        // 8,000
  if (gid < n_x1) {
    size_t row = gid >> 4; int chunk = (int)(gid & 15);
    const f32x4* s = (const f32x4*)(x1 + row * 128 + chunk * 8);
    f32x4 v0 = s[0], v1 = s[1];
    uint4 o;
    o.x = pack_bf16x2(v0.x, v0.y); o.y = pack_bf16x2(v0.z, v0.w);
    o.z = pack_bf16x2(v1.x, v1.y); o.w = pack_bf16x2(v1.z, v1.w);
    *(uint4*)(x1bf + row * 64 + chunk * 4) = o;
    const float* cp = c + chunk * 8;
    float d = v0.x * cp[0] + v0.y * cp[1] + v0.z * cp[2] + v0.w * cp[3] +
              v1.x * cp[4] + v1.y * cp[5] + v1.z * cp[6] + v1.w * cp[7];
#pragma unroll
    for (int off = 1; off < 16; off <<= 1) d += __shfl_xor(d, off, 64);
    if (chunk == 0) z1g[row] = d;
  } else if (gid < n_x1 + n_a) {
    size_t idx = gid - n_x1;
    const f32x4* s = (const f32x4*)(a + idx * 8);
    f32x4 v0 = s[0], v1 = s[1];
    uint4 o;
    o.x = pack_bf16x2(v0.x, v0.y); o.y = pack_bf16x2(v0.z, v0.w);
    o.z = pack_bf16x2(v1.x, v1.y); o.w = pack_bf16x2(v1.z, v1.w);
    *(uint4*)(abf + idx * 4) = o;
  } else if (gid < n_x1 + n_a + n_x2) {
    size_t idx = gid - n_x1 - n_a;
    size_t row = idx >> 4; int chunk = (int)(idx & 15);
    const f32x4* s = (const f32x4*)(x2 + row * 128 + chunk * 8);
    f32x4 v0 = s[0], v1 = s[1];
    uint4 o;
    o.x = pack_bf16x2(v0.x, v0.y); o.y = pack_bf16x2(v0.z, v0.w);
    o.z = pack_bf16x2(v1.x, v1.y); o.w = pack_bf16x2(v1.z, v1.w);
    *(uint4*)(x2bf + row * 64 + chunk * 4) = o;
    const float* cp = c + 128 + chunk * 8;
    float d = v0.x * cp[0] + v0.y * cp[1] + v0.z * cp[2] + v0.w * cp[3] +
              v1.x * cp[4] + v1.y * cp[5] + v1.z * cp[6] + v1.w * cp[7];
#pragma unroll
    for (int off = 1; off < 16; off <<= 1) d += __shfl_xor(d, off, 64);
    if (chunk == 0) z2g[row] = d;
  }
}

// ---------------- linear pass: histograms + w + bf16 transcode (register-direct) ----------------
__global__ __launch_bounds__(256) void k_histw(const int* __restrict__ src,
                                               const int* __restrict__ dst,
                                               const float* __restrict__ ee,
                                               const float* __restrict__ z1g,
                                               const float* __restrict__ z2g,
                                               const float* __restrict__ c,
                                               int* __restrict__ c1,
                                               int* __restrict__ hblk,
                                               float* __restrict__ wbuf,
                                               u32* __restrict__ eeh) {
  __shared__ int h[512];
  for (int i = threadIdx.x; i < 512; i += 256) h[i] = 0;
  int tid = threadIdx.x;
  int wave = tid >> 6, lane = tid & 63;
  int r = lane >> 4, cc = lane & 15;
  float c0 = c[256 + cc * 4 + 0], c1r = c[256 + cc * 4 + 1];
  float c2 = c[256 + cc * 4 + 2], c3 = c[256 + cc * 4 + 3];
  __syncthreads();

  int b = blockIdx.x;
  int b0 = b * CHUNK, b1 = min(b0 + CHUNK, NEV);
  for (int eb = b0 + wave * 4; eb < b1; eb += 16) {
    int e = eb + r;
    bool ok = e < b1;
    int ec = ok ? e : b0;
    f32x4 v = __builtin_nontemporal_load((const f32x4*)(ee + (size_t)ec * 64) + cc);
    float d = v.x * c0 + v.y * c1r + v.z * c2 + v.w * c3;
#pragma unroll
    for (int off = 1; off < 16; off <<= 1) d += __shfl_xor(d, off, 64);
    if (ok) {
      u32x2 o;
      o.x = pack_bf16x2(v.x, v.y);
      o.y = pack_bf16x2(v.z, v.w);
      *(u32x2*)(eeh + (size_t)ec * 32 + cc * 2) = o;
      if (cc == 0) {
        int sv = src[e], dv = dst[e];
        float z = z1g[sv] + z2g[dv] + d;
        float zp = z > 0.f ? z : ALPHAV * z;
        wbuf[e] = __expf(-zp);
        atomicAdd(&c1[sv], 1);
        atomicAdd(&h[dv], 1);
      }
    }
  }
  __syncthreads();
  for (int i = threadIdx.x; i < 512; i += 256) hblk[(size_t)b * 512 + i] = h[i];
}

// ---------------- column scan over NB blocks ----------------
__global__ __launch_bounds__(256) void k_colscan(int* __restrict__ hblk,
                                                 int* __restrict__ tot2) {
  __shared__ int s[256];
  int t = blockIdx.x;
  int tid = threadIdx.x;
  int v[8]; int tot = 0;
#pragma unroll
  for (int j = 0; j < 8; ++j) {
    int b = tid * 8 + j;
    v[j] = hblk[(size_t)b * 512 + t];
    tot += v[j];
  }
  s[tid] = tot; __syncthreads();
  for (int off = 1; off < 256; off <<= 1) {
    int tv = (tid >= off) ? s[tid - off] : 0;
    __syncthreads();
    if (tid >= off) s[tid] += tv;
    __syncthreads();
  }
  int run = s[tid] - tot;
#pragma unroll
  for (int j = 0; j < 8; ++j) {
    int b = tid * 8 + j;
    hblk[(size_t)b * 512 + t] = run;
    run += v[j];
  }
  if (tid == 255) tot2[t] = run;
}

// ---------------- scan for src counts ----------------
__global__ __launch_bounds__(256) void k_scanA(const int* __restrict__ cnt,
                                               int* __restrict__ outp,
                                               int* __restrict__ partials, int n) {
  __shared__ int s[256];
  int tid = threadIdx.x;
  int base = blockIdx.x * 2048 + tid * 8;
  int v[8]; int tot = 0;
#pragma unroll
  for (int j = 0; j < 8; ++j) { int idx = base + j; v[j] = (idx < n) ? cnt[idx] : 0; tot += v[j]; }
  s[tid] = tot; __syncthreads();
  for (int off = 1; off < 256; off <<= 1) {
    int tv = 0;
    if (tid >= off) tv = s[tid - off];
    __syncthreads();
    if (tid >= off) s[tid] += tv;
    __syncthreads();
  }
  int run = s[tid] - tot;
#pragma unroll
  for (int j = 0; j < 8; ++j) { int idx = base + j; if (idx < n) outp[idx] = run; run += v[j]; }
  if (tid == 255) partials[blockIdx.x] = s[255];
}

__global__ __launch_bounds__(512) void k_scanB(int* __restrict__ partials, int nPart,
                                               const int* __restrict__ tot2,
                                               int* __restrict__ rp2) {
  __shared__ int s[512];
  int tid = threadIdx.x;
  int v = (tid < N2V) ? tot2[tid] : 0;
  s[tid] = v; __syncthreads();
  for (int off = 1; off < 512; off <<= 1) {
    int tv = 0;
    if (tid >= off) tv = s[tid - off];
    __syncthreads();
    if (tid >= off) s[tid] += tv;
    __syncthreads();
  }
  if (tid < N2V) rp2[tid] = s[tid] - v;
  if (tid == N2V - 1) rp2[N2V] = s[tid];
  if (tid == 0) {
    int run = 0;
    for (int b = 0; b < nPart; ++b) { int t = partials[b]; partials[b] = run; run += t; }
  }
}

__global__ __launch_bounds__(256) void k_scanC(int* __restrict__ rp, int* __restrict__ cur,
                                               const int* __restrict__ partials, int n, int total) {
  int i = blockIdx.x * 256 + threadIdx.x;
  if (i < n) {
    int v = rp[i] + partials[i >> 11];
    rp[i] = v; cur[i] = v;
  }
  if (i == 0) rp[n] = total;
}

// ---------------- scatter: CSR placement + slot-ordered (w, partner) ----------------
__global__ __launch_bounds__(256) void k_scatter(const int* __restrict__ src,
                                                 const int* __restrict__ dst,
                                                 const float* __restrict__ wbuf,
                                                 int* __restrict__ cur1,
                                                 const int* __restrict__ hblk,
                                                 const int* __restrict__ rp2,
                                                 int* __restrict__ e1, int* __restrict__ e2,
                                                 float2* __restrict__ wd1,
                                                 float2* __restrict__ wd2) {
  __shared__ int h[512];
  __shared__ int basep[512];
  int b = blockIdx.x;
  int b0 = b * CHUNK, b1 = min(b0 + CHUNK, NEV);
  for (int i = threadIdx.x; i < 512; i += 256) {
    basep[i] = ((i < N2V) ? rp2[i] : 0) + hblk[(size_t)b * 512 + i];
    h[i] = 0;
  }
  __syncthreads();
  for (int e = b0 + threadIdx.x; e < b1; e += 256) {
    int sv = src[e], d = dst[e];
    float w = wbuf[e];
    int p = atomicAdd(&cur1[sv], 1);
    e1[p] = e;
    wd1[p] = make_float2(w, __int_as_float(d));
    int loc = atomicAdd(&h[d], 1);
    int q2 = basep[d] + loc;
    e2[q2] = e;
    wd2[q2] = make_float2(w, __int_as_float(sv));
  }
}

// ---------------- fused gather pass (bf16 rows, slot-packed w/partner) ----------------
__global__ __launch_bounds__(256) void k_gather(const u32* __restrict__ x1bf,
                                                const u32* __restrict__ x2bf,
                                                const u32* __restrict__ eeh32,
                                                const int* __restrict__ rp2,
                                                const int* __restrict__ e2,
                                                const float2* __restrict__ wd2,
                                                const int* __restrict__ rp1,
                                                const int* __restrict__ e1,
                                                const float2* __restrict__ wd1,
                                                float* __restrict__ acc2,
                                                u32* __restrict__ sbuf1bf,
                                                float* __restrict__ rs1) {
  __shared__ float red[4][224];
  int tid = threadIdx.x;
  int l = tid & 63;
  int pl = l & 31, hi = l >> 5;

  if (blockIdx.x < NDSTB) {
    // ---------- dst role ----------
    int t = blockIdx.x / CHD;
    int chunk = blockIdx.x % CHD;
    int wv = tid >> 6;
    int start = rp2[t], end = rp2[t + 1];
    int n = end - start;
    int sub = chunk * 4 + wv;                                  // 0..31
    int i0 = start + (int)(((long long)n * sub) >> 5);
    int i1 = start + (int)(((long long)n * (sub + 1)) >> 5);
    float sxaa = 0.f, sxab = 0.f, sxba = 0.f, sxbb = 0.f, s3a = 0.f, s3b = 0.f, rsum = 0.f;
    int p = i0;
    for (; p + 4 <= i1; p += 4) {
      int ea = e2[p + hi], eb = e2[p + 2 + hi];
      float2 qa = wd2[p + hi], qb = wd2[p + 2 + hi];
      float wa = qa.x, wb = qb.x;
      int sa = __float_as_int(qa.y), sb = __float_as_int(qb.y);
      u32 va = eeh32[(size_t)ea * 32 + pl];
      u32 vb = eeh32[(size_t)eb * 32 + pl];
      u32 xaa = x1bf[(size_t)sa * 64 + pl];
      u32 xab = x1bf[(size_t)sa * 64 + 32 + pl];
      u32 xba = x1bf[(size_t)sb * 64 + pl];
      u32 xbb = x1bf[(size_t)sb * 64 + 32 + pl];
      rsum += wa + wb;
      s3a += wa * bf16_lo(va) + wb * bf16_lo(vb);
      s3b += wa * bf16_hi(va) + wb * bf16_hi(vb);
      sxaa += wa * bf16_lo(xaa) + wb * bf16_lo(xba);
      sxab += wa * bf16_hi(xaa) + wb * bf16_hi(xba);
      sxba += wa * bf16_lo(xab) + wb * bf16_lo(xbb);
      sxbb += wa * bf16_hi(xab) + wb * bf16_hi(xbb);
    }
    for (; p < i1; p += 2) {
      int q = p + hi;
      bool ok = q < i1;
      int qc = ok ? q : i0;
      int ea = e2[qc];
      float2 qa = wd2[qc];
      float wa = ok ? qa.x : 0.f;
      int sa = __float_as_int(qa.y);
      u32 va = eeh32[(size_t)ea * 32 + pl];
      u32 xaa = x1bf[(size_t)sa * 64 + pl];
      u32 xab = x1bf[(size_t)sa * 64 + 32 + pl];
      rsum += wa;
      s3a += wa * bf16_lo(va);
      s3b += wa * bf16_hi(va);
      sxaa += wa * bf16_lo(xaa); sxab += wa * bf16_hi(xaa);
      sxba += wa * bf16_lo(xab); sxbb += wa * bf16_hi(xab);
    }
    sxaa += __shfl_xor(sxaa, 32); sxab += __shfl_xor(sxab, 32);
    sxba += __shfl_xor(sxba, 32); sxbb += __shfl_xor(sxbb, 32);
    s3a += __shfl_xor(s3a, 32);  s3b += __shfl_xor(s3b, 32);
    rsum += __shfl_xor(rsum, 32);
    if (hi == 0) {
      red[wv][2 * pl] = sxaa;       red[wv][2 * pl + 1] = sxab;
      red[wv][64 + 2 * pl] = sxba;  red[wv][64 + 2 * pl + 1] = sxbb;
      red[wv][128 + 2 * pl] = s3a;  red[wv][128 + 2 * pl + 1] = s3b;
      if (pl == 0) red[wv][192] = rsum;
    }
    __syncthreads();
    if (tid < 193) {
      float v = red[0][tid] + red[1][tid] + red[2][tid] + red[3][tid];
      if (v != 0.f) atomicAdd(&acc2[t * 256 + tid], v);
    }
  } else {
    // ---------- src role ----------
    int bid = blockIdx.x - NDSTB;
    int wid = (bid * 256 + tid) >> 6;
    if (wid >= N1V) return;
    int start = rp1[wid], end = rp1[wid + 1];
    float s2aa = 0.f, s2ab = 0.f, s2ba = 0.f, s2bb = 0.f, s1a = 0.f, s1b = 0.f, rsum = 0.f;
    int p = start;
    for (; p + 4 <= end; p += 4) {
      int ea = e1[p + hi], eb = e1[p + 2 + hi];
      float2 qa = wd1[p + hi], qb = wd1[p + 2 + hi];
      float wa = qa.x, wb = qb.x;
      int da = __float_as_int(qa.y), db = __float_as_int(qb.y);
      u32 va = eeh32[(size_t)ea * 32 + pl];
      u32 vb = eeh32[(size_t)eb * 32 + pl];
      u32 xaa = x2bf[(size_t)da * 64 + pl];
      u32 xab = x2bf[(size_t)da * 64 + 32 + pl];
      u32 xba = x2bf[(size_t)db * 64 + pl];
      u32 xbb = x2bf[(size_t)db * 64 + 32 + pl];
      rsum += wa + wb;
      s1a += wa * bf16_lo(va) + wb * bf16_lo(vb);
      s1b += wa * bf16_hi(va) + wb * bf16_hi(vb);
      s2aa += wa * bf16_lo(xaa) + wb * bf16_lo(xba);
      s2ab += wa * bf16_hi(xaa) + wb * bf16_hi(xba);
      s2ba += wa * bf16_lo(xab) + wb * bf16_lo(xbb);
      s2bb += wa * bf16_hi(xab) + wb * bf16_hi(xbb);
    }
    for (; p < end; p += 2) {
      int q = p + hi;
      bool ok = q < end;
      int qc = ok ? q : start;
      int ea = e1[qc];
      float2 qa = wd1[qc];
      float wa = ok ? qa.x : 0.f;
      int da = __float_as_int(qa.y);
      u32 va = eeh32[(size_t)ea * 32 + pl];
      u32 xaa = x2bf[(size_t)da * 64 + pl];
      u32 xab = x2bf[(size_t)da * 64 + 32 + pl];
      rsum += wa;
      s1a += wa * bf16_lo(va);
      s1b += wa * bf16_hi(va);
      s2aa += wa * bf16_lo(xaa); s2ab += wa * bf16_hi(xaa);
      s2ba += wa * bf16_lo(xab); s2bb += wa * bf16_hi(xab);
    }
    s2aa += __shfl_xor(s2aa, 32); s2ab += __shfl_xor(s2ab, 32);
    s2ba += __shfl_xor(s2ba, 32); s2bb += __shfl_xor(s2bb, 32);
    s1a += __shfl_xor(s1a, 32);  s1b += __shfl_xor(s1b, 32);
    rsum += __shfl_xor(rsum, 32);
    float scale = (end > start) ? 1.0f / rsum : 0.f;
    if (hi == 0) {
      u32* baseo = sbuf1bf + (size_t)wid * 96;
      baseo[pl] = pack_bf16x2(s2aa * scale, s2ab * scale);
      baseo[32 + pl] = pack_bf16x2(s2ba * scale, s2bb * scale);
      baseo[64 + pl] = pack_bf16x2(s1a * scale, s1b * scale);
      if (pl == 0) rs1[wid] = (end > start) ? rsum : 0.f;
    }
  }
}

// ---------------- dst finalize: bf16-pack sbuf2 ----------------
__global__ __launch_bounds__(256) void k_dst_final(const float* __restrict__ acc2,
                                                   u32* __restrict__ sbuf2bf,
                                                   float* __restrict__ rs2) {
  int t = blockIdx.x, tid = threadIdx.x;
  float rtot = acc2[t * 256 + 192];
  float scale = rtot > 0.f ? 1.0f / rtot : 0.f;
  if (tid < 192) {
    float o = acc2[t * 256 + tid] * scale;
    float pr = __shfl_xor(o, 1);
    if (!(tid & 1)) sbuf2bf[t * 96 + (tid >> 1)] = pack_bf16x2(o, pr);
  }
  if (tid == 192) rs2[t] = rtot;
}

// ---------------- MFMA output GEMM, both modes in one launch ----------------
__global__ __launch_bounds__(256) void k_gemm(const u32* __restrict__ x1bf,
                                              const u32* __restrict__ sbuf1bf,
                                              const u32* __restrict__ x2bf,
                                              const u32* __restrict__ sbuf2bf,
                                              const u32* __restrict__ abf,   // [128][160] u32
                                              const float* __restrict__ rs1,
                                              const float* __restrict__ rs2,
                                              float* __restrict__ outall) {
  __shared__ short Bt[128 * 40];   // [n=128][k=32 bf16 + pad 8]
  int tid = threadIdx.x;
  int w = tid >> 6, l = tid & 63;
  int r = l & 15, cchunk = l >> 4;          // 0..3
  int mode, row0, M;
  const u32 *Xbf, *Sbf;
  const float* rs;
  float* out;
  if (blockIdx.x < NGEMM1) {
    mode = 0; row0 = blockIdx.x * 64; M = N1V;
    Xbf = x1bf; Sbf = sbuf1bf; rs = rs1; out = outall;
  } else {
    mode = 1; row0 = (blockIdx.x - NGEMM1) * 64; M = N2V;
    Xbf = x2bf; Sbf = sbuf2bf; rs = rs2; out = outall + (size_t)N1V * 128;
  }
  int gi = row0 + w * 16 + r;               // A-row this lane loads
  int gclamp = min(gi, M - 1);
  f32x4v acc[8];
#pragma unroll
  for (int i = 0; i < 8; ++i) acc[i] = (f32x4v){0.f, 0.f, 0.f, 0.f};

  for (int ks = 0; ks < 10; ++ks) {
    if (ks) __syncthreads();
    {
      int n = tid >> 1, half = tid & 1;
      const u32* srcp = abf + n * 160 + ks * 16 + half * 8;
      u32* dstp = (u32*)&Bt[n * 40] + half * 8;
      *(uint4*)(dstp) = *(const uint4*)(srcp);
      *(uint4*)(dstp + 4) = *(const uint4*)(srcp + 4);
    }
    __syncthreads();
    int ck = ks * 4 + cchunk;                // 8-elem chunk index, 0..39
    const u32* ap;
    if (mode == 0) {
      ap = (ck < 16) ? (Xbf + (size_t)gclamp * 64 + ck * 4)
                     : (Sbf + (size_t)gclamp * 96 + (ck - 16) * 4);
    } else {
      ap = (ck < 16) ? (Sbf + (size_t)gclamp * 96 + ck * 4)
         : (ck < 32) ? (Xbf + (size_t)gclamp * 64 + (ck - 16) * 4)
                     : (Sbf + (size_t)gclamp * 96 + 64 + (ck - 32) * 4);
    }
    bf16x8 afrag = *(const bf16x8*)ap;
#pragma unroll
    for (int nt = 0; nt < 8; ++nt) {
      bf16x8 bfrag = *(const bf16x8*)&Bt[(nt * 16 + r) * 40 + cchunk * 8];
      acc[nt] = __builtin_amdgcn_mfma_f32_16x16x32_bf16(afrag, bfrag, acc[nt], 0, 0, 0);
    }
  }
  int baser = row0 + w * 16 + cchunk * 4;
#pragma unroll
  for (int rr = 0; rr < 4; ++rr) {
    int go = baser + rr;
    if (go < M) {
      float rsv = rs[go];
      bool ok = rsv > 0.f;
#pragma unroll
      for (int nt = 0; nt < 8; ++nt) {
        float h = acc[nt][rr];
        float v = ok ? (h > 0.f ? h : expm1f(h)) : 0.f;
        out[(size_t)go * 128 + nt * 16 + r] = v;
      }
    }
  }
}

// =====================================================================================

static inline size_t align_up(size_t x, size_t a) { return (x + a - 1) & ~(a - 1); }

extern "C" void kernel_launch(void* const* d_in, const int* in_sizes, int n_in,
                              void* d_out, int out_size, void* d_ws, size_t ws_size,
                              hipStream_t stream) {
  const float* x1 = (const float*)d_in[0];
  const float* x2 = (const float*)d_in[1];
  const float* ee = (const float*)d_in[2];
  const float* a = (const float*)d_in[3];
  const float* a2 = (const float*)d_in[4];
  const int* esrc = (const int*)d_in[5];
  const int* edst = (const int*)d_in[6];
  float* out = (float*)d_out;

  char* base = (char*)d_ws;
  size_t off = 0;
  auto alloc = [&](size_t bytes) -> char* {
    char* p = base + off;
    off = align_up(off + bytes, 256);
    return p;
  };
  float* c = (float*)alloc(320 * 4);
  float* z1g = (float*)alloc(N1V * 4);
  float* z2g = (float*)alloc(512 * 4);
  u32* x1bf = (u32*)alloc((size_t)N1V * 64 * 4);      // 25.6 MB
  u32* x2bf = (u32*)alloc((size_t)N2V * 64 * 4);
  u32* abf = (u32*)alloc(128 * 160 * 4);              // 80 KB
  int* rp1 = (int*)alloc((N1V + 1) * 4);
  int* cur1 = (int*)alloc(N1V * 4);
  int* rp2 = (int*)alloc(512 * 4);
  int* partials = (int*)alloc(64 * 4);
  int* hblk = (int*)alloc((size_t)NB * 512 * 4);      // 4 MB
  int* tot2 = (int*)alloc(512 * 4);
  int* e1 = (int*)alloc(NEV * 4);
  int* e2 = (int*)alloc(NEV * 4);
  float2* wd1 = (float2*)alloc((size_t)NEV * 8);
  float2* wd2 = (float2*)alloc((size_t)NEV * 8);
  float* wbuf = (float*)alloc(NEV * 4);
  u32* eeh = (u32*)alloc((size_t)NEV * 128);          // 128 MB (bf16 ee)
  float* rs1 = (float*)alloc(N1V * 4);
  float* rs2 = (float*)alloc(512 * 4);
  u32* sbuf1bf = (u32*)alloc((size_t)N1V * 96 * 4);   // 38.4 MB
  u32* sbuf2bf = (u32*)alloc(512 * 96 * 4);
  float* acc2 = (float*)alloc(512 * 256 * 4);
  (void)ws_size; (void)out_size; (void)n_in; (void)in_sizes;

  hipMemsetAsync(cur1, 0, N1V * 4, stream);
  hipMemsetAsync(acc2, 0, 512 * 256 * 4, stream);

  hipLaunchKernelGGL(k_prep, dim3(2), dim3(256), 0, stream, a, a2, c);
  hipLaunchKernelGGL(k_conv, dim3((1600000 + 5120 + 8000 + 255) / 256), dim3(256), 0, stream,
                     x1, x2, a, c, x1bf, x2bf, abf, z1g, z2g);
  hipLaunchKernelGGL(k_histw, dim3(NB), dim3(256), 0, stream,
                     esrc, edst, ee, z1g, z2g, c, cur1, hblk, wbuf, eeh);
  hipLaunchKernelGGL(k_colscan, dim3(512), dim3(256), 0, stream, hblk, tot2);

  const int nScanBlocks = (N1V + 2047) / 2048;  // 49
  hipLaunchKernelGGL(k_scanA, dim3(nScanBlocks), dim3(256), 0, stream, cur1, rp1, partials, N1V);
  hipLaunchKernelGGL(k_scanB, dim3(1), dim3(512), 0, stream, partials, nScanBlocks, tot2, rp2);
  hipLaunchKernelGGL(k_scanC, dim3((N1V + 255) / 256), dim3(256), 0, stream, rp1, cur1, partials, N1V, NEV);
  hipLaunchKernelGGL(k_scatter, dim3(NB), dim3(256), 0, stream,
                     esrc, edst, wbuf, cur1, hblk, rp2, e1, e2, wd1, wd2);

  hipLaunchKernelGGL(k_gather, dim3(NDSTB + NSRCB), dim3(256), 0, stream,
                     x1bf, x2bf, eeh, rp2, e2, wd2, rp1, e1, wd1,
                     acc2, sbuf1bf, rs1);
  hipLaunchKernelGGL(k_dst_final, dim3(N2V), dim3(256), 0, stream, acc2, sbuf2bf, rs2);

  hipLaunchKernelGGL(k_gemm, dim3(NGEMM1 + NGEMM2), dim3(256), 0, stream,
                     x1bf, sbuf1bf, x2bf, sbuf2bf, abf, rs1, rs2, out);
}